// Round 8
// baseline (1365.993 us; speedup 1.0000x reference)
//
#include <hip/hip_runtime.h>
#include <math.h>

#define NEGV -1000000000.0f

typedef short short8 __attribute__((ext_vector_type(8)));
typedef float floatx4 __attribute__((ext_vector_type(4)));

__device__ __forceinline__ float sigm(float x){ return 1.0f/(1.0f+expf(-x)); }
__device__ __forceinline__ void edge_sd(int e,const int* src,const int* dst,int E,int& s,int& d){
  if(e<E){ s=src[e]; d=dst[e]; } else { s=e-E; d=s; }
}
__device__ __forceinline__ ushort bf16rn(float x){
  unsigned u = __float_as_uint(x);
  unsigned r = (u + 0x7fffu + ((u>>16)&1u)) >> 16;
  return (ushort)r;
}
__device__ __forceinline__ float bf16f(ushort h){ return __uint_as_float(((unsigned)h)<<16); }

__global__ void k_zero(float* __restrict__ p, size_t n){
  size_t i = (size_t)blockIdx.x*256 + threadIdx.x;
  if (i < n) p[i] = 0.0f;
}

// ---------------- bf16x3 conversions ----------------
__global__ void k_split3(const float* __restrict__ src,int R,int Cs,int ld,
                         ushort* __restrict__ dst,int Cp,int bmode){
  int idx = blockIdx.x*256+threadIdx.x;
  if (idx >= R*Cp) return;
  int r = idx / Cp, c = idx - r*Cp;
  float x = (c < Cs) ? src[(size_t)r*ld + c] : 0.0f;
  ushort h = bf16rn(x);
  ushort l = bf16rn(x - bf16f(h));
  size_t base = (size_t)r*(3*Cp) + c;
  dst[base]        = h;
  dst[base + Cp]   = bmode ? l : h;
  dst[base + 2*Cp] = bmode ? h : l;
}
// Sp = exp(src[:,perm]-mcol[perm])*invd[perm], transposed to K-innermost; writes BOTH
// A-role (dstA) and B-role (dstB); zero-pads k>=Rs rows in dstA/dstB AND dstCpad.
__global__ void k_split3_Tdual(const float* __restrict__ src,int Rs,int Cs,int ld,
                               const int* __restrict__ gperm,const float* __restrict__ cscale,
                               const float* __restrict__ emax,
                               ushort* __restrict__ dstA,ushort* __restrict__ dstB,
                               ushort* __restrict__ dstCpad,int Kp){
  __shared__ float t[32][33];
  int tx = threadIdx.x & 31, ty = threadIdx.x >> 5;
  int kb = blockIdx.y*32, xb = blockIdx.x*32;
  int x = xb + tx;
  int gx = (x < Cs) ? gperm[x] : 0;
#pragma unroll
  for (int i=0;i<4;i++){
    int k = kb + ty + i*8;
    t[ty+i*8][tx] = (k < Rs && x < Cs) ? src[(size_t)k*ld + gx] : 0.0f;
  }
  __syncthreads();
  const int K3 = 3*Kp;
#pragma unroll
  for (int i=0;i<4;i++){
    int xo = xb + ty + i*8, ko = kb + tx;
    if (xo < Cs){
      float v = 0.0f;
      if (ko < Rs){
        int g = gperm[xo];
        v = expf(t[tx][ty+i*8] - emax[g]) * cscale[g];
      }
      ushort h = bf16rn(v);
      ushort l = bf16rn(v - bf16f(h));
      size_t base = (size_t)xo*K3 + ko;
      dstA[base] = h; dstA[base+Kp] = h; dstA[base+2*Kp] = l;
      dstB[base] = h; dstB[base+Kp] = l; dstB[base+2*Kp] = h;
      if (ko >= Rs){ dstCpad[base]=0; dstCpad[base+Kp]=0; dstCpad[base+2*Kp]=0; }
    }
  }
}

// ---------------- MFMA bf16 GEMM (64x64 tile, K-step 64, double-buffered) ----------------
// EPI 1: mask(A+I)+leakyrelu.  (Used for the score GEMM, K3=192.)
template<int EPI>
__global__ __launch_bounds__(256) void k_gemm_mfma(
    const ushort* __restrict__ A, const ushort* __restrict__ B,
    float* __restrict__ C, int ldc, int M, int N, int K3,
    const float* __restrict__ mask, int ldm)
{
  __shared__ ushort As[2][64][72];
  __shared__ ushort Bs[2][64][72];
  const int tid = threadIdx.x;
  const int m0 = blockIdx.y*64, n0 = blockIdx.x*64;
  const int w = tid>>6, lane = tid&63;
  const int lo4 = lane&15, quad = lane>>4;
  const int sr = tid>>2, sseg = tid&3;

  floatx4 acc[4];
#pragma unroll
  for(int c=0;c<4;c++){ acc[c][0]=0.f; acc[c][1]=0.f; acc[c][2]=0.f; acc[c][3]=0.f; }

  const size_t arow = (size_t)(m0+sr)*K3;
  const size_t brow = (size_t)(n0+sr)*K3;
  const bool aval = (m0+sr) < M;
  const bool bval = (n0+sr) < N;

  uint4 av0 = make_uint4(0,0,0,0), av1 = make_uint4(0,0,0,0);
  uint4 bv0 = make_uint4(0,0,0,0), bv1 = make_uint4(0,0,0,0);
  if (aval){ av0 = *(const uint4*)(A + arow + sseg*8);
             av1 = *(const uint4*)(A + arow + 32 + sseg*8); }
  if (bval){ bv0 = *(const uint4*)(B + brow + sseg*8);
             bv1 = *(const uint4*)(B + brow + 32 + sseg*8); }
  *(uint4*)&As[0][sr][sseg*8] = av0; *(uint4*)&As[0][sr][32+sseg*8] = av1;
  *(uint4*)&Bs[0][sr][sseg*8] = bv0; *(uint4*)&Bs[0][sr][32+sseg*8] = bv1;
  __syncthreads();

  const int T = K3 >> 6;
  for (int i=0;i<T;i++){
    const int cb = i & 1;
    if (i+1 < T){
      const int k0 = (i+1)<<6;
      av0 = make_uint4(0,0,0,0); av1 = make_uint4(0,0,0,0);
      bv0 = make_uint4(0,0,0,0); bv1 = make_uint4(0,0,0,0);
      if (aval){ av0 = *(const uint4*)(A + arow + k0 + sseg*8);
                 av1 = *(const uint4*)(A + arow + k0 + 32 + sseg*8); }
      if (bval){ bv0 = *(const uint4*)(B + brow + k0 + sseg*8);
                 bv1 = *(const uint4*)(B + brow + k0 + 32 + sseg*8); }
    }
    short8 af0 = *(const short8*)&As[cb][16*w + lo4][quad*8];
    short8 af1 = *(const short8*)&As[cb][16*w + lo4][32+quad*8];
#pragma unroll
    for (int c=0;c<4;c++){
      short8 bf0 = *(const short8*)&Bs[cb][16*c + lo4][quad*8];
      acc[c] = __builtin_amdgcn_mfma_f32_16x16x32_bf16(af0, bf0, acc[c], 0, 0, 0);
      short8 bf1 = *(const short8*)&Bs[cb][16*c + lo4][32+quad*8];
      acc[c] = __builtin_amdgcn_mfma_f32_16x16x32_bf16(af1, bf1, acc[c], 0, 0, 0);
    }
    if (i+1 < T){
      __syncthreads();
      *(uint4*)&As[1-cb][sr][sseg*8] = av0; *(uint4*)&As[1-cb][sr][32+sseg*8] = av1;
      *(uint4*)&Bs[1-cb][sr][sseg*8] = bv0; *(uint4*)&Bs[1-cb][sr][32+sseg*8] = bv1;
      __syncthreads();
    }
  }

#pragma unroll
  for (int c=0;c<4;c++){
    const int gn = n0 + 16*c + lo4;
#pragma unroll
    for (int r=0;r<4;r++){
      const int gm = m0 + 16*w + quad*4 + r;
      if (gm < M && gn < N){
        float v = acc[c][r];
        if (EPI==1) v = (mask[(size_t)gm*ldm+gn] != 0.0f || gm==gn) ? (v > 0.0f ? v : 0.2f*v) : NEGV;
        C[(size_t)gm*ldc+gn] = v;
      }
    }
  }
}

// ---------------- split-K x4 MFMA partial-product GEMM, 128x128 tile, K-step 32 ----------------
// R7: K-step 64 -> 32 halves LDS to 40KB -> EXACTLY 4 blocks/CU (16 waves/CU, 4/SIMD)
// vs 2 before — doubles the TLP hiding L3 latency (pp was ~15% of its MFMA floor at
// 2 blocks/CU). Per K-step a wave does 8 ds_read_b128 for 16 MFMAs (same density).
// MFMA sequence per acc element is IDENTICAL to the K-step-64 version (each
// 16x16x32 MFMA consumes the same k-slice in the same order) -> bit-identical.
// XCD-chunked bijective swizzle retained.
__global__ __launch_bounds__(256,4) void k_gemm_pp(
    const ushort* __restrict__ A, const ushort* __restrict__ B,
    float* __restrict__ P0, float* __restrict__ P1,
    float* __restrict__ P2, float* __restrict__ P3, int ldp,
    int M, int N, int K3, int kchunk)
{
  __shared__ ushort As[2][128][40];
  __shared__ ushort Bs[2][128][40];
  const int tid = threadIdx.x;

  // ---- XCD-chunked bijective block remap ----
  const int gx = gridDim.x, gxy = gridDim.x*gridDim.y;
  const int TT = gxy*gridDim.z;
  const int s  = blockIdx.x + gx*blockIdx.y + gxy*blockIdx.z;
  const int c8 = s & 7, u = s >> 3;
  const int q = TT >> 3, r8 = TT & 7;
  const int w0 = (c8 < r8) ? c8*(q+1) + u : r8*(q+1) + (c8 - r8)*q + u;
  const int z  = w0 / gxy;
  const int lin = w0 - z*gxy;
  const int ty = lin / gx, tx = lin - ty*gx;

  const int m0 = ty*128, n0 = tx*128;
  const int w = tid>>6, lane = tid&63;
  const int lo4 = lane&15, quad = lane>>4;
  const int wr = w>>1, wc = w&1;

  // staging: thread t -> row t>>1, k-half t&1 (16 ushort = 2x uint4 per operand)
  const int srow = tid>>1, shalf = tid&1;
  const int sbase = shalf*16;

  float* __restrict__ P = (z==0) ? P0 : (z==1) ? P1 : (z==2) ? P2 : P3;
  const int kbeg = z * kchunk;
  int klen = K3 - kbeg; if (klen > kchunk) klen = kchunk; if (klen < 0) klen = 0;
  const int T = klen >> 5;

  floatx4 acc[4][4];
#pragma unroll
  for(int i=0;i<4;i++)
#pragma unroll
    for(int c=0;c<4;c++){ acc[i][c][0]=0.f; acc[i][c][1]=0.f; acc[i][c][2]=0.f; acc[i][c][3]=0.f; }

  const size_t arow = (size_t)(m0+srow)*K3 + kbeg + shalf*16;
  const size_t brow = (size_t)(n0+srow)*K3 + kbeg + shalf*16;
  const bool aval = (m0+srow) < M;
  const bool bval = (n0+srow) < N;

  uint4 apre[2], bpre[2];
#pragma unroll
  for(int s2=0;s2<2;s2++){ apre[s2]=make_uint4(0,0,0,0); bpre[s2]=make_uint4(0,0,0,0); }
  if (aval){
#pragma unroll
    for(int s2=0;s2<2;s2++) apre[s2] = *(const uint4*)(A + arow + s2*8);
  }
  if (bval){
#pragma unroll
    for(int s2=0;s2<2;s2++) bpre[s2] = *(const uint4*)(B + brow + s2*8);
  }
#pragma unroll
  for(int s2=0;s2<2;s2++){
    *(uint4*)&As[0][srow][sbase + s2*8] = apre[s2];
    *(uint4*)&Bs[0][srow][sbase + s2*8] = bpre[s2];
  }
  __syncthreads();

  for (int it=0; it<T; ++it){
    const int cb = it & 1;
    if (it+1 < T){
      const int k0 = (it+1)<<5;
#pragma unroll
      for(int s2=0;s2<2;s2++){ apre[s2]=make_uint4(0,0,0,0); bpre[s2]=make_uint4(0,0,0,0); }
      if (aval){
#pragma unroll
        for(int s2=0;s2<2;s2++) apre[s2] = *(const uint4*)(A + arow + k0 + s2*8);
      }
      if (bval){
#pragma unroll
        for(int s2=0;s2<2;s2++) bpre[s2] = *(const uint4*)(B + brow + k0 + s2*8);
      }
    }
    short8 af[4];
#pragma unroll
    for(int i=0;i<4;i++)
      af[i] = *(const short8*)&As[cb][wr*64 + 16*i + lo4][quad*8];
#pragma unroll
    for(int c=0;c<4;c++){
      short8 bf = *(const short8*)&Bs[cb][wc*64 + 16*c + lo4][quad*8];
#pragma unroll
      for(int i=0;i<4;i++)
        acc[i][c] = __builtin_amdgcn_mfma_f32_16x16x32_bf16(af[i], bf, acc[i][c], 0, 0, 0);
    }
    if (it+1 < T){
      __syncthreads();
#pragma unroll
      for(int s2=0;s2<2;s2++){
        *(uint4*)&As[1-cb][srow][sbase + s2*8] = apre[s2];
        *(uint4*)&Bs[1-cb][srow][sbase + s2*8] = bpre[s2];
      }
      __syncthreads();
    }
  }

#pragma unroll
  for(int c=0;c<4;c++){
    const int gn = n0 + wc*64 + 16*c + lo4;
    if (gn < N){
#pragma unroll
      for(int i=0;i<4;i++){
#pragma unroll
        for(int r=0;r<4;r++){
          const int gm = m0 + wr*64 + 16*i + quad*4 + r;
          if (gm < M) P[(size_t)gm*ldp+gn] = acc[i][c][r];
        }
      }
    }
  }
}

// reduce 4 TB slabs + Sp, transpose-store as bf16x3 B-role (h,l,h) at gn*K3o+gm.
__global__ __launch_bounds__(256) void k_red_tb(
    const float* __restrict__ P0,const float* __restrict__ P1,
    const float* __restrict__ P2,const float* __restrict__ P3,int ldp,
    const ushort* __restrict__ Bb, ushort* __restrict__ Cb,
    int M,int N,int Kp)
{
  __shared__ float t[32][33];
  const int tx = threadIdx.x & 31, ty = threadIdx.x >> 5;
  const int mb = blockIdx.y*32, nb = blockIdx.x*32;
  const int n = nb + tx;
#pragma unroll
  for (int i=0;i<4;i++){
    int m = mb + ty + i*8;
    float v = 0.0f;
    if (m < M && n < N){
      size_t o = (size_t)m*ldp + n;
      v = (P0[o] + P1[o]) + (P2[o] + P3[o]);
    }
    t[ty+i*8][tx] = v;
  }
  __syncthreads();
  const int K3o = 3*Kp;
#pragma unroll
  for (int i=0;i<4;i++){
    int no = nb + ty + i*8, mo = mb + tx;
    if (no < N && mo < M){
      size_t base = (size_t)no*K3o + mo;
      float sp = bf16f(Bb[base]) + bf16f(Bb[base+Kp]);
      float v = t[tx][ty+i*8] + sp;
      ushort h = bf16rn(v), l = bf16rn(v - bf16f(h));
      Cb[base] = h; Cb[base+Kp] = l; Cb[base+2*Kp] = h;
    }
  }
}

// reduce 4 A_new slabs + zero diagonal. (C may alias one of the slabs: per-element
// read-then-write, no cross-thread sharing -> safe.)
__global__ void k_red_diag(const float* __restrict__ P0,const float* __restrict__ P1,
                           const float* __restrict__ P2,const float* __restrict__ P3,
                           float* __restrict__ C,int kk){
  int idx = blockIdx.x*256+threadIdx.x;
  if (idx >= kk*kk) return;
  int u = idx/kk, v = idx - u*kk;
  float s = (P0[idx] + P1[idx]) + (P2[idx] + P3[idx]);
  C[idx] = (u==v) ? 0.0f : s;
}

// ---------------- atomic-free skinny agg GEMM ----------------
template<bool MAXM, bool COUNT, bool EXPM, bool SELF>
__global__ __launch_bounds__(256) void k_skinny(
    const float* __restrict__ A, int lda,
    const float* __restrict__ X,
    const float* __restrict__ mcol,
    float* __restrict__ P, int* __restrict__ cntp,
    int M, int K, int kchunk)
{
  __shared__ float As[16][68];
  __shared__ float Xs[16][68];
  const int tid = threadIdx.x;
  const int m0 = blockIdx.y * 64;
  const int tmb = (tid & 15) * 4, tnb = (tid >> 4) * 4;
  float acc[4][4];
  int cacc[4] = {0,0,0,0};
#pragma unroll
  for (int i=0;i<4;i++)
#pragma unroll
    for (int j=0;j<4;j++) acc[i][j] = MAXM ? NEGV : 0.0f;

  const int kstart = blockIdx.z * kchunk;
  int kend = kstart + kchunk; if (kend > K) kend = K;
  const int ml = tid & 63, tb = tid >> 6;
  const bool mvalid = (m0 + ml) < M;
  float mc = 0.0f;
  if (EXPM && mvalid) mc = mcol[m0 + ml];

  for (int k0 = kstart; k0 < kend; k0 += 16) {
#pragma unroll
    for (int s=0;s<4;s++) {
      const int tk = tb + s*4;
      float va = 0.0f, vx = 0.0f;
      if ((k0+tk) < K) {
        if (mvalid){
          va = A[(size_t)(k0+tk)*lda + m0 + ml];
          if (EXPM) va = expf(va - mc);
        }
        vx = X[(size_t)(k0+tk)*64 + ml];
      }
      As[tk][ml] = va;
      Xs[tk][ml] = vx;
    }
    __syncthreads();
#pragma unroll
    for (int kk=0; kk<16; kk++) {
      const float4 a4 = *(const float4*)&As[kk][tmb];
      const float4 b4 = *(const float4*)&Xs[kk][tnb];
      const float av[4] = {a4.x,a4.y,a4.z,a4.w};
      const float bv[4] = {b4.x,b4.y,b4.z,b4.w};
#pragma unroll
      for (int i=0;i<4;i++){
        if (COUNT) cacc[i] += (av[i] != 0.0f) ? 1 : 0;
#pragma unroll
        for (int j=0;j<4;j++) {
          if (MAXM) acc[i][j] = fmaxf(acc[i][j], av[i] != 0.0f ? bv[j] : NEGV);
          else      acc[i][j] = fmaf(av[i], bv[j], acc[i][j]);
        }
      }
    }
    __syncthreads();
  }

  const size_t slab = (size_t)blockIdx.z * M * 64;
#pragma unroll
  for (int i=0;i<4;i++){
    const int m = m0 + tmb + i;
    if (m < M){
#pragma unroll
      for (int j=0;j<4;j++){
        float v = acc[i][j];
        if (SELF) v = fmaxf(v, X[(size_t)m*64 + tnb + j]);
        P[slab + (size_t)m*64 + tnb + j] = v;
      }
    }
  }
  if (COUNT && tnb == 0){
#pragma unroll
    for (int i=0;i<4;i++){
      const int m = m0 + tmb + i;
      if (m < M) cntp[blockIdx.z*M + m] = cacc[i];
    }
  }
}

// slab max-reduce -> xq; xq2 = xq@pW+pb; cntP = 1 + sum counts.
// Also emits bf16x3 operands: dstA (A-role from X), dstB (B-role from xq2).
__global__ __launch_bounds__(256) void k_poolq(
    const float* __restrict__ SEGP,const int* __restrict__ cntp8,int Z,
    const float* __restrict__ pWp,const float* __restrict__ pbp,
    const float* __restrict__ X,
    ushort* __restrict__ dstA,ushort* __restrict__ dstB,
    float* __restrict__ cntP,int n)
{
  __shared__ float xq[4][65];
  const int tid = threadIdx.x;
  const int r = tid>>6, j = tid&63;
  const int i = blockIdx.x*4 + r;
  float v = NEGV;
  if (i < n){
    for(int z=0;z<Z;z++) v = fmaxf(v, SEGP[(size_t)z*n*64 + (size_t)i*64 + j]);
    if (j == 0){
      int c=1; for(int z=0;z<Z;z++) c += cntp8[z*n+i];
      cntP[i] = (float)c;
    }
  }
  xq[r][j] = v;
  __syncthreads();
  if (i < n){
    float s = pbp[j];
    for(int q=0;q<64;q++) s = fmaf(xq[r][q], pWp[q*64+j], s);
    size_t base = (size_t)i*192 + j;
    ushort h = bf16rn(s), l = bf16rn(s - bf16f(h));
    dstB[base] = h; dstB[base+64] = l; dstB[base+128] = h;
    float x = X[(size_t)i*64 + j];
    h = bf16rn(x); l = bf16rn(x - bf16f(h));
    dstA[base] = h; dstA[base+64] = h; dstA[base+128] = l;
  }
}

// fused dense gconv: reduce slabs, two 64x64 matmuls, relu, mean-accumulate.
__global__ __launch_bounds__(256) void k_gconv_fuse(
    const float* __restrict__ SEGP,const int* __restrict__ cntp8,int Z,
    const float* __restrict__ Wrel,const float* __restrict__ brel,
    const float* __restrict__ X,const float* __restrict__ Wroot,
    float* __restrict__ XN,int n,float* __restrict__ meanacc,float inv_n)
{
  __shared__ float agg_s[4][65];
  __shared__ float xrow[4][65];
  __shared__ float cnt_s[4];
  const int tid = threadIdx.x;
  const int r = tid>>6, j = tid&63;
  const int i = blockIdx.x*4 + r;
  float a = 0.0f;
  if (i < n){
    for(int z=0;z<Z;z++) a += SEGP[(size_t)z*n*64 + (size_t)i*64 + j];
    xrow[r][j] = X[(size_t)i*64 + j];
    if (j == 0){
      int c=0; for(int z=0;z<Z;z++) c += cntp8[z*n+i];
      cnt_s[r] = (float)(c>1?c:1);
    }
  }
  agg_s[r][j] = a;
  __syncthreads();
  float v = 0.0f;
  if (i < n){
    float acc=0.0f, rt=0.0f;
    for(int q=0;q<64;q++){
      acc = fmaf(agg_s[r][q], Wrel[q*64+j], acc);
      rt  = fmaf(xrow[r][q],  Wroot[q*64+j], rt);
    }
    v = fmaxf(acc/cnt_s[r] + brel[j] + rt, 0.0f);
    XN[(size_t)i*64 + j] = v;
  }
  __syncthreads();
  agg_s[r][j] = v;
  __syncthreads();
  if (r == 0) atomicAdd(&meanacc[j], (agg_s[0][j]+agg_s[1][j]+agg_s[2][j]+agg_s[3][j])*inv_n);
}

// ---------------- fused column softmax stats (ONE kernel) ----------------
__global__ __launch_bounds__(256) void k_smax_fused(const float* __restrict__ S,int n,
                                                    float* __restrict__ mcol,float* __restrict__ invd){
  __shared__ float red[16][17];
  const int jc = threadIdx.x & 15, rg = threadIdx.x >> 4;
  const int j = blockIdx.x*16 + jc;
  float m = -3.0e38f;
  if (j < n)
    for(int i=rg;i<n;i+=16) m = fmaxf(m, S[(size_t)i*n+j]);
  red[rg][jc] = m;
  __syncthreads();
  for(int s=8;s>0;s>>=1){
    if(rg<s) red[rg][jc] = fmaxf(red[rg][jc], red[rg+s][jc]);
    __syncthreads();
  }
  const float mc = red[0][jc];
  __syncthreads();
  float sum = 0.0f;
  if (j < n)
    for(int i=rg;i<n;i+=16) sum += expf(S[(size_t)i*n+j]-mc);
  red[rg][jc] = sum;
  __syncthreads();
  for(int s=8;s>0;s>>=1){
    if(rg<s) red[rg][jc] += red[rg+s][jc];
    __syncthreads();
  }
  if(rg==0 && j<n){ mcol[j]=mc; invd[j]=1.0f/red[0][jc]; }
}

// slab sum * invd -> XC; then aN/bN/cN per row; zeroes pcnt.
__global__ __launch_bounds__(256) void k_xcabc_dense(
    const float* __restrict__ SEGP,int Z,const float* __restrict__ invd,
    float* __restrict__ XC,
    const float* __restrict__ w1,const float* bb1,const float* __restrict__ w2,
    const float* __restrict__ w3,const float* bb3,
    float* aN,float* bN,float* cN,int* pcnt,int n)
{
  __shared__ float xc[4][65];
  const int tid = threadIdx.x;
  const int r = tid>>6, j = tid&63;
  const int i = blockIdx.x*4 + r;
  if (blockIdx.x==0 && tid==0) *pcnt = 0;
  float v = 0.0f;
  if (i < n){
    for(int z=0;z<Z;z++) v += SEGP[(size_t)z*n*64 + (size_t)i*64 + j];
    v *= invd[i];
    XC[(size_t)i*64+j] = v;
  }
  xc[r][j] = v;
  __syncthreads();
  if (i < n && j < 3){
    float s = (j==0)?bb1[0]:((j==2)?bb3[0]:0.0f);
    const float* w = (j==0)?w1:((j==1)?w2:w3);
    for(int q=0;q<64;q++) s = fmaf(xc[r][q], w[q], s);
    if(j==0) aN[i]=s; else if(j==1) bN[i]=s; else cN[i]=s;
  }
}

__global__ void k_aggcol(const float* __restrict__ A,const float* __restrict__ aN,
                         float* __restrict__ aggp,int n){
  int idx = blockIdx.x*256+threadIdx.x; if(idx>=n*16) return;
  int j = idx % n, c = idx / n;
  int i0 = (int)(((long long)n*c)/16), i1 = (int)(((long long)n*(c+1))/16);
  float s = 0.0f;
  for(int i=i0;i<i1;i++) if(A[(size_t)i*n + j] != 0.0f) s += aN[i];
  aggp[c*n + j] = s;
}

// ---------------- parallel top-k rank ----------------
__global__ void k_fit_dense(const float* __restrict__ aggp,const float* __restrict__ cntP,
                            const float* __restrict__ aN,const float* __restrict__ bN,
                            const float* __restrict__ cN,
                            float* __restrict__ fit,int* __restrict__ rank,int* pcnt,int n){
  int u = blockIdx.x*256+threadIdx.x;
  if (blockIdx.x==0 && threadIdx.x==0) *pcnt = 0;
  if (u >= n) return;
  float a = aN[u];
  for(int c=0;c<16;c++) a += aggp[c*n+u];
  fit[u] = sigm(a - cntP[u]*bN[u] + cN[u]);
  rank[u] = 0;
}
__global__ __launch_bounds__(256) void k_rank_cnt(const float* __restrict__ fit,
                                                  int* __restrict__ rank,int n){
  __shared__ float fsc[128];
  const int u0 = blockIdx.y*128;
  int u1 = u0+128; if (u1 > n) u1 = n;
  const int cl = u1 - u0;
  if ((int)threadIdx.x < cl) fsc[threadIdx.x] = fit[u0+threadIdx.x];
  __syncthreads();
  const int v = blockIdx.x*256+threadIdx.x;
  if (v >= n) return;
  const float fv = fit[v];
  int r = 0;
  for(int t=0;t<cl;t++){
    const float fu = fsc[t];
    const int u = u0+t;
    r += (fu > fv || (fu == fv && u < v)) ? 1 : 0;
  }
  atomicAdd(&rank[v], r);
}
// Selection + coalesced XN write; optionally records inverse perm (ipos[v]=slot).
__global__ __launch_bounds__(256) void k_rank_sel(const int* __restrict__ rank,
    const float* __restrict__ fit,const float* __restrict__ XC,float* __restrict__ XN,
    int n,int k,int* pcnt,int* perm,int* __restrict__ ipos){
  __shared__ int ps[4];
  const int r = threadIdx.x>>6, h = threadIdx.x&63;
  const int v = blockIdx.x*4 + r;
  const bool sel = (v < n) && (rank[v] < k);
  if (h == 0 && sel){
    int p = atomicAdd(pcnt,1);
    ps[r] = p;
    perm[p] = v;
    if (ipos) ipos[v] = p;
  }
  __syncthreads();
  if (sel){
    const int p = ps[r];
    XN[(size_t)p*64 + h] = XC[(size_t)v*64 + h] * fit[v];
  }
}

// ---------------- prologue: degrees + CSR over L=E+n edges (incl self) ----------------
__global__ void k_deg(const int* __restrict__ src,const int* __restrict__ dst,int* indeg,int* outdeg,int E){
  int e = blockIdx.x*256+threadIdx.x; if(e>=E) return;
  atomicAdd(&indeg[dst[e]],1); atomicAdd(&outdeg[src[e]],1);
}
__global__ __launch_bounds__(256) void k_prefix2(const int* __restrict__ indeg,const int* __restrict__ outdeg,
                          int* offD,int* curD,int* offS,int* curS,int n){
  __shared__ int ds[1504];
  const int* dsrc = blockIdx.y ? outdeg : indeg;
  for(int u=threadIdx.x; u<n; u+=256) ds[u] = dsrc[u];
  __syncthreads();
  int t = blockIdx.x*256+threadIdx.x; if(t>n) return;
  int s = 0;
  for(int u=0;u<t;u++) s += ds[u]+1;
  if (blockIdx.y){ offS[t]=s; if(t<n) curS[t]=s; }
  else           { offD[t]=s; if(t<n) curD[t]=s; }
}
__global__ void k_csr_fill2(const int* src,const int* dst,
                            int* curS,int* colS,int* eidS,
                            int* curD,int* rowD,int* eidD,int E,int n){
  int e = blockIdx.x*256+threadIdx.x; if(e>=E+n) return;
  int s,d; edge_sd(e,src,dst,E,s,d);
  int p = atomicAdd(&curS[s],1); colS[p]=d; eidS[p]=e;
  int q = atomicAdd(&curD[d],1); rowD[q]=s; eidD[q]=e;
}

__global__ void k_mm_small(const float* __restrict__ A,const float* __restrict__ W,
                           const float* __restrict__ b,float* __restrict__ C,
                           int M,int K,int Np,int act){
  int idx = blockIdx.x*256+threadIdx.x; if(idx>=M*Np) return;
  int m = idx/Np, j = idx - m*Np;
  float s = b ? b[j] : 0.0f;
  const float* a = A + (size_t)m*K;
  for(int q=0;q<K;q++) s = fmaf(a[q], W[(size_t)q*Np + j], s);
  if(act==1) s = fmaxf(s, 0.0f);
  C[idx] = s;
}

// feast: gather-mean over in-edges (incl self), +b, elu; optional mean (H==64)
__global__ void k_feast_gf(const float* __restrict__ Y,const int* __restrict__ offD,
                           const int* __restrict__ rowD,
                           const float* __restrict__ b,float* X,int n,int H,
                           float* __restrict__ meanacc,float inv_n){
  __shared__ float ms[4][64];
  int idx = blockIdx.x*256+threadIdx.x;
  float v = 0.0f;
  if(idx<n*H){
    int i = idx/H, h = idx - i*H;
    int p0 = offD[i], p1 = offD[i+1];
    float s = 0.0f;
    for(int p=p0;p<p1;p++) s += Y[(size_t)rowD[p]*H + h];
    float t = s/(float)(p1-p0) + b[h];
    v = t > 0.0f ? t : (expf(t)-1.0f);
    X[idx] = v;
  }
  if(meanacc){
    int r = threadIdx.x>>6, j = threadIdx.x&63;
    ms[r][j] = (idx<n*H) ? v : 0.0f;
    __syncthreads();
    if(r==0) atomicAdd(&meanacc[j], (ms[0][j]+ms[1][j]+ms[2][j]+ms[3][j])*inv_n);
  }
}

// fused sparse gconv: gather agg (real edges only), 2 matmuls, relu, mean.
__global__ __launch_bounds__(256) void k_gconv_sparse_f(
    const float* __restrict__ X,const int* __restrict__ offD,const int* __restrict__ rowD,
    const int* __restrict__ eidD,int E,
    const float* __restrict__ Wrel,const float* __restrict__ brel,
    const float* __restrict__ Wroot,
    float* __restrict__ XN,int n,float* __restrict__ meanacc,float inv_n)
{
  __shared__ float agg_s[4][65];
  __shared__ float xrow[4][65];
  __shared__ float cnt_s[4];
  const int tid = threadIdx.x;
  const int r = tid>>6, j = tid&63;
  const int i = blockIdx.x*4 + r;
  float a = 0.0f;
  if (i < n){
    int p0 = offD[i], p1 = offD[i+1], c = 0;
    for(int p=p0;p<p1;p++){
      if (eidD[p] < E){ a += X[(size_t)rowD[p]*64 + j]; c++; }
    }
    xrow[r][j] = X[(size_t)i*64 + j];
    if (j == 0) cnt_s[r] = (float)(c>1?c:1);
  }
  agg_s[r][j] = a;
  __syncthreads();
  float v = 0.0f;
  if (i < n){
    float acc=0.0f, rt=0.0f;
    for(int q=0;q<64;q++){
      acc = fmaf(agg_s[r][q], Wrel[q*64+j], acc);
      rt  = fmaf(xrow[r][q],  Wroot[q*64+j], rt);
    }
    v = fmaxf(acc/cnt_s[r] + brel[j] + rt, 0.0f);
    XN[(size_t)i*64 + j] = v;
  }
  __syncthreads();
  agg_s[r][j] = v;
  __syncthreads();
  if (r == 0) atomicAdd(&meanacc[j], (agg_s[0][j]+agg_s[1][j]+agg_s[2][j]+agg_s[3][j])*inv_n);
}

// pool0: xq = segmax gather (incl self) then @pW+pb
__global__ __launch_bounds__(256) void k_xqmaxq(
    const float* __restrict__ X,const int* __restrict__ offD,const int* __restrict__ rowD,
    const float* __restrict__ pWp,const float* __restrict__ pbp,
    float* __restrict__ XQ2,int n)
{
  __shared__ float xq[4][65];
  const int tid = threadIdx.x;
  const int r = tid>>6, j = tid&63;
  const int i = blockIdx.x*4 + r;
  float v = -3.0e38f;
  if (i < n){
    int p0 = offD[i], p1 = offD[i+1];
    for(int p=p0;p<p1;p++) v = fmaxf(v, X[(size_t)rowD[p]*64 + j]);
  }
  xq[r][j] = v;
  __syncthreads();
  if (i < n){
    float s = pbp[j];
    for(int q=0;q<64;q++) s = fmaf(xq[r][q], pWp[q*64+j], s);
    XQ2[(size_t)i*64+j] = s;
  }
}

__global__ void k_edge_score(const int* __restrict__ src,const int* __restrict__ dst,
                             const float* __restrict__ XQ2,const float* __restrict__ X,
                             float* sE,int E,int n){
  int e = blockIdx.x*256+threadIdx.x; if(e>=E+n) return;
  int s,d; edge_sd(e,src,dst,E,s,d);
  const float* q = XQ2 + (size_t)d*64;
  const float* x = X + (size_t)s*64;
  float acc = 0.0f;
  for(int h=0;h<64;h++) acc = fmaf(q[h], x[h], acc);
  sE[e] = acc > 0.0f ? acc : 0.2f*acc;
}

// per-dst softmax over in-edges -> scE; also emits Mt[p] = {rowD[p]*kk, bits(scE)}
// (fused former k_prep2 — values identical, one launch saved).
__global__ void k_dstsoft(const int* __restrict__ offD,const int* __restrict__ eidD,
                          const int* __restrict__ rowD,
                          const float* __restrict__ sE,float* __restrict__ scE,
                          int2* __restrict__ Mt,int kk,int n){
  int i = blockIdx.x*256+threadIdx.x; if(i>=n) return;
  int p0 = offD[i], p1 = offD[i+1];
  float m = -3.0e38f;
  for(int p=p0;p<p1;p++) m = fmaxf(m, sE[eidD[p]]);
  float d = 0.0f;
  for(int p=p0;p<p1;p++) d += expf(sE[eidD[p]]-m);
  float inv = 1.0f/d;
  for(int p=p0;p<p1;p++){
    int e = eidD[p];
    float v = expf(sE[e]-m)*inv;
    scE[e] = v;
    Mt[p] = make_int2(rowD[p]*kk, __float_as_int(v));
  }
}

// pool0: xc gather + aN/bN/cN; zeroes pcnt
__global__ __launch_bounds__(256) void k_xcabc0(
    const int* __restrict__ offD,const int* __restrict__ rowD,const int* __restrict__ eidD,
    const float* __restrict__ scE,const float* __restrict__ X,
    float* __restrict__ XC,
    const float* __restrict__ w1,const float* bb1,const float* __restrict__ w2,
    const float* __restrict__ w3,const float* bb3,
    float* aN,float* bN,float* cN,int* pcnt,int n)
{
  __shared__ float xc[4][65];
  const int tid = threadIdx.x;
  const int r = tid>>6, j = tid&63;
  const int i = blockIdx.x*4 + r;
  if (blockIdx.x==0 && tid==0) *pcnt = 0;
  float v = 0.0f;
  if (i < n){
    int p0 = offD[i], p1 = offD[i+1];
    for(int p=p0;p<p1;p++) v += scE[eidD[p]] * X[(size_t)rowD[p]*64 + j];
    XC[(size_t)i*64+j] = v;
  }
  xc[r][j] = v;
  __syncthreads();
  if (i < n && j < 3){
    float s = (j==0)?bb1[0]:((j==2)?bb3[0]:0.0f);
    const float* w = (j==0)?w1:((j==1)?w2:w3);
    for(int q=0;q<64;q++) s = fmaf(xc[r][q], w[q], s);
    if(j==0) aN[i]=s; else if(j==1) bN[i]=s; else cN[i]=s;
  }
}

// pool0 fit + zero rank + ipos=-1 (fused former k_fillm1)
__global__ void k_aggfit0(const int* __restrict__ offD,const int* __restrict__ rowD,
                          const float* aN,const float* bN,const float* cN,
                          float* fit,int* __restrict__ rank,int* __restrict__ ipos,int n){
  int i = blockIdx.x*256+threadIdx.x; if(i>=n) return;
  int p0 = offD[i], p1 = offD[i+1];
  float s = 0.0f;
  for(int p=p0;p<p1;p++) s += aN[rowD[p]];
  fit[i] = sigm(s - (float)(p1-p0)*bN[i] + cN[i]);
  rank[i] = 0;
  ipos[i] = -1;
}

// R column-permuted at write time: Rp[i][ipos[c]] += scE  (only kept columns).
__global__ void k_stage1p(const int* src,const int* dst,const int* __restrict__ offS,
                          const int* __restrict__ colS,const int* __restrict__ eidS,
                          const float* __restrict__ scE,const int* __restrict__ ipos,
                          float* Rp,int E,int n,int kk){
  int e = blockIdx.x*256+threadIdx.x; if(e>=E+n) return;
  int i,j; edge_sd(e,src,dst,E,i,j);
  int p0 = offS[j], p1 = offS[j+1];
  float* Ri = Rp + (size_t)i*kk;
  for(int p=p0;p<p1;p++){
    int ip = ipos[colS[p]];
    if (ip >= 0) atomicAdd(&Ri[ip], scE[eidS[p]]);
  }
}
// A_new[u][v] = sum over in-edges of perm[u]: scE * Rp[row][v].
// XCD-sliced (confirmed R2: FETCH 43.6->5.9 MB) + Mt-fused unroll-4 (R3).
__global__ __launch_bounds__(256) void k_stage2x(
    const int* __restrict__ perm,const int* __restrict__ offD,
    const int2* __restrict__ Mt,
    const float* __restrict__ Rp,float* A,int k,int vw,int cbn){
  const int bid = blockIdx.x;
  const int slice = bid & 7;
  const int rest = bid >> 3;
  const int cb = rest % cbn;
  const int ub = rest / cbn;
  const int u = ub*4 + (threadIdx.x>>6);
  if (u >= k) return;
  const int vbase = slice*vw;
  int vend = vbase + vw; if (vend > k) vend = k;
  const int v = vbase + cb*64 + (threadIdx.x&63);
  const bool vok = v < vend;
  const int vs = vok ? v : vbase;
  const int d = perm[u];
  float acc = 0.0f;
  int p = offD[d];
  const int p1 = offD[d+1];
  for(; p+4 <= p1; p += 4){
    const int2 m0 = Mt[p];
    const int2 m1 = Mt[p+1];
    const int2 m2 = Mt[p+2];
    const int2 m3 = Mt[p+3];
    const float r0 = Rp[m0.x + vs];
    const float r1 = Rp[m1.x + vs];
    const float r2 = Rp[m2.x + vs];
    const float r3 = Rp[m3.x + vs];
    acc = fmaf(__int_as_float(m0.y), r0, acc);
    acc = fmaf(__int_as_float(m1.y), r1, acc);
    acc = fmaf(__int_as_float(m2.y), r2, acc);
    acc = fmaf(__int_as_float(m3.y), r3, acc);
  }
  for(; p < p1; ++p){
    const int2 m = Mt[p];
    acc = fmaf(__int_as_float(m.y), Rp[m.x + vs], acc);
  }
  if (vok) A[(size_t)u*k + v] = (u==v) ? 0.0f : acc;
}

__global__ void k_head2(const float* __restrict__ xs,const float* __restrict__ W1,
                        const float* __restrict__ b1,const float* __restrict__ W2,
                        const float* __restrict__ b2,float* out){
  __shared__ float h2[64];
  __shared__ float lg[10];
  int t = threadIdx.x;
  float s = b1[t];
  for(int q=0;q<640;q++) s = fmaf(xs[q], W1[q*64+t], s);
  h2[t] = fmaxf(s, 0.0f);
  __syncthreads();
  if(t < 10){
    float s2 = b2[t];
    for(int k=0;k<64;k++) s2 = fmaf(h2[k], W2[k*10+t], s2);
    lg[t] = s2;
  }
  __syncthreads();
  if(t == 0){
    float mx = lg[0];
    for(int i=1;i<10;i++) mx = fmaxf(mx, lg[i]);
    float se = 0.0f;
    for(int i=0;i<10;i++) se += expf(lg[i]-mx);
    float lse = mx + logf(se);
    for(int i=0;i<10;i++) out[i] = lg[i]-lse;
  }
}

// ---------------- host orchestration ----------------
extern "C" void kernel_launch(void* const* d_in, const int* in_sizes, int n_in,
                              void* d_out, int out_size, void* d_ws, size_t ws_size,
                              hipStream_t stream) {
  const int N0 = 1500, E = 24000, Z = 16, L = E + N0;
  const float* x0   = (const float*)d_in[0];
  const int* esrc   = (const int*)d_in[1];
  const int* edst   = (const int*)d_in[2];
  const float* W1   = (const float*)d_in[3];  const float* b1   = (const float*)d_in[4];
  const float* W2   = (const float*)d_in[5];  const float* b2   = (const float*)d_in[6];
  const float* W3   = (const float*)d_in[7];  const float* b3   = (const float*)d_in[8];
  const float* Wrel = (const float*)d_in[9];  const float* brel = (const float*)d_in[10];
  const float* Wroot= (const float*)d_in[11];
  const float* pW   = (const float*)d_in[12]; const float* pb   = (const float*)d_in[13];
  const float* leW1 = (const float*)d_in[14]; const float* leb1 = (const float*)d_in[15];
  const float* leW2 = (const float*)d_in[16]; const float* leW3 = (const float*)d_in[17];
  const float* leb3 = (const float*)d_in[18];
  const float* linW1= (const float*)d_in[19]; const float* linb1= (const float*)d_in[20];
  const float* linW2= (const float*)d_in[21]; const float* linb2= (const float*)d_in[22];
  float* out = (float*)d_out;

  float* ws = (float*)d_ws;
  size_t cur = 0;
  auto allocF = [&](size_t nf)->float*{ float* p = ws + cur; cur += (nf + 15) & ~(size_t)15; return p; };
  // contiguous zero block: xs | indeg | outdeg
  float* xs   = allocF(640);
  int* indeg  = (int*)allocF(1504);
  int* outdeg = (int*)allocF(1504);
  float* Xa  = allocF(96000); float* Xb  = allocF(96000); float* Y   = allocF(96000);
  float* XQ2 = allocF(96000); float* XC  = allocF(96000);
  float* mcol = allocF(1504); float* invd = allocF(1504);
  float* aN = allocF(1504); float* bN = allocF(1504); float* cN = allocF(1504);
  float* fit = allocF(1504); float* cntP = allocF(1504);
  int* pcnt = (int*)allocF(16);
  int* perm = (int*)allocF(1504);
  int* offD = (int*)allocF(1504); int* offS = (int*)allocF(1504);
  int* curD = (int*)allocF(1504); int* curS = (int*)allocF(1504);
  int* colS = (int*)allocF(25504); int* eidS = (int*)allocF(25504);
  int* rowD = (int*)allocF(25504); int* eidD = (int*)allocF(25504);
  float* sE = allocF(25504); float* scE = allocF(25504);
  int2* Mt  = (int2*)allocF(51008);
  int* cntp8 = (int*)allocF((size_t)Z*1504);
  float* aggp = allocF(16*1504);
  float* SEGP = allocF((size_t)Z*1504*64);
  float* Rbig = allocF((size_t)1500*1500);   // pool0 Rp; aliased as split-K slab 0 + SCb
  float* SCb  = Rbig;
  float* A0  = allocF((size_t)1350*1350);
  float* A1s = allocF((size_t)1350*1350);
  const size_t SLAB = 1650048;               // >= 1350*1215
  float* PS2 = allocF(SLAB);
  float* PS3 = allocF(SLAB);
  const size_t BFSZ = (size_t)1350*4224/2 + 32;
  ushort* Abf = (ushort*)allocF(BFSZ);
  ushort* Bbf = (ushort*)allocF(BFSZ);
  ushort* Cbf = (ushort*)allocF(BFSZ);
  ushort* Dbf = (ushort*)allocF(BFSZ);
  int* rankb = indeg;                        // dead after k_prefix2

  dim3 B256(256);
  auto G1 = [&](size_t n){ return dim3((unsigned)((n + 255) / 256)); };
  auto ZF = [&](void* p, size_t nfloats){ k_zero<<<G1(nfloats),B256,0,stream>>>((float*)p, nfloats); };
  auto kcz = [&](int K){ return (int)(((K + Z*16 - 1) / (Z*16)) * 16); };

  // ---- prologue: zero (xs+indeg+outdeg contiguous), degrees, CSR ----
  ZF(xs, 640 + 1504 + 1504);
  k_deg<<<G1(E),B256,0,stream>>>(esrc, edst, indeg, outdeg, E);
  k_prefix2<<<dim3((N0+256)/256,2),B256,0,stream>>>(indeg, outdeg, offD, curD, offS, curS, N0);
  k_csr_fill2<<<G1(L),B256,0,stream>>>(esrc, edst, curS, colS, eidS, curD, rowD, eidD, E, N0);

  // ---- FEAST x3 (2 nodes each) ----
  auto feast = [&](const float* xin,int cin,const float* W,const float* bb,int hh,float* xout,float* macc){
    k_mm_small<<<G1((size_t)N0*hh),B256,0,stream>>>(xin, W, nullptr, Y, N0, cin, hh, 0);
    k_feast_gf<<<G1((size_t)N0*hh),B256,0,stream>>>(Y, offD, rowD, bb, xout, N0, hh, macc, 1.0f/N0);
  };
  feast(x0, 16, W1, b1, 32, Xa, nullptr);
  feast(Xa, 32, W2, b2, 64, Xb, nullptr);
  feast(Xb, 64, W3, b3, 64, Xa, xs + 0);
  float* X = Xa; float* XN = Xb;

  // ---- i=0 gconv_sparse (1 node) ----
  k_gconv_sparse_f<<<dim3((N0+3)/4),B256,0,stream>>>(X, offD, rowD, eidD, E, Wrel, brel, Wroot,
                                                     XN, N0, xs + 64, 1.0f/N0);
  { float* t = X; X = XN; XN = t; }

  // ---- pool 0 (sparse ASAP), n=1500 -> k=1350 ----
  {
    const int n = 1500, kk = 1350;
    int* ipos = curD;   // dead after CSR build
    k_xqmaxq<<<dim3((n+3)/4),B256,0,stream>>>(X, offD, rowD, pW, pb, XQ2, n);
    k_edge_score<<<G1(L),B256,0,stream>>>(esrc, edst, XQ2, X, sE, E, n);
    k_dstsoft<<<G1(n),B256,0,stream>>>(offD, eidD, rowD, sE, scE, Mt, kk, n);
    k_xcabc0<<<dim3((n+3)/4),B256,0,stream>>>(offD, rowD, eidD, scE, X, XC,
                                              leW1, leb1, leW2, leW3, leb3, aN, bN, cN, pcnt, n);
    k_aggfit0<<<G1(n),B256,0,stream>>>(offD, rowD, aN, bN, cN, fit, rankb, ipos, n);
    k_rank_cnt<<<dim3((n+255)/256,(n+127)/128),B256,0,stream>>>(fit, rankb, n);
    k_rank_sel<<<dim3((n+3)/4),B256,0,stream>>>(rankb, fit, XC, XN, n, kk, pcnt, perm, ipos);
    ZF(Rbig, (size_t)n*kk);
    k_stage1p<<<G1(L),B256,0,stream>>>(esrc, edst, offS, colS, eidS, scE, ipos, Rbig, E, n, kk);
    {
      const int vw = (kk + 7) / 8;          // 169
      const int cbn = (vw + 63) / 64;       // 3
      const int ubn = (kk + 3) / 4;         // 338
      k_stage2x<<<dim3((unsigned)(8*cbn*ubn)),B256,0,stream>>>(perm, offD, Mt,
                                                               Rbig, A0, kk, vw, cbn);
    }
    { float* t = X; X = XN; XN = t; }
  }

  float* Acur = A0; float* Aoth = A1s;
  int nn = 1350;

  // ---- dense gconv (2 nodes) ----
  auto gconv_dense = [&](int layer){
    dim3 g(1, (nn+63)/64, Z);
    k_skinny<false,true,false,false><<<g,B256,0,stream>>>(Acur, nn, X, nullptr, SEGP, cntp8, nn, nn, kcz(nn));
    k_gconv_fuse<<<dim3((nn+3)/4),B256,0,stream>>>(SEGP, cntp8, Z,
        Wrel + (size_t)layer*4096, brel + layer*64, X, Wroot + (size_t)layer*4096,
        XN, nn, xs + (size_t)(layer+1)*64, 1.0f/nn);
    { float* t = X; X = XN; XN = t; }
  };

  // ---- dense ASAP pool ----
  auto asap_dense = [&](int kk, int p){
    {
      dim3 g(1, (nn+63)/64, Z);
      k_skinny<true,true,false,true><<<g,B256,0,stream>>>(Acur, nn, X, nullptr, SEGP, cntp8, nn, nn, kcz(nn));
    }
    k_poolq<<<dim3((nn+3)/4),B256,0,stream>>>(SEGP, cntp8, Z, pW + (size_t)p*4096, pb + p*64,
                                              X, Abf, Bbf, cntP, nn);
    {
      dim3 g((nn+63)/64, (nn+63)/64);
      k_gemm_mfma<1><<<g,B256,0,stream>>>(Abf, Bbf, SCb, nn, nn, nn, 192, Acur, nn);
    }
    k_smax_fused<<<dim3((nn+15)/16),B256,0,stream>>>(SCb, nn, mcol, invd);
    {
      dim3 g(1, (nn+63)/64, Z);
      k_skinny<false,false,true,false><<<g,B256,0,stream>>>(SCb, nn, X, mcol, SEGP, nullptr, nn, nn, kcz(nn));
    }
    k_xcabc_dense<<<dim3((nn+3)/4),B256,0,stream>>>(SEGP, Z, invd, XC,
        leW1 + p*64, leb1 + p, leW2 + p*64, leW3 + p*64, leb3 + p, aN, bN, cN, pcnt, nn);
    k_aggcol<<<G1((size_t)nn*16),B256,0,stream>>>(Acur, aN, aggp, nn);
    k_fit_dense<<<G1(nn),B256,0,stream>>>(aggp, cntP, aN, bN, cN, fit, rankb, pcnt, nn);
    k_rank_cnt<<<dim3((nn+255)/256,(nn+127)/128),B256,0,stream>>>(fit, rankb, nn);
    k_rank_sel<<<dim3((nn+3)/4),B256,0,stream>>>(rankb, fit, XC, XN, nn, kk, pcnt, perm, nullptr);
    const int Kp = (nn + 63) & ~63;
    const int K3 = 3*Kp;
    k_split3<<<G1((size_t)nn*Kp),B256,0,stream>>>(Acur, nn, nn, nn, Abf, Kp, 0);
    { dim3 gt((kk+31)/32, Kp/32);
      k_split3_Tdual<<<gt,B256,0,stream>>>(SCb, nn, kk, nn, perm, invd, mcol, Dbf, Bbf, Cbf, Kp); }
    // ---- TB = A@Sp + Sp : split-K x4 (128x128 tiles, K-step 32, XCD swizzle) ----
    const int Tk = K3 >> 6;
    const int kchunk = ((Tk + 3) >> 2) << 6;
    {
      dim3 g((kk+127)/128, (nn+127)/128, 4);
      k_gemm_pp<<<g,B256,0,stream>>>(Abf, Bbf, Rbig, Aoth, PS2, PS3, kk, nn, kk, K3, kchunk);
      dim3 gr((kk+31)/32, (nn+31)/32);
      k_red_tb<<<gr,B256,0,stream>>>(Rbig, Aoth, PS2, PS3, kk, Bbf, Cbf, nn, kk, Kp);
    }
    // ---- A_new = Sp^T @ TB (zero diag): split-K x4 (output Aoth aliases slab 1: safe) ----
    {
      dim3 g((kk+127)/128, (kk+127)/128, 4);
      k_gemm_pp<<<g,B256,0,stream>>>(Dbf, Cbf, Rbig, Aoth, PS2, PS3, kk, kk, kk, K3, kchunk);
      k_red_diag<<<G1((size_t)kk*kk),B256,0,stream>>>(Rbig, Aoth, PS2, PS3, Aoth, kk);
    }
    { float* t = X; X = XN; XN = t; }
    { float* t = Acur; Acur = Aoth; Aoth = t; }
    nn = kk;
  };

  gconv_dense(1);
  gconv_dense(2);
  asap_dense(1215, 1);
  gconv_dense(3);
  gconv_dense(4);
  asap_dense(1094, 2);
  gconv_dense(5);
  gconv_dense(6);
  asap_dense(985, 3);
  gconv_dense(7);
  gconv_dense(8);

  // ---- head (1 node) ----
  k_head2<<<1,64,0,stream>>>(xs, linW1, linb1, linW2, linb2, out);
}

// Round 9
// 1346.786 us; speedup vs baseline: 1.0143x; 1.0143x over previous
//
#include <hip/hip_runtime.h>
#include <math.h>

#define NEGV -1000000000.0f

typedef short short8 __attribute__((ext_vector_type(8)));
typedef float floatx4 __attribute__((ext_vector_type(4)));

__device__ __forceinline__ float sigm(float x){ return 1.0f/(1.0f+expf(-x)); }
__device__ __forceinline__ void edge_sd(int e,const int* src,const int* dst,int E,int& s,int& d){
  if(e<E){ s=src[e]; d=dst[e]; } else { s=e-E; d=s; }
}
__device__ __forceinline__ ushort bf16rn(float x){
  unsigned u = __float_as_uint(x);
  unsigned r = (u + 0x7fffu + ((u>>16)&1u)) >> 16;
  return (ushort)r;
}
__device__ __forceinline__ float bf16f(ushort h){ return __uint_as_float(((unsigned)h)<<16); }

__global__ void k_zero(float* __restrict__ p, size_t n){
  size_t i = (size_t)blockIdx.x*256 + threadIdx.x;
  if (i < n) p[i] = 0.0f;
}

// ---------------- bf16x3 conversions ----------------
__global__ void k_split3(const float* __restrict__ src,int R,int Cs,int ld,
                         ushort* __restrict__ dst,int Cp,int bmode){
  int idx = blockIdx.x*256+threadIdx.x;
  if (idx >= R*Cp) return;
  int r = idx / Cp, c = idx - r*Cp;
  float x = (c < Cs) ? src[(size_t)r*ld + c] : 0.0f;
  ushort h = bf16rn(x);
  ushort l = bf16rn(x - bf16f(h));
  size_t base = (size_t)r*(3*Cp) + c;
  dst[base]        = h;
  dst[base + Cp]   = bmode ? l : h;
  dst[base + 2*Cp] = bmode ? h : l;
}
// Sp = exp(src[:,perm]-mcol[perm])*invd[perm], transposed to K-innermost; writes BOTH
// A-role (dstA) and B-role (dstB); zero-pads k>=Rs rows in dstA/dstB AND dstCpad.
__global__ void k_split3_Tdual(const float* __restrict__ src,int Rs,int Cs,int ld,
                               const int* __restrict__ gperm,const float* __restrict__ cscale,
                               const float* __restrict__ emax,
                               ushort* __restrict__ dstA,ushort* __restrict__ dstB,
                               ushort* __restrict__ dstCpad,int Kp){
  __shared__ float t[32][33];
  int tx = threadIdx.x & 31, ty = threadIdx.x >> 5;
  int kb = blockIdx.y*32, xb = blockIdx.x*32;
  int x = xb + tx;
  int gx = (x < Cs) ? gperm[x] : 0;
#pragma unroll
  for (int i=0;i<4;i++){
    int k = kb + ty + i*8;
    t[ty+i*8][tx] = (k < Rs && x < Cs) ? src[(size_t)k*ld + gx] : 0.0f;
  }
  __syncthreads();
  const int K3 = 3*Kp;
#pragma unroll
  for (int i=0;i<4;i++){
    int xo = xb + ty + i*8, ko = kb + tx;
    if (xo < Cs){
      float v = 0.0f;
      if (ko < Rs){
        int g = gperm[xo];
        v = expf(t[tx][ty+i*8] - emax[g]) * cscale[g];
      }
      ushort h = bf16rn(v);
      ushort l = bf16rn(v - bf16f(h));
      size_t base = (size_t)xo*K3 + ko;
      dstA[base] = h; dstA[base+Kp] = h; dstA[base+2*Kp] = l;
      dstB[base] = h; dstB[base+Kp] = l; dstB[base+2*Kp] = h;
      if (ko >= Rs){ dstCpad[base]=0; dstCpad[base+Kp]=0; dstCpad[base+2*Kp]=0; }
    }
  }
}

// ---------------- MFMA bf16 GEMM (64x64 tile, K-step 64, double-buffered) ----------------
// EPI 1: mask(A+I)+leakyrelu.  (Used for the score GEMM, K3=192.)
template<int EPI>
__global__ __launch_bounds__(256) void k_gemm_mfma(
    const ushort* __restrict__ A, const ushort* __restrict__ B,
    float* __restrict__ C, int ldc, int M, int N, int K3,
    const float* __restrict__ mask, int ldm)
{
  __shared__ ushort As[2][64][72];
  __shared__ ushort Bs[2][64][72];
  const int tid = threadIdx.x;
  const int m0 = blockIdx.y*64, n0 = blockIdx.x*64;
  const int w = tid>>6, lane = tid&63;
  const int lo4 = lane&15, quad = lane>>4;
  const int sr = tid>>2, sseg = tid&3;

  floatx4 acc[4];
#pragma unroll
  for(int c=0;c<4;c++){ acc[c][0]=0.f; acc[c][1]=0.f; acc[c][2]=0.f; acc[c][3]=0.f; }

  const size_t arow = (size_t)(m0+sr)*K3;
  const size_t brow = (size_t)(n0+sr)*K3;
  const bool aval = (m0+sr) < M;
  const bool bval = (n0+sr) < N;

  uint4 av0 = make_uint4(0,0,0,0), av1 = make_uint4(0,0,0,0);
  uint4 bv0 = make_uint4(0,0,0,0), bv1 = make_uint4(0,0,0,0);
  if (aval){ av0 = *(const uint4*)(A + arow + sseg*8);
             av1 = *(const uint4*)(A + arow + 32 + sseg*8); }
  if (bval){ bv0 = *(const uint4*)(B + brow + sseg*8);
             bv1 = *(const uint4*)(B + brow + 32 + sseg*8); }
  *(uint4*)&As[0][sr][sseg*8] = av0; *(uint4*)&As[0][sr][32+sseg*8] = av1;
  *(uint4*)&Bs[0][sr][sseg*8] = bv0; *(uint4*)&Bs[0][sr][32+sseg*8] = bv1;
  __syncthreads();

  const int T = K3 >> 6;
  for (int i=0;i<T;i++){
    const int cb = i & 1;
    if (i+1 < T){
      const int k0 = (i+1)<<6;
      av0 = make_uint4(0,0,0,0); av1 = make_uint4(0,0,0,0);
      bv0 = make_uint4(0,0,0,0); bv1 = make_uint4(0,0,0,0);
      if (aval){ av0 = *(const uint4*)(A + arow + k0 + sseg*8);
                 av1 = *(const uint4*)(A + arow + k0 + 32 + sseg*8); }
      if (bval){ bv0 = *(const uint4*)(B + brow + k0 + sseg*8);
                 bv1 = *(const uint4*)(B + brow + k0 + 32 + sseg*8); }
    }
    short8 af0 = *(const short8*)&As[cb][16*w + lo4][quad*8];
    short8 af1 = *(const short8*)&As[cb][16*w + lo4][32+quad*8];
#pragma unroll
    for (int c=0;c<4;c++){
      short8 bf0 = *(const short8*)&Bs[cb][16*c + lo4][quad*8];
      acc[c] = __builtin_amdgcn_mfma_f32_16x16x32_bf16(af0, bf0, acc[c], 0, 0, 0);
      short8 bf1 = *(const short8*)&Bs[cb][16*c + lo4][32+quad*8];
      acc[c] = __builtin_amdgcn_mfma_f32_16x16x32_bf16(af1, bf1, acc[c], 0, 0, 0);
    }
    if (i+1 < T){
      __syncthreads();
      *(uint4*)&As[1-cb][sr][sseg*8] = av0; *(uint4*)&As[1-cb][sr][32+sseg*8] = av1;
      *(uint4*)&Bs[1-cb][sr][sseg*8] = bv0; *(uint4*)&Bs[1-cb][sr][32+sseg*8] = bv1;
      __syncthreads();
    }
  }

#pragma unroll
  for (int c=0;c<4;c++){
    const int gn = n0 + 16*c + lo4;
#pragma unroll
    for (int r=0;r<4;r++){
      const int gm = m0 + 16*w + quad*4 + r;
      if (gm < M && gn < N){
        float v = acc[c][r];
        if (EPI==1) v = (mask[(size_t)gm*ldm+gn] != 0.0f || gm==gn) ? (v > 0.0f ? v : 0.2f*v) : NEGV;
        C[(size_t)gm*ldc+gn] = v;
      }
    }
  }
}

// ---------------- split-K x4 MFMA partial-product GEMM, 128x128 tile ----------------
// R8: REVERT to the R6 configuration (K-step 64, measured best 1347.5us).
// R7's K-step-32 (4 blocks/CU) regressed: doubled barrier count outweighed TLP.
// 4 waves, each owns a 64x64 output quadrant (4x4 16x16 fragments).
// XCD-chunked bijective swizzle retained. blockIdx.z selects a K-chunk.
// K accumulation order per output element unchanged -> bit-identical results.
__global__ __launch_bounds__(256) void k_gemm_pp(
    const ushort* __restrict__ A, const ushort* __restrict__ B,
    float* __restrict__ P0, float* __restrict__ P1,
    float* __restrict__ P2, float* __restrict__ P3, int ldp,
    int M, int N, int K3, int kchunk)
{
  __shared__ ushort As[2][128][72];
  __shared__ ushort Bs[2][128][72];
  const int tid = threadIdx.x;

  // ---- XCD-chunked bijective block remap ----
  const int gx = gridDim.x, gxy = gridDim.x*gridDim.y;
  const int TT = gxy*gridDim.z;
  const int s  = blockIdx.x + gx*blockIdx.y + gxy*blockIdx.z;
  const int c8 = s & 7, u = s >> 3;
  const int q = TT >> 3, r8 = TT & 7;
  const int w0 = (c8 < r8) ? c8*(q+1) + u : r8*(q+1) + (c8 - r8)*q + u;
  const int z  = w0 / gxy;
  const int lin = w0 - z*gxy;
  const int ty = lin / gx, tx = lin - ty*gx;

  const int m0 = ty*128, n0 = tx*128;
  const int w = tid>>6, lane = tid&63;
  const int lo4 = lane&15, quad = lane>>4;
  const int wr = w>>1, wc = w&1;

  // staging: thread t -> row t>>1, half t&1 (32 ushort = 4x uint4 per operand)
  const int srow = tid>>1, shalf = tid&1;

  float* __restrict__ P = (z==0) ? P0 : (z==1) ? P1 : (z==2) ? P2 : P3;
  const int kbeg = z * kchunk;
  int klen = K3 - kbeg; if (klen > kchunk) klen = kchunk; if (klen < 0) klen = 0;
  const int T = klen >> 6;

  floatx4 acc[4][4];
#pragma unroll
  for(int i=0;i<4;i++)
#pragma unroll
    for(int c=0;c<4;c++){ acc[i][c][0]=0.f; acc[i][c][1]=0.f; acc[i][c][2]=0.f; acc[i][c][3]=0.f; }

  const size_t arow = (size_t)(m0+srow)*K3 + kbeg + shalf*32;
  const size_t brow = (size_t)(n0+srow)*K3 + kbeg + shalf*32;
  const bool aval = (m0+srow) < M;
  const bool bval = (n0+srow) < N;
  const int sbase = shalf*32;

  uint4 apre[4], bpre[4];
#pragma unroll
  for(int s2=0;s2<4;s2++){ apre[s2]=make_uint4(0,0,0,0); bpre[s2]=make_uint4(0,0,0,0); }
  if (aval){
#pragma unroll
    for(int s2=0;s2<4;s2++) apre[s2] = *(const uint4*)(A + arow + s2*8);
  }
  if (bval){
#pragma unroll
    for(int s2=0;s2<4;s2++) bpre[s2] = *(const uint4*)(B + brow + s2*8);
  }
#pragma unroll
  for(int s2=0;s2<4;s2++){
    *(uint4*)&As[0][srow][sbase + s2*8] = apre[s2];
    *(uint4*)&Bs[0][srow][sbase + s2*8] = bpre[s2];
  }
  __syncthreads();

  for (int it=0; it<T; ++it){
    const int cb = it & 1;
    if (it+1 < T){
      const int k0 = (it+1)<<6;
#pragma unroll
      for(int s2=0;s2<4;s2++){ apre[s2]=make_uint4(0,0,0,0); bpre[s2]=make_uint4(0,0,0,0); }
      if (aval){
#pragma unroll
        for(int s2=0;s2<4;s2++) apre[s2] = *(const uint4*)(A + arow + k0 + s2*8);
      }
      if (bval){
#pragma unroll
        for(int s2=0;s2<4;s2++) bpre[s2] = *(const uint4*)(B + brow + k0 + s2*8);
      }
    }
    short8 af[4][2];
#pragma unroll
    for(int i=0;i<4;i++){
      af[i][0] = *(const short8*)&As[cb][wr*64 + 16*i + lo4][quad*8];
      af[i][1] = *(const short8*)&As[cb][wr*64 + 16*i + lo4][32 + quad*8];
    }
#pragma unroll
    for(int c=0;c<4;c++){
      short8 bf0 = *(const short8*)&Bs[cb][wc*64 + 16*c + lo4][quad*8];
      short8 bf1 = *(const short8*)&Bs[cb][wc*64 + 16*c + lo4][32 + quad*8];
#pragma unroll
      for(int i=0;i<4;i++){
        acc[i][c] = __builtin_amdgcn_mfma_f32_16x16x32_bf16(af[i][0], bf0, acc[i][c], 0, 0, 0);
        acc[i][c] = __builtin_amdgcn_mfma_f32_16x16x32_bf16(af[i][1], bf1, acc[i][c], 0, 0, 0);
      }
    }
    if (it+1 < T){
      __syncthreads();
#pragma unroll
      for(int s2=0;s2<4;s2++){
        *(uint4*)&As[1-cb][srow][sbase + s2*8] = apre[s2];
        *(uint4*)&Bs[1-cb][srow][sbase + s2*8] = bpre[s2];
      }
      __syncthreads();
    }
  }

#pragma unroll
  for(int c=0;c<4;c++){
    const int gn = n0 + wc*64 + 16*c + lo4;
    if (gn < N){
#pragma unroll
      for(int i=0;i<4;i++){
#pragma unroll
        for(int r=0;r<4;r++){
          const int gm = m0 + wr*64 + 16*i + quad*4 + r;
          if (gm < M) P[(size_t)gm*ldp+gn] = acc[i][c][r];
        }
      }
    }
  }
}

// reduce 4 TB slabs + Sp, transpose-store as bf16x3 B-role (h,l,h) at gn*K3o+gm.
__global__ __launch_bounds__(256) void k_red_tb(
    const float* __restrict__ P0,const float* __restrict__ P1,
    const float* __restrict__ P2,const float* __restrict__ P3,int ldp,
    const ushort* __restrict__ Bb, ushort* __restrict__ Cb,
    int M,int N,int Kp)
{
  __shared__ float t[32][33];
  const int tx = threadIdx.x & 31, ty = threadIdx.x >> 5;
  const int mb = blockIdx.y*32, nb = blockIdx.x*32;
  const int n = nb + tx;
#pragma unroll
  for (int i=0;i<4;i++){
    int m = mb + ty + i*8;
    float v = 0.0f;
    if (m < M && n < N){
      size_t o = (size_t)m*ldp + n;
      v = (P0[o] + P1[o]) + (P2[o] + P3[o]);
    }
    t[ty+i*8][tx] = v;
  }
  __syncthreads();
  const int K3o = 3*Kp;
#pragma unroll
  for (int i=0;i<4;i++){
    int no = nb + ty + i*8, mo = mb + tx;
    if (no < N && mo < M){
      size_t base = (size_t)no*K3o + mo;
      float sp = bf16f(Bb[base]) + bf16f(Bb[base+Kp]);
      float v = t[tx][ty+i*8] + sp;
      ushort h = bf16rn(v), l = bf16rn(v - bf16f(h));
      Cb[base] = h; Cb[base+Kp] = l; Cb[base+2*Kp] = h;
    }
  }
}

// reduce 4 A_new slabs + zero diagonal. (C may alias one of the slabs: per-element
// read-then-write, no cross-thread sharing -> safe.)
__global__ void k_red_diag(const float* __restrict__ P0,const float* __restrict__ P1,
                           const float* __restrict__ P2,const float* __restrict__ P3,
                           float* __restrict__ C,int kk){
  int idx = blockIdx.x*256+threadIdx.x;
  if (idx >= kk*kk) return;
  int u = idx/kk, v = idx - u*kk;
  float s = (P0[idx] + P1[idx]) + (P2[idx] + P3[idx]);
  C[idx] = (u==v) ? 0.0f : s;
}

// ---------------- atomic-free skinny agg GEMM ----------------
template<bool MAXM, bool COUNT, bool EXPM, bool SELF>
__global__ __launch_bounds__(256) void k_skinny(
    const float* __restrict__ A, int lda,
    const float* __restrict__ X,
    const float* __restrict__ mcol,
    float* __restrict__ P, int* __restrict__ cntp,
    int M, int K, int kchunk)
{
  __shared__ float As[16][68];
  __shared__ float Xs[16][68];
  const int tid = threadIdx.x;
  const int m0 = blockIdx.y * 64;
  const int tmb = (tid & 15) * 4, tnb = (tid >> 4) * 4;
  float acc[4][4];
  int cacc[4] = {0,0,0,0};
#pragma unroll
  for (int i=0;i<4;i++)
#pragma unroll
    for (int j=0;j<4;j++) acc[i][j] = MAXM ? NEGV : 0.0f;

  const int kstart = blockIdx.z * kchunk;
  int kend = kstart + kchunk; if (kend > K) kend = K;
  const int ml = tid & 63, tb = tid >> 6;
  const bool mvalid = (m0 + ml) < M;
  float mc = 0.0f;
  if (EXPM && mvalid) mc = mcol[m0 + ml];

  for (int k0 = kstart; k0 < kend; k0 += 16) {
#pragma unroll
    for (int s=0;s<4;s++) {
      const int tk = tb + s*4;
      float va = 0.0f, vx = 0.0f;
      if ((k0+tk) < K) {
        if (mvalid){
          va = A[(size_t)(k0+tk)*lda + m0 + ml];
          if (EXPM) va = expf(va - mc);
        }
        vx = X[(size_t)(k0+tk)*64 + ml];
      }
      As[tk][ml] = va;
      Xs[tk][ml] = vx;
    }
    __syncthreads();
#pragma unroll
    for (int kk=0; kk<16; kk++) {
      const float4 a4 = *(const float4*)&As[kk][tmb];
      const float4 b4 = *(const float4*)&Xs[kk][tnb];
      const float av[4] = {a4.x,a4.y,a4.z,a4.w};
      const float bv[4] = {b4.x,b4.y,b4.z,b4.w};
#pragma unroll
      for (int i=0;i<4;i++){
        if (COUNT) cacc[i] += (av[i] != 0.0f) ? 1 : 0;
#pragma unroll
        for (int j=0;j<4;j++) {
          if (MAXM) acc[i][j] = fmaxf(acc[i][j], av[i] != 0.0f ? bv[j] : NEGV);
          else      acc[i][j] = fmaf(av[i], bv[j], acc[i][j]);
        }
      }
    }
    __syncthreads();
  }

  const size_t slab = (size_t)blockIdx.z * M * 64;
#pragma unroll
  for (int i=0;i<4;i++){
    const int m = m0 + tmb + i;
    if (m < M){
#pragma unroll
      for (int j=0;j<4;j++){
        float v = acc[i][j];
        if (SELF) v = fmaxf(v, X[(size_t)m*64 + tnb + j]);
        P[slab + (size_t)m*64 + tnb + j] = v;
      }
    }
  }
  if (COUNT && tnb == 0){
#pragma unroll
    for (int i=0;i<4;i++){
      const int m = m0 + tmb + i;
      if (m < M) cntp[blockIdx.z*M + m] = cacc[i];
    }
  }
}

// slab max-reduce -> xq; xq2 = xq@pW+pb; cntP = 1 + sum counts.
// Also emits bf16x3 operands: dstA (A-role from X), dstB (B-role from xq2).
__global__ __launch_bounds__(256) void k_poolq(
    const float* __restrict__ SEGP,const int* __restrict__ cntp8,int Z,
    const float* __restrict__ pWp,const float* __restrict__ pbp,
    const float* __restrict__ X,
    ushort* __restrict__ dstA,ushort* __restrict__ dstB,
    float* __restrict__ cntP,int n)
{
  __shared__ float xq[4][65];
  const int tid = threadIdx.x;
  const int r = tid>>6, j = tid&63;
  const int i = blockIdx.x*4 + r;
  float v = NEGV;
  if (i < n){
    for(int z=0;z<Z;z++) v = fmaxf(v, SEGP[(size_t)z*n*64 + (size_t)i*64 + j]);
    if (j == 0){
      int c=1; for(int z=0;z<Z;z++) c += cntp8[z*n+i];
      cntP[i] = (float)c;
    }
  }
  xq[r][j] = v;
  __syncthreads();
  if (i < n){
    float s = pbp[j];
    for(int q=0;q<64;q++) s = fmaf(xq[r][q], pWp[q*64+j], s);
    size_t base = (size_t)i*192 + j;
    ushort h = bf16rn(s), l = bf16rn(s - bf16f(h));
    dstB[base] = h; dstB[base+64] = l; dstB[base+128] = h;
    float x = X[(size_t)i*64 + j];
    h = bf16rn(x); l = bf16rn(x - bf16f(h));
    dstA[base] = h; dstA[base+64] = h; dstA[base+128] = l;
  }
}

// fused dense gconv: reduce slabs, two 64x64 matmuls, relu, mean-accumulate.
__global__ __launch_bounds__(256) void k_gconv_fuse(
    const float* __restrict__ SEGP,const int* __restrict__ cntp8,int Z,
    const float* __restrict__ Wrel,const float* __restrict__ brel,
    const float* __restrict__ X,const float* __restrict__ Wroot,
    float* __restrict__ XN,int n,float* __restrict__ meanacc,float inv_n)
{
  __shared__ float agg_s[4][65];
  __shared__ float xrow[4][65];
  __shared__ float cnt_s[4];
  const int tid = threadIdx.x;
  const int r = tid>>6, j = tid&63;
  const int i = blockIdx.x*4 + r;
  float a = 0.0f;
  if (i < n){
    for(int z=0;z<Z;z++) a += SEGP[(size_t)z*n*64 + (size_t)i*64 + j];
    xrow[r][j] = X[(size_t)i*64 + j];
    if (j == 0){
      int c=0; for(int z=0;z<Z;z++) c += cntp8[z*n+i];
      cnt_s[r] = (float)(c>1?c:1);
    }
  }
  agg_s[r][j] = a;
  __syncthreads();
  float v = 0.0f;
  if (i < n){
    float acc=0.0f, rt=0.0f;
    for(int q=0;q<64;q++){
      acc = fmaf(agg_s[r][q], Wrel[q*64+j], acc);
      rt  = fmaf(xrow[r][q],  Wroot[q*64+j], rt);
    }
    v = fmaxf(acc/cnt_s[r] + brel[j] + rt, 0.0f);
    XN[(size_t)i*64 + j] = v;
  }
  __syncthreads();
  agg_s[r][j] = v;
  __syncthreads();
  if (r == 0) atomicAdd(&meanacc[j], (agg_s[0][j]+agg_s[1][j]+agg_s[2][j]+agg_s[3][j])*inv_n);
}

// ---------------- fused column softmax stats (ONE kernel) ----------------
__global__ __launch_bounds__(256) void k_smax_fused(const float* __restrict__ S,int n,
                                                    float* __restrict__ mcol,float* __restrict__ invd){
  __shared__ float red[16][17];
  const int jc = threadIdx.x & 15, rg = threadIdx.x >> 4;
  const int j = blockIdx.x*16 + jc;
  float m = -3.0e38f;
  if (j < n)
    for(int i=rg;i<n;i+=16) m = fmaxf(m, S[(size_t)i*n+j]);
  red[rg][jc] = m;
  __syncthreads();
  for(int s=8;s>0;s>>=1){
    if(rg<s) red[rg][jc] = fmaxf(red[rg][jc], red[rg+s][jc]);
    __syncthreads();
  }
  const float mc = red[0][jc];
  __syncthreads();
  float sum = 0.0f;
  if (j < n)
    for(int i=rg;i<n;i+=16) sum += expf(S[(size_t)i*n+j]-mc);
  red[rg][jc] = sum;
  __syncthreads();
  for(int s=8;s>0;s>>=1){
    if(rg<s) red[rg][jc] += red[rg+s][jc];
    __syncthreads();
  }
  if(rg==0 && j<n){ mcol[j]=mc; invd[j]=1.0f/red[0][jc]; }
}

// slab sum * invd -> XC; then aN/bN/cN per row; zeroes pcnt.
__global__ __launch_bounds__(256) void k_xcabc_dense(
    const float* __restrict__ SEGP,int Z,const float* __restrict__ invd,
    float* __restrict__ XC,
    const float* __restrict__ w1,const float* bb1,const float* __restrict__ w2,
    const float* __restrict__ w3,const float* bb3,
    float* aN,float* bN,float* cN,int* pcnt,int n)
{
  __shared__ float xc[4][65];
  const int tid = threadIdx.x;
  const int r = tid>>6, j = tid&63;
  const int i = blockIdx.x*4 + r;
  if (blockIdx.x==0 && tid==0) *pcnt = 0;
  float v = 0.0f;
  if (i < n){
    for(int z=0;z<Z;z++) v += SEGP[(size_t)z*n*64 + (size_t)i*64 + j];
    v *= invd[i];
    XC[(size_t)i*64+j] = v;
  }
  xc[r][j] = v;
  __syncthreads();
  if (i < n && j < 3){
    float s = (j==0)?bb1[0]:((j==2)?bb3[0]:0.0f);
    const float* w = (j==0)?w1:((j==1)?w2:w3);
    for(int q=0;q<64;q++) s = fmaf(xc[r][q], w[q], s);
    if(j==0) aN[i]=s; else if(j==1) bN[i]=s; else cN[i]=s;
  }
}

__global__ void k_aggcol(const float* __restrict__ A,const float* __restrict__ aN,
                         float* __restrict__ aggp,int n){
  int idx = blockIdx.x*256+threadIdx.x; if(idx>=n*16) return;
  int j = idx % n, c = idx / n;
  int i0 = (int)(((long long)n*c)/16), i1 = (int)(((long long)n*(c+1))/16);
  float s = 0.0f;
  for(int i=i0;i<i1;i++) if(A[(size_t)i*n + j] != 0.0f) s += aN[i];
  aggp[c*n + j] = s;
}

// ---------------- parallel top-k rank ----------------
__global__ void k_fit_dense(const float* __restrict__ aggp,const float* __restrict__ cntP,
                            const float* __restrict__ aN,const float* __restrict__ bN,
                            const float* __restrict__ cN,
                            float* __restrict__ fit,int* __restrict__ rank,int* pcnt,int n){
  int u = blockIdx.x*256+threadIdx.x;
  if (blockIdx.x==0 && threadIdx.x==0) *pcnt = 0;
  if (u >= n) return;
  float a = aN[u];
  for(int c=0;c<16;c++) a += aggp[c*n+u];
  fit[u] = sigm(a - cntP[u]*bN[u] + cN[u]);
  rank[u] = 0;
}
__global__ __launch_bounds__(256) void k_rank_cnt(const float* __restrict__ fit,
                                                  int* __restrict__ rank,int n){
  __shared__ float fsc[128];
  const int u0 = blockIdx.y*128;
  int u1 = u0+128; if (u1 > n) u1 = n;
  const int cl = u1 - u0;
  if ((int)threadIdx.x < cl) fsc[threadIdx.x] = fit[u0+threadIdx.x];
  __syncthreads();
  const int v = blockIdx.x*256+threadIdx.x;
  if (v >= n) return;
  const float fv = fit[v];
  int r = 0;
  for(int t=0;t<cl;t++){
    const float fu = fsc[t];
    const int u = u0+t;
    r += (fu > fv || (fu == fv && u < v)) ? 1 : 0;
  }
  atomicAdd(&rank[v], r);
}
// Selection + coalesced XN write; optionally records inverse perm (ipos[v]=slot).
__global__ __launch_bounds__(256) void k_rank_sel(const int* __restrict__ rank,
    const float* __restrict__ fit,const float* __restrict__ XC,float* __restrict__ XN,
    int n,int k,int* pcnt,int* perm,int* __restrict__ ipos){
  __shared__ int ps[4];
  const int r = threadIdx.x>>6, h = threadIdx.x&63;
  const int v = blockIdx.x*4 + r;
  const bool sel = (v < n) && (rank[v] < k);
  if (h == 0 && sel){
    int p = atomicAdd(pcnt,1);
    ps[r] = p;
    perm[p] = v;
    if (ipos) ipos[v] = p;
  }
  __syncthreads();
  if (sel){
    const int p = ps[r];
    XN[(size_t)p*64 + h] = XC[(size_t)v*64 + h] * fit[v];
  }
}

// ---------------- prologue: degrees + CSR over L=E+n edges (incl self) ----------------
__global__ void k_deg(const int* __restrict__ src,const int* __restrict__ dst,int* indeg,int* outdeg,int E){
  int e = blockIdx.x*256+threadIdx.x; if(e>=E) return;
  atomicAdd(&indeg[dst[e]],1); atomicAdd(&outdeg[src[e]],1);
}
__global__ __launch_bounds__(256) void k_prefix2(const int* __restrict__ indeg,const int* __restrict__ outdeg,
                          int* offD,int* curD,int* offS,int* curS,int n){
  __shared__ int ds[1504];
  const int* dsrc = blockIdx.y ? outdeg : indeg;
  for(int u=threadIdx.x; u<n; u+=256) ds[u] = dsrc[u];
  __syncthreads();
  int t = blockIdx.x*256+threadIdx.x; if(t>n) return;
  int s = 0;
  for(int u=0;u<t;u++) s += ds[u]+1;
  if (blockIdx.y){ offS[t]=s; if(t<n) curS[t]=s; }
  else           { offD[t]=s; if(t<n) curD[t]=s; }
}
__global__ void k_csr_fill2(const int* src,const int* dst,
                            int* curS,int* colS,int* eidS,
                            int* curD,int* rowD,int* eidD,int E,int n){
  int e = blockIdx.x*256+threadIdx.x; if(e>=E+n) return;
  int s,d; edge_sd(e,src,dst,E,s,d);
  int p = atomicAdd(&curS[s],1); colS[p]=d; eidS[p]=e;
  int q = atomicAdd(&curD[d],1); rowD[q]=s; eidD[q]=e;
}

__global__ void k_mm_small(const float* __restrict__ A,const float* __restrict__ W,
                           const float* __restrict__ b,float* __restrict__ C,
                           int M,int K,int Np,int act){
  int idx = blockIdx.x*256+threadIdx.x; if(idx>=M*Np) return;
  int m = idx/Np, j = idx - m*Np;
  float s = b ? b[j] : 0.0f;
  const float* a = A + (size_t)m*K;
  for(int q=0;q<K;q++) s = fmaf(a[q], W[(size_t)q*Np + j], s);
  if(act==1) s = fmaxf(s, 0.0f);
  C[idx] = s;
}

// feast: gather-mean over in-edges (incl self), +b, elu; optional mean (H==64)
__global__ void k_feast_gf(const float* __restrict__ Y,const int* __restrict__ offD,
                           const int* __restrict__ rowD,
                           const float* __restrict__ b,float* X,int n,int H,
                           float* __restrict__ meanacc,float inv_n){
  __shared__ float ms[4][64];
  int idx = blockIdx.x*256+threadIdx.x;
  float v = 0.0f;
  if(idx<n*H){
    int i = idx/H, h = idx - i*H;
    int p0 = offD[i], p1 = offD[i+1];
    float s = 0.0f;
    for(int p=p0;p<p1;p++) s += Y[(size_t)rowD[p]*H + h];
    float t = s/(float)(p1-p0) + b[h];
    v = t > 0.0f ? t : (expf(t)-1.0f);
    X[idx] = v;
  }
  if(meanacc){
    int r = threadIdx.x>>6, j = threadIdx.x&63;
    ms[r][j] = (idx<n*H) ? v : 0.0f;
    __syncthreads();
    if(r==0) atomicAdd(&meanacc[j], (ms[0][j]+ms[1][j]+ms[2][j]+ms[3][j])*inv_n);
  }
}

// fused sparse gconv: gather agg (real edges only), 2 matmuls, relu, mean.
__global__ __launch_bounds__(256) void k_gconv_sparse_f(
    const float* __restrict__ X,const int* __restrict__ offD,const int* __restrict__ rowD,
    const int* __restrict__ eidD,int E,
    const float* __restrict__ Wrel,const float* __restrict__ brel,
    const float* __restrict__ Wroot,
    float* __restrict__ XN,int n,float* __restrict__ meanacc,float inv_n)
{
  __shared__ float agg_s[4][65];
  __shared__ float xrow[4][65];
  __shared__ float cnt_s[4];
  const int tid = threadIdx.x;
  const int r = tid>>6, j = tid&63;
  const int i = blockIdx.x*4 + r;
  float a = 0.0f;
  if (i < n){
    int p0 = offD[i], p1 = offD[i+1], c = 0;
    for(int p=p0;p<p1;p++){
      if (eidD[p] < E){ a += X[(size_t)rowD[p]*64 + j]; c++; }
    }
    xrow[r][j] = X[(size_t)i*64 + j];
    if (j == 0) cnt_s[r] = (float)(c>1?c:1);
  }
  agg_s[r][j] = a;
  __syncthreads();
  float v = 0.0f;
  if (i < n){
    float acc=0.0f, rt=0.0f;
    for(int q=0;q<64;q++){
      acc = fmaf(agg_s[r][q], Wrel[q*64+j], acc);
      rt  = fmaf(xrow[r][q],  Wroot[q*64+j], rt);
    }
    v = fmaxf(acc/cnt_s[r] + brel[j] + rt, 0.0f);
    XN[(size_t)i*64 + j] = v;
  }
  __syncthreads();
  agg_s[r][j] = v;
  __syncthreads();
  if (r == 0) atomicAdd(&meanacc[j], (agg_s[0][j]+agg_s[1][j]+agg_s[2][j]+agg_s[3][j])*inv_n);
}

// pool0: xq = segmax gather (incl self) then @pW+pb
__global__ __launch_bounds__(256) void k_xqmaxq(
    const float* __restrict__ X,const int* __restrict__ offD,const int* __restrict__ rowD,
    const float* __restrict__ pWp,const float* __restrict__ pbp,
    float* __restrict__ XQ2,int n)
{
  __shared__ float xq[4][65];
  const int tid = threadIdx.x;
  const int r = tid>>6, j = tid&63;
  const int i = blockIdx.x*4 + r;
  float v = -3.0e38f;
  if (i < n){
    int p0 = offD[i], p1 = offD[i+1];
    for(int p=p0;p<p1;p++) v = fmaxf(v, X[(size_t)rowD[p]*64 + j]);
  }
  xq[r][j] = v;
  __syncthreads();
  if (i < n){
    float s = pbp[j];
    for(int q=0;q<64;q++) s = fmaf(xq[r][q], pWp[q*64+j], s);
    XQ2[(size_t)i*64+j] = s;
  }
}

__global__ void k_edge_score(const int* __restrict__ src,const int* __restrict__ dst,
                             const float* __restrict__ XQ2,const float* __restrict__ X,
                             float* sE,int E,int n){
  int e = blockIdx.x*256+threadIdx.x; if(e>=E+n) return;
  int s,d; edge_sd(e,src,dst,E,s,d);
  const float* q = XQ2 + (size_t)d*64;
  const float* x = X + (size_t)s*64;
  float acc = 0.0f;
  for(int h=0;h<64;h++) acc = fmaf(q[h], x[h], acc);
  sE[e] = acc > 0.0f ? acc : 0.2f*acc;
}

// per-dst softmax over in-edges -> scE; also emits Mt[p] = {rowD[p]*kk, bits(scE)}
// (fused former k_prep2 — values identical, one launch saved).
__global__ void k_dstsoft(const int* __restrict__ offD,const int* __restrict__ eidD,
                          const int* __restrict__ rowD,
                          const float* __restrict__ sE,float* __restrict__ scE,
                          int2* __restrict__ Mt,int kk,int n){
  int i = blockIdx.x*256+threadIdx.x; if(i>=n) return;
  int p0 = offD[i], p1 = offD[i+1];
  float m = -3.0e38f;
  for(int p=p0;p<p1;p++) m = fmaxf(m, sE[eidD[p]]);
  float d = 0.0f;
  for(int p=p0;p<p1;p++) d += expf(sE[eidD[p]]-m);
  float inv = 1.0f/d;
  for(int p=p0;p<p1;p++){
    int e = eidD[p];
    float v = expf(sE[e]-m)*inv;
    scE[e] = v;
    Mt[p] = make_int2(rowD[p]*kk, __float_as_int(v));
  }
}

// pool0: xc gather + aN/bN/cN; zeroes pcnt
__global__ __launch_bounds__(256) void k_xcabc0(
    const int* __restrict__ offD,const int* __restrict__ rowD,const int* __restrict__ eidD,
    const float* __restrict__ scE,const float* __restrict__ X,
    float* __restrict__ XC,
    const float* __restrict__ w1,const float* bb1,const float* __restrict__ w2,
    const float* __restrict__ w3,const float* bb3,
    float* aN,float* bN,float* cN,int* pcnt,int n)
{
  __shared__ float xc[4][65];
  const int tid = threadIdx.x;
  const int r = tid>>6, j = tid&63;
  const int i = blockIdx.x*4 + r;
  if (blockIdx.x==0 && tid==0) *pcnt = 0;
  float v = 0.0f;
  if (i < n){
    int p0 = offD[i], p1 = offD[i+1];
    for(int p=p0;p<p1;p++) v += scE[eidD[p]] * X[(size_t)rowD[p]*64 + j];
    XC[(size_t)i*64+j] = v;
  }
  xc[r][j] = v;
  __syncthreads();
  if (i < n && j < 3){
    float s = (j==0)?bb1[0]:((j==2)?bb3[0]:0.0f);
    const float* w = (j==0)?w1:((j==1)?w2:w3);
    for(int q=0;q<64;q++) s = fmaf(xc[r][q], w[q], s);
    if(j==0) aN[i]=s; else if(j==1) bN[i]=s; else cN[i]=s;
  }
}

// pool0 fit + zero rank + ipos=-1 (fused former k_fillm1)
__global__ void k_aggfit0(const int* __restrict__ offD,const int* __restrict__ rowD,
                          const float* aN,const float* bN,const float* cN,
                          float* fit,int* __restrict__ rank,int* __restrict__ ipos,int n){
  int i = blockIdx.x*256+threadIdx.x; if(i>=n) return;
  int p0 = offD[i], p1 = offD[i+1];
  float s = 0.0f;
  for(int p=p0;p<p1;p++) s += aN[rowD[p]];
  fit[i] = sigm(s - (float)(p1-p0)*bN[i] + cN[i]);
  rank[i] = 0;
  ipos[i] = -1;
}

// R column-permuted at write time: Rp[i][ipos[c]] += scE  (only kept columns).
__global__ void k_stage1p(const int* src,const int* dst,const int* __restrict__ offS,
                          const int* __restrict__ colS,const int* __restrict__ eidS,
                          const float* __restrict__ scE,const int* __restrict__ ipos,
                          float* Rp,int E,int n,int kk){
  int e = blockIdx.x*256+threadIdx.x; if(e>=E+n) return;
  int i,j; edge_sd(e,src,dst,E,i,j);
  int p0 = offS[j], p1 = offS[j+1];
  float* Ri = Rp + (size_t)i*kk;
  for(int p=p0;p<p1;p++){
    int ip = ipos[colS[p]];
    if (ip >= 0) atomicAdd(&Ri[ip], scE[eidS[p]]);
  }
}
// A_new[u][v] = sum over in-edges of perm[u]: scE * Rp[row][v].
// XCD-sliced (confirmed R2: FETCH 43.6->5.9 MB) + Mt-fused unroll-4 (R3).
__global__ __launch_bounds__(256) void k_stage2x(
    const int* __restrict__ perm,const int* __restrict__ offD,
    const int2* __restrict__ Mt,
    const float* __restrict__ Rp,float* A,int k,int vw,int cbn){
  const int bid = blockIdx.x;
  const int slice = bid & 7;
  const int rest = bid >> 3;
  const int cb = rest % cbn;
  const int ub = rest / cbn;
  const int u = ub*4 + (threadIdx.x>>6);
  if (u >= k) return;
  const int vbase = slice*vw;
  int vend = vbase + vw; if (vend > k) vend = k;
  const int v = vbase + cb*64 + (threadIdx.x&63);
  const bool vok = v < vend;
  const int vs = vok ? v : vbase;
  const int d = perm[u];
  float acc = 0.0f;
  int p = offD[d];
  const int p1 = offD[d+1];
  for(; p+4 <= p1; p += 4){
    const int2 m0 = Mt[p];
    const int2 m1 = Mt[p+1];
    const int2 m2 = Mt[p+2];
    const int2 m3 = Mt[p+3];
    const float r0 = Rp[m0.x + vs];
    const float r1 = Rp[m1.x + vs];
    const float r2 = Rp[m2.x + vs];
    const float r3 = Rp[m3.x + vs];
    acc = fmaf(__int_as_float(m0.y), r0, acc);
    acc = fmaf(__int_as_float(m1.y), r1, acc);
    acc = fmaf(__int_as_float(m2.y), r2, acc);
    acc = fmaf(__int_as_float(m3.y), r3, acc);
  }
  for(; p < p1; ++p){
    const int2 m = Mt[p];
    acc = fmaf(__int_as_float(m.y), Rp[m.x + vs], acc);
  }
  if (vok) A[(size_t)u*k + v] = (u==v) ? 0.0f : acc;
}

__global__ void k_head2(const float* __restrict__ xs,const float* __restrict__ W1,
                        const float* __restrict__ b1,const float* __restrict__ W2,
                        const float* __restrict__ b2,float* out){
  __shared__ float h2[64];
  __shared__ float lg[10];
  int t = threadIdx.x;
  float s = b1[t];
  for(int q=0;q<640;q++) s = fmaf(xs[q], W1[q*64+t], s);
  h2[t] = fmaxf(s, 0.0f);
  __syncthreads();
  if(t < 10){
    float s2 = b2[t];
    for(int k=0;k<64;k++) s2 = fmaf(h2[k], W2[k*10+t], s2);
    lg[t] = s2;
  }
  __syncthreads();
  if(t == 0){
    float mx = lg[0];
    for(int i=1;i<10;i++) mx = fmaxf(mx, lg[i]);
    float se = 0.0f;
    for(int i=0;i<10;i++) se += expf(lg[i]-mx);
    float lse = mx + logf(se);
    for(int i=0;i<10;i++) out[i] = lg[i]-lse;
  }
}

// ---------------- host orchestration ----------------
extern "C" void kernel_launch(void* const* d_in, const int* in_sizes, int n_in,
                              void* d_out, int out_size, void* d_ws, size_t ws_size,
                              hipStream_t stream) {
  const int N0 = 1500, E = 24000, Z = 16, L = E + N0;
  const float* x0   = (const float*)d_in[0];
  const int* esrc   = (const int*)d_in[1];
  const int* edst   = (const int*)d_in[2];
  const float* W1   = (const float*)d_in[3];  const float* b1   = (const float*)d_in[4];
  const float* W2   = (const float*)d_in[5];  const float* b2   = (const float*)d_in[6];
  const float* W3   = (const float*)d_in[7];  const float* b3   = (const float*)d_in[8];
  const float* Wrel = (const float*)d_in[9];  const float* brel = (const float*)d_in[10];
  const float* Wroot= (const float*)d_in[11];
  const float* pW   = (const float*)d_in[12]; const float* pb   = (const float*)d_in[13];
  const float* leW1 = (const float*)d_in[14]; const float* leb1 = (const float*)d_in[15];
  const float* leW2 = (const float*)d_in[16]; const float* leW3 = (const float*)d_in[17];
  const float* leb3 = (const float*)d_in[18];
  const float* linW1= (const float*)d_in[19]; const float* linb1= (const float*)d_in[20];
  const float* linW2= (const float*)d_in[21]; const float* linb2= (const float*)d_in[22];
  float* out = (float*)d_out;

  float* ws = (float*)d_ws;
  size_t cur = 0;
  auto allocF = [&](size_t nf)->float*{ float* p = ws + cur; cur += (nf + 15) & ~(size_t)15; return p; };
  // contiguous zero block: xs | indeg | outdeg
  float* xs   = allocF(640);
  int* indeg  = (int*)allocF(1504);
  int* outdeg = (int*)allocF(1504);
  float* Xa  = allocF(96000); float* Xb  = allocF(96000); float* Y   = allocF(96000);
  float* XQ2 = allocF(96000); float* XC  = allocF(96000);
  float* mcol = allocF(1504); float* invd = allocF(1504);
  float* aN = allocF(1504); float* bN = allocF(1504); float* cN = allocF(1504);
  float* fit = allocF(1504); float* cntP = allocF(1504);
  int* pcnt = (int*)allocF(16);
  int* perm = (int*)allocF(1504);
  int* offD = (int*)allocF(1504); int* offS = (int*)allocF(1504);
  int* curD = (int*)allocF(1504); int* curS = (int*)allocF(1504);
  int* colS = (int*)allocF(25504); int* eidS = (int*)allocF(25504);
  int* rowD = (int*)allocF(25504); int* eidD = (int*)allocF(25504);
  float* sE = allocF(25504); float* scE = allocF(25504);
  int2* Mt  = (int2*)allocF(51008);
  int* cntp8 = (int*)allocF((size_t)Z*1504);
  float* aggp = allocF(16*1504);
  float* SEGP = allocF((size_t)Z*1504*64);
  float* Rbig = allocF((size_t)1500*1500);   // pool0 Rp; aliased as split-K slab 0 + SCb
  float* SCb  = Rbig;
  float* A0  = allocF((size_t)1350*1350);
  float* A1s = allocF((size_t)1350*1350);
  const size_t SLAB = 1650048;               // >= 1350*1215
  float* PS2 = allocF(SLAB);
  float* PS3 = allocF(SLAB);
  const size_t BFSZ = (size_t)1350*4224/2 + 32;
  ushort* Abf = (ushort*)allocF(BFSZ);
  ushort* Bbf = (ushort*)allocF(BFSZ);
  ushort* Cbf = (ushort*)allocF(BFSZ);
  ushort* Dbf = (ushort*)allocF(BFSZ);
  int* rankb = indeg;                        // dead after k_prefix2

  dim3 B256(256);
  auto G1 = [&](size_t n){ return dim3((unsigned)((n + 255) / 256)); };
  auto ZF = [&](void* p, size_t nfloats){ k_zero<<<G1(nfloats),B256,0,stream>>>((float*)p, nfloats); };
  auto kcz = [&](int K){ return (int)(((K + Z*16 - 1) / (Z*16)) * 16); };

  // ---- prologue: zero (xs+indeg+outdeg contiguous), degrees, CSR ----
  ZF(xs, 640 + 1504 + 1504);
  k_deg<<<G1(E),B256,0,stream>>>(esrc, edst, indeg, outdeg, E);
  k_prefix2<<<dim3((N0+256)/256,2),B256,0,stream>>>(indeg, outdeg, offD, curD, offS, curS, N0);
  k_csr_fill2<<<G1(L),B256,0,stream>>>(esrc, edst, curS, colS, eidS, curD, rowD, eidD, E, N0);

  // ---- FEAST x3 (2 nodes each) ----
  auto feast = [&](const float* xin,int cin,const float* W,const float* bb,int hh,float* xout,float* macc){
    k_mm_small<<<G1((size_t)N0*hh),B256,0,stream>>>(xin, W, nullptr, Y, N0, cin, hh, 0);
    k_feast_gf<<<G1((size_t)N0*hh),B256,0,stream>>>(Y, offD, rowD, bb, xout, N0, hh, macc, 1.0f/N0);
  };
  feast(x0, 16, W1, b1, 32, Xa, nullptr);
  feast(Xa, 32, W2, b2, 64, Xb, nullptr);
  feast(Xb, 64, W3, b3, 64, Xa, xs + 0);
  float* X = Xa; float* XN = Xb;

  // ---- i=0 gconv_sparse (1 node) ----
  k_gconv_sparse_f<<<dim3((N0+3)/4),B256,0,stream>>>(X, offD, rowD, eidD, E, Wrel, brel, Wroot,
                                                     XN, N0, xs + 64, 1.0f/N0);
  { float* t = X; X = XN; XN = t; }

  // ---- pool 0 (sparse ASAP), n=1500 -> k=1350 ----
  {
    const int n = 1500, kk = 1350;
    int* ipos = curD;   // dead after CSR build
    k_xqmaxq<<<dim3((n+3)/4),B256,0,stream>>>(X, offD, rowD, pW, pb, XQ2, n);
    k_edge_score<<<G1(L),B256,0,stream>>>(esrc, edst, XQ2, X, sE, E, n);
    k_dstsoft<<<G1(n),B256,0,stream>>>(offD, eidD, rowD, sE, scE, Mt, kk, n);
    k_xcabc0<<<dim3((n+3)/4),B256,0,stream>>>(offD, rowD, eidD, scE, X, XC,
                                              leW1, leb1, leW2, leW3, leb3, aN, bN, cN, pcnt, n);
    k_aggfit0<<<G1(n),B256,0,stream>>>(offD, rowD, aN, bN, cN, fit, rankb, ipos, n);
    k_rank_cnt<<<dim3((n+255)/256,(n+127)/128),B256,0,stream>>>(fit, rankb, n);
    k_rank_sel<<<dim3((n+3)/4),B256,0,stream>>>(rankb, fit, XC, XN, n, kk, pcnt, perm, ipos);
    ZF(Rbig, (size_t)n*kk);
    k_stage1p<<<G1(L),B256,0,stream>>>(esrc, edst, offS, colS, eidS, scE, ipos, Rbig, E, n, kk);
    {
      const int vw = (kk + 7) / 8;          // 169
      const int cbn = (vw + 63) / 64;       // 3
      const int ubn = (kk + 3) / 4;         // 338
      k_stage2x<<<dim3((unsigned)(8*cbn*ubn)),B256,0,stream>>>(perm, offD, Mt,
                                                               Rbig, A0, kk, vw, cbn);
    }
    { float* t = X; X = XN; XN = t; }
  }

  float* Acur = A0; float* Aoth = A1s;
  int nn = 1350;

  // ---- dense gconv (2 nodes) ----
  auto gconv_dense = [&](int layer){
    dim3 g(1, (nn+63)/64, Z);
    k_skinny<false,true,false,false><<<g,B256,0,stream>>>(Acur, nn, X, nullptr, SEGP, cntp8, nn, nn, kcz(nn));
    k_gconv_fuse<<<dim3((nn+3)/4),B256,0,stream>>>(SEGP, cntp8, Z,
        Wrel + (size_t)layer*4096, brel + layer*64, X, Wroot + (size_t)layer*4096,
        XN, nn, xs + (size_t)(layer+1)*64, 1.0f/nn);
    { float* t = X; X = XN; XN = t; }
  };

  // ---- dense ASAP pool ----
  auto asap_dense = [&](int kk, int p){
    {
      dim3 g(1, (nn+63)/64, Z);
      k_skinny<true,true,false,true><<<g,B256,0,stream>>>(Acur, nn, X, nullptr, SEGP, cntp8, nn, nn, kcz(nn));
    }
    k_poolq<<<dim3((nn+3)/4),B256,0,stream>>>(SEGP, cntp8, Z, pW + (size_t)p*4096, pb + p*64,
                                              X, Abf, Bbf, cntP, nn);
    {
      dim3 g((nn+63)/64, (nn+63)/64);
      k_gemm_mfma<1><<<g,B256,0,stream>>>(Abf, Bbf, SCb, nn, nn, nn, 192, Acur, nn);
    }
    k_smax_fused<<<dim3((nn+15)/16),B256,0,stream>>>(SCb, nn, mcol, invd);
    {
      dim3 g(1, (nn+63)/64, Z);
      k_skinny<false,false,true,false><<<g,B256,0,stream>>>(SCb, nn, X, mcol, SEGP, nullptr, nn, nn, kcz(nn));
    }
    k_xcabc_dense<<<dim3((nn+3)/4),B256,0,stream>>>(SEGP, Z, invd, XC,
        leW1 + p*64, leb1 + p, leW2 + p*64, leW3 + p*64, leb3 + p, aN, bN, cN, pcnt, nn);
    k_aggcol<<<G1((size_t)nn*16),B256,0,stream>>>(Acur, aN, aggp, nn);
    k_fit_dense<<<G1(nn),B256,0,stream>>>(aggp, cntP, aN, bN, cN, fit, rankb, pcnt, nn);
    k_rank_cnt<<<dim3((nn+255)/256,(nn+127)/128),B256,0,stream>>>(fit, rankb, nn);
    k_rank_sel<<<dim3((nn+3)/4),B256,0,stream>>>(rankb, fit, XC, XN, nn, kk, pcnt, perm, nullptr);
    const int Kp = (nn + 63) & ~63;
    const int K3 = 3*Kp;
    k_split3<<<G1((size_t)nn*Kp),B256,0,stream>>>(Acur, nn, nn, nn, Abf, Kp, 0);
    { dim3 gt((kk+31)/32, Kp/32);
      k_split3_Tdual<<<gt,B256,0,stream>>>(SCb, nn, kk, nn, perm, invd, mcol, Dbf, Bbf, Cbf, Kp); }
    // ---- TB = A@Sp + Sp : split-K x4 (128x128 tiles, K-step 64, XCD swizzle) ----
    const int Tk = K3 >> 6;
    const int kchunk = ((Tk + 3) >> 2) << 6;
    {
      dim3 g((kk+127)/128, (nn+127)/128, 4);
      k_gemm_pp<<<g,B256,0,stream>>>(Abf, Bbf, Rbig, Aoth, PS2, PS3, kk, nn, kk, K3, kchunk);
      dim3 gr((kk+31)/32, (nn+31)/32);
      k_red_tb<<<gr,B256,0,stream>>>(Rbig, Aoth, PS2, PS3, kk, Bbf, Cbf, nn, kk, Kp);
    }
    // ---- A_new = Sp^T @ TB (zero diag): split-K x4 (output Aoth aliases slab 1: safe) ----
    {
      dim3 g((kk+127)/128, (kk+127)/128, 4);
      k_gemm_pp<<<g,B256,0,stream>>>(Dbf, Cbf, Rbig, Aoth, PS2, PS3, kk, kk, kk, K3, kchunk);
      k_red_diag<<<G1((size_t)kk*kk),B256,0,stream>>>(Rbig, Aoth, PS2, PS3, Aoth, kk);
    }
    { float* t = X; X = XN; XN = t; }
    { float* t = Acur; Acur = Aoth; Aoth = t; }
    nn = kk;
  };

  gconv_dense(1);
  gconv_dense(2);
  asap_dense(1215, 1);
  gconv_dense(3);
  gconv_dense(4);
  asap_dense(1094, 2);
  gconv_dense(5);
  gconv_dense(6);
  asap_dense(985, 3);
  gconv_dense(7);
  gconv_dense(8);

  // ---- head (1 node) ----
  k_head2<<<1,64,0,stream>>>(xs, linW1, linb1, linW2, linb2, out);
}

// Round 10
// 1287.057 us; speedup vs baseline: 1.0613x; 1.0464x over previous
//
#include <hip/hip_runtime.h>
#include <math.h>

#define NEGV -1000000000.0f

typedef short short8 __attribute__((ext_vector_type(8)));
typedef float floatx4 __attribute__((ext_vector_type(4)));

__device__ __forceinline__ float sigm(float x){ return 1.0f/(1.0f+expf(-x)); }
__device__ __forceinline__ void edge_sd(int e,const int* src,const int* dst,int E,int& s,int& d){
  if(e<E){ s=src[e]; d=dst[e]; } else { s=e-E; d=s; }
}
__device__ __forceinline__ ushort bf16rn(float x){
  unsigned u = __float_as_uint(x);
  unsigned r = (u + 0x7fffu + ((u>>16)&1u)) >> 16;
  return (ushort)r;
}
__device__ __forceinline__ float bf16f(ushort h){ return __uint_as_float(((unsigned)h)<<16); }

__global__ void k_zero(float* __restrict__ p, size_t n){
  size_t i = (size_t)blockIdx.x*256 + threadIdx.x;
  if (i < n) p[i] = 0.0f;
}

// ---------------- bf16x3 conversions ----------------
__global__ void k_split3(const float* __restrict__ src,int R,int Cs,int ld,
                         ushort* __restrict__ dst,int Cp,int bmode){
  int idx = blockIdx.x*256+threadIdx.x;
  if (idx >= R*Cp) return;
  int r = idx / Cp, c = idx - r*Cp;
  float x = (c < Cs) ? src[(size_t)r*ld + c] : 0.0f;
  ushort h = bf16rn(x);
  ushort l = bf16rn(x - bf16f(h));
  size_t base = (size_t)r*(3*Cp) + c;
  dst[base]        = h;
  dst[base + Cp]   = bmode ? l : h;
  dst[base + 2*Cp] = bmode ? h : l;
}
// Sp = exp(src[:,perm]-mcol[perm])*invd[perm], transposed to K-innermost; writes BOTH
// A-role (dstA) and B-role (dstB); zero-pads k>=Rs rows in dstA/dstB AND dstCpad.
__global__ void k_split3_Tdual(const float* __restrict__ src,int Rs,int Cs,int ld,
                               const int* __restrict__ gperm,const float* __restrict__ cscale,
                               const float* __restrict__ emax,
                               ushort* __restrict__ dstA,ushort* __restrict__ dstB,
                               ushort* __restrict__ dstCpad,int Kp){
  __shared__ float t[32][33];
  int tx = threadIdx.x & 31, ty = threadIdx.x >> 5;
  int kb = blockIdx.y*32, xb = blockIdx.x*32;
  int x = xb + tx;
  int gx = (x < Cs) ? gperm[x] : 0;
#pragma unroll
  for (int i=0;i<4;i++){
    int k = kb + ty + i*8;
    t[ty+i*8][tx] = (k < Rs && x < Cs) ? src[(size_t)k*ld + gx] : 0.0f;
  }
  __syncthreads();
  const int K3 = 3*Kp;
#pragma unroll
  for (int i=0;i<4;i++){
    int xo = xb + ty + i*8, ko = kb + tx;
    if (xo < Cs){
      float v = 0.0f;
      if (ko < Rs){
        int g = gperm[xo];
        v = expf(t[tx][ty+i*8] - emax[g]) * cscale[g];
      }
      ushort h = bf16rn(v);
      ushort l = bf16rn(v - bf16f(h));
      size_t base = (size_t)xo*K3 + ko;
      dstA[base] = h; dstA[base+Kp] = h; dstA[base+2*Kp] = l;
      dstB[base] = h; dstB[base+Kp] = l; dstB[base+2*Kp] = h;
      if (ko >= Rs){ dstCpad[base]=0; dstCpad[base+Kp]=0; dstCpad[base+2*Kp]=0; }
    }
  }
}

// ---------------- MFMA bf16 GEMM (64x64 tile, K-step 64, double-buffered) ----------------
// EPI 1: mask(A+I)+leakyrelu.  (Used for the score GEMM, K3=192.)
template<int EPI>
__global__ __launch_bounds__(256) void k_gemm_mfma(
    const ushort* __restrict__ A, const ushort* __restrict__ B,
    float* __restrict__ C, int ldc, int M, int N, int K3,
    const float* __restrict__ mask, int ldm)
{
  __shared__ ushort As[2][64][72];
  __shared__ ushort Bs[2][64][72];
  const int tid = threadIdx.x;
  const int m0 = blockIdx.y*64, n0 = blockIdx.x*64;
  const int w = tid>>6, lane = tid&63;
  const int lo4 = lane&15, quad = lane>>4;
  const int sr = tid>>2, sseg = tid&3;

  floatx4 acc[4];
#pragma unroll
  for(int c=0;c<4;c++){ acc[c][0]=0.f; acc[c][1]=0.f; acc[c][2]=0.f; acc[c][3]=0.f; }

  const size_t arow = (size_t)(m0+sr)*K3;
  const size_t brow = (size_t)(n0+sr)*K3;
  const bool aval = (m0+sr) < M;
  const bool bval = (n0+sr) < N;

  uint4 av0 = make_uint4(0,0,0,0), av1 = make_uint4(0,0,0,0);
  uint4 bv0 = make_uint4(0,0,0,0), bv1 = make_uint4(0,0,0,0);
  if (aval){ av0 = *(const uint4*)(A + arow + sseg*8);
             av1 = *(const uint4*)(A + arow + 32 + sseg*8); }
  if (bval){ bv0 = *(const uint4*)(B + brow + sseg*8);
             bv1 = *(const uint4*)(B + brow + 32 + sseg*8); }
  *(uint4*)&As[0][sr][sseg*8] = av0; *(uint4*)&As[0][sr][32+sseg*8] = av1;
  *(uint4*)&Bs[0][sr][sseg*8] = bv0; *(uint4*)&Bs[0][sr][32+sseg*8] = bv1;
  __syncthreads();

  const int T = K3 >> 6;
  for (int i=0;i<T;i++){
    const int cb = i & 1;
    if (i+1 < T){
      const int k0 = (i+1)<<6;
      av0 = make_uint4(0,0,0,0); av1 = make_uint4(0,0,0,0);
      bv0 = make_uint4(0,0,0,0); bv1 = make_uint4(0,0,0,0);
      if (aval){ av0 = *(const uint4*)(A + arow + k0 + sseg*8);
                 av1 = *(const uint4*)(A + arow + k0 + 32 + sseg*8); }
      if (bval){ bv0 = *(const uint4*)(B + brow + k0 + sseg*8);
                 bv1 = *(const uint4*)(B + brow + k0 + 32 + sseg*8); }
    }
    short8 af0 = *(const short8*)&As[cb][16*w + lo4][quad*8];
    short8 af1 = *(const short8*)&As[cb][16*w + lo4][32+quad*8];
#pragma unroll
    for (int c=0;c<4;c++){
      short8 bf0 = *(const short8*)&Bs[cb][16*c + lo4][quad*8];
      acc[c] = __builtin_amdgcn_mfma_f32_16x16x32_bf16(af0, bf0, acc[c], 0, 0, 0);
      short8 bf1 = *(const short8*)&Bs[cb][16*c + lo4][32+quad*8];
      acc[c] = __builtin_amdgcn_mfma_f32_16x16x32_bf16(af1, bf1, acc[c], 0, 0, 0);
    }
    if (i+1 < T){
      __syncthreads();
      *(uint4*)&As[1-cb][sr][sseg*8] = av0; *(uint4*)&As[1-cb][sr][32+sseg*8] = av1;
      *(uint4*)&Bs[1-cb][sr][sseg*8] = bv0; *(uint4*)&Bs[1-cb][sr][32+sseg*8] = bv1;
      __syncthreads();
    }
  }

#pragma unroll
  for (int c=0;c<4;c++){
    const int gn = n0 + 16*c + lo4;
#pragma unroll
    for (int r=0;r<4;r++){
      const int gm = m0 + 16*w + quad*4 + r;
      if (gm < M && gn < N){
        float v = acc[c][r];
        if (EPI==1) v = (mask[(size_t)gm*ldm+gn] != 0.0f || gm==gn) ? (v > 0.0f ? v : 0.2f*v) : NEGV;
        C[(size_t)gm*ldc+gn] = v;
      }
    }
  }
}

// ---------------- split-K x4 MFMA partial-product GEMM, 128x128 tile ----------------
// K-step 64 (measured best). 4 waves, each owns a 64x64 output quadrant.
// XCD-chunked bijective swizzle. blockIdx.z selects a K-chunk.
__global__ __launch_bounds__(256) void k_gemm_pp(
    const ushort* __restrict__ A, const ushort* __restrict__ B,
    float* __restrict__ P0, float* __restrict__ P1,
    float* __restrict__ P2, float* __restrict__ P3, int ldp,
    int M, int N, int K3, int kchunk)
{
  __shared__ ushort As[2][128][72];
  __shared__ ushort Bs[2][128][72];
  const int tid = threadIdx.x;

  // ---- XCD-chunked bijective block remap ----
  const int gx = gridDim.x, gxy = gridDim.x*gridDim.y;
  const int TT = gxy*gridDim.z;
  const int s  = blockIdx.x + gx*blockIdx.y + gxy*blockIdx.z;
  const int c8 = s & 7, u = s >> 3;
  const int q = TT >> 3, r8 = TT & 7;
  const int w0 = (c8 < r8) ? c8*(q+1) + u : r8*(q+1) + (c8 - r8)*q + u;
  const int z  = w0 / gxy;
  const int lin = w0 - z*gxy;
  const int ty = lin / gx, tx = lin - ty*gx;

  const int m0 = ty*128, n0 = tx*128;
  const int w = tid>>6, lane = tid&63;
  const int lo4 = lane&15, quad = lane>>4;
  const int wr = w>>1, wc = w&1;

  // staging: thread t -> row t>>1, half t&1 (32 ushort = 4x uint4 per operand)
  const int srow = tid>>1, shalf = tid&1;

  float* __restrict__ P = (z==0) ? P0 : (z==1) ? P1 : (z==2) ? P2 : P3;
  const int kbeg = z * kchunk;
  int klen = K3 - kbeg; if (klen > kchunk) klen = kchunk; if (klen < 0) klen = 0;
  const int T = klen >> 6;

  floatx4 acc[4][4];
#pragma unroll
  for(int i=0;i<4;i++)
#pragma unroll
    for(int c=0;c<4;c++){ acc[i][c][0]=0.f; acc[i][c][1]=0.f; acc[i][c][2]=0.f; acc[i][c][3]=0.f; }

  const size_t arow = (size_t)(m0+srow)*K3 + kbeg + shalf*32;
  const size_t brow = (size_t)(n0+srow)*K3 + kbeg + shalf*32;
  const bool aval = (m0+srow) < M;
  const bool bval = (n0+srow) < N;
  const int sbase = shalf*32;

  uint4 apre[4], bpre[4];
#pragma unroll
  for(int s2=0;s2<4;s2++){ apre[s2]=make_uint4(0,0,0,0); bpre[s2]=make_uint4(0,0,0,0); }
  if (aval){
#pragma unroll
    for(int s2=0;s2<4;s2++) apre[s2] = *(const uint4*)(A + arow + s2*8);
  }
  if (bval){
#pragma unroll
    for(int s2=0;s2<4;s2++) bpre[s2] = *(const uint4*)(B + brow + s2*8);
  }
#pragma unroll
  for(int s2=0;s2<4;s2++){
    *(uint4*)&As[0][srow][sbase + s2*8] = apre[s2];
    *(uint4*)&Bs[0][srow][sbase + s2*8] = bpre[s2];
  }
  __syncthreads();

  for (int it=0; it<T; ++it){
    const int cb = it & 1;
    if (it+1 < T){
      const int k0 = (it+1)<<6;
#pragma unroll
      for(int s2=0;s2<4;s2++){ apre[s2]=make_uint4(0,0,0,0); bpre[s2]=make_uint4(0,0,0,0); }
      if (aval){
#pragma unroll
        for(int s2=0;s2<4;s2++) apre[s2] = *(const uint4*)(A + arow + k0 + s2*8);
      }
      if (bval){
#pragma unroll
        for(int s2=0;s2<4;s2++) bpre[s2] = *(const uint4*)(B + brow + k0 + s2*8);
      }
    }
    short8 af[4][2];
#pragma unroll
    for(int i=0;i<4;i++){
      af[i][0] = *(const short8*)&As[cb][wr*64 + 16*i + lo4][quad*8];
      af[i][1] = *(const short8*)&As[cb][wr*64 + 16*i + lo4][32 + quad*8];
    }
#pragma unroll
    for(int c=0;c<4;c++){
      short8 bf0 = *(const short8*)&Bs[cb][wc*64 + 16*c + lo4][quad*8];
      short8 bf1 = *(const short8*)&Bs[cb][wc*64 + 16*c + lo4][32 + quad*8];
#pragma unroll
      for(int i=0;i<4;i++){
        acc[i][c] = __builtin_amdgcn_mfma_f32_16x16x32_bf16(af[i][0], bf0, acc[i][c], 0, 0, 0);
        acc[i][c] = __builtin_amdgcn_mfma_f32_16x16x32_bf16(af[i][1], bf1, acc[i][c], 0, 0, 0);
      }
    }
    if (it+1 < T){
      __syncthreads();
#pragma unroll
      for(int s2=0;s2<4;s2++){
        *(uint4*)&As[1-cb][srow][sbase + s2*8] = apre[s2];
        *(uint4*)&Bs[1-cb][srow][sbase + s2*8] = bpre[s2];
      }
      __syncthreads();
    }
  }

#pragma unroll
  for(int c=0;c<4;c++){
    const int gn = n0 + wc*64 + 16*c + lo4;
    if (gn < N){
#pragma unroll
      for(int i=0;i<4;i++){
#pragma unroll
        for(int r=0;r<4;r++){
          const int gm = m0 + wr*64 + 16*i + quad*4 + r;
          if (gm < M) P[(size_t)gm*ldp+gn] = acc[i][c][r];
        }
      }
    }
  }
}

// reduce 4 TB slabs + Sp, transpose-store as bf16x3 B-role (h,l,h) at gn*K3o+gm.
__global__ __launch_bounds__(256) void k_red_tb(
    const float* __restrict__ P0,const float* __restrict__ P1,
    const float* __restrict__ P2,const float* __restrict__ P3,int ldp,
    const ushort* __restrict__ Bb, ushort* __restrict__ Cb,
    int M,int N,int Kp)
{
  __shared__ float t[32][33];
  const int tx = threadIdx.x & 31, ty = threadIdx.x >> 5;
  const int mb = blockIdx.y*32, nb = blockIdx.x*32;
  const int n = nb + tx;
#pragma unroll
  for (int i=0;i<4;i++){
    int m = mb + ty + i*8;
    float v = 0.0f;
    if (m < M && n < N){
      size_t o = (size_t)m*ldp + n;
      v = (P0[o] + P1[o]) + (P2[o] + P3[o]);
    }
    t[ty+i*8][tx] = v;
  }
  __syncthreads();
  const int K3o = 3*Kp;
#pragma unroll
  for (int i=0;i<4;i++){
    int no = nb + ty + i*8, mo = mb + tx;
    if (no < N && mo < M){
      size_t base = (size_t)no*K3o + mo;
      float sp = bf16f(Bb[base]) + bf16f(Bb[base+Kp]);
      float v = t[tx][ty+i*8] + sp;
      ushort h = bf16rn(v), l = bf16rn(v - bf16f(h));
      Cb[base] = h; Cb[base+Kp] = l; Cb[base+2*Kp] = h;
    }
  }
}

// reduce 4 A_new slabs + zero diagonal. (C may alias one of the slabs: per-element
// read-then-write, no cross-thread sharing -> safe.)
__global__ void k_red_diag(const float* __restrict__ P0,const float* __restrict__ P1,
                           const float* __restrict__ P2,const float* __restrict__ P3,
                           float* __restrict__ C,int kk){
  int idx = blockIdx.x*256+threadIdx.x;
  if (idx >= kk*kk) return;
  int u = idx/kk, v = idx - u*kk;
  float s = (P0[idx] + P1[idx]) + (P2[idx] + P3[idx]);
  C[idx] = (u==v) ? 0.0f : s;
}

// ---------------- atomic-free skinny agg GEMM ----------------
template<bool MAXM, bool COUNT, bool EXPM, bool SELF>
__global__ __launch_bounds__(256) void k_skinny(
    const float* __restrict__ A, int lda,
    const float* __restrict__ X,
    const float* __restrict__ mcol,
    float* __restrict__ P, int* __restrict__ cntp,
    int M, int K, int kchunk)
{
  __shared__ float As[16][68];
  __shared__ float Xs[16][68];
  const int tid = threadIdx.x;
  const int m0 = blockIdx.y * 64;
  const int tmb = (tid & 15) * 4, tnb = (tid >> 4) * 4;
  float acc[4][4];
  int cacc[4] = {0,0,0,0};
#pragma unroll
  for (int i=0;i<4;i++)
#pragma unroll
    for (int j=0;j<4;j++) acc[i][j] = MAXM ? NEGV : 0.0f;

  const int kstart = blockIdx.z * kchunk;
  int kend = kstart + kchunk; if (kend > K) kend = K;
  const int ml = tid & 63, tb = tid >> 6;
  const bool mvalid = (m0 + ml) < M;
  float mc = 0.0f;
  if (EXPM && mvalid) mc = mcol[m0 + ml];

  for (int k0 = kstart; k0 < kend; k0 += 16) {
#pragma unroll
    for (int s=0;s<4;s++) {
      const int tk = tb + s*4;
      float va = 0.0f, vx = 0.0f;
      if ((k0+tk) < K) {
        if (mvalid){
          va = A[(size_t)(k0+tk)*lda + m0 + ml];
          if (EXPM) va = expf(va - mc);
        }
        vx = X[(size_t)(k0+tk)*64 + ml];
      }
      As[tk][ml] = va;
      Xs[tk][ml] = vx;
    }
    __syncthreads();
#pragma unroll
    for (int kk=0; kk<16; kk++) {
      const float4 a4 = *(const float4*)&As[kk][tmb];
      const float4 b4 = *(const float4*)&Xs[kk][tnb];
      const float av[4] = {a4.x,a4.y,a4.z,a4.w};
      const float bv[4] = {b4.x,b4.y,b4.z,b4.w};
#pragma unroll
      for (int i=0;i<4;i++){
        if (COUNT) cacc[i] += (av[i] != 0.0f) ? 1 : 0;
#pragma unroll
        for (int j=0;j<4;j++) {
          if (MAXM) acc[i][j] = fmaxf(acc[i][j], av[i] != 0.0f ? bv[j] : NEGV);
          else      acc[i][j] = fmaf(av[i], bv[j], acc[i][j]);
        }
      }
    }
    __syncthreads();
  }

  const size_t slab = (size_t)blockIdx.z * M * 64;
#pragma unroll
  for (int i=0;i<4;i++){
    const int m = m0 + tmb + i;
    if (m < M){
#pragma unroll
      for (int j=0;j<4;j++){
        float v = acc[i][j];
        if (SELF) v = fmaxf(v, X[(size_t)m*64 + tnb + j]);
        P[slab + (size_t)m*64 + tnb + j] = v;
      }
    }
  }
  if (COUNT && tnb == 0){
#pragma unroll
    for (int i=0;i<4;i++){
      const int m = m0 + tmb + i;
      if (m < M) cntp[blockIdx.z*M + m] = cacc[i];
    }
  }
}

// slab max-reduce -> xq; xq2 = xq@pW+pb; cntP = 1 + sum counts.
// Also emits bf16x3 operands: dstA (A-role from X), dstB (B-role from xq2).
__global__ __launch_bounds__(256) void k_poolq(
    const float* __restrict__ SEGP,const int* __restrict__ cntp8,int Z,
    const float* __restrict__ pWp,const float* __restrict__ pbp,
    const float* __restrict__ X,
    ushort* __restrict__ dstA,ushort* __restrict__ dstB,
    float* __restrict__ cntP,int n)
{
  __shared__ float xq[4][65];
  const int tid = threadIdx.x;
  const int r = tid>>6, j = tid&63;
  const int i = blockIdx.x*4 + r;
  float v = NEGV;
  if (i < n){
    for(int z=0;z<Z;z++) v = fmaxf(v, SEGP[(size_t)z*n*64 + (size_t)i*64 + j]);
    if (j == 0){
      int c=1; for(int z=0;z<Z;z++) c += cntp8[z*n+i];
      cntP[i] = (float)c;
    }
  }
  xq[r][j] = v;
  __syncthreads();
  if (i < n){
    float s = pbp[j];
    for(int q=0;q<64;q++) s = fmaf(xq[r][q], pWp[q*64+j], s);
    size_t base = (size_t)i*192 + j;
    ushort h = bf16rn(s), l = bf16rn(s - bf16f(h));
    dstB[base] = h; dstB[base+64] = l; dstB[base+128] = h;
    float x = X[(size_t)i*64 + j];
    h = bf16rn(x); l = bf16rn(x - bf16f(h));
    dstA[base] = h; dstA[base+64] = h; dstA[base+128] = l;
  }
}

// fused dense gconv: reduce slabs, two 64x64 matmuls, relu, mean-accumulate.
__global__ __launch_bounds__(256) void k_gconv_fuse(
    const float* __restrict__ SEGP,const int* __restrict__ cntp8,int Z,
    const float* __restrict__ Wrel,const float* __restrict__ brel,
    const float* __restrict__ X,const float* __restrict__ Wroot,
    float* __restrict__ XN,int n,float* __restrict__ meanacc,float inv_n)
{
  __shared__ float agg_s[4][65];
  __shared__ float xrow[4][65];
  __shared__ float cnt_s[4];
  const int tid = threadIdx.x;
  const int r = tid>>6, j = tid&63;
  const int i = blockIdx.x*4 + r;
  float a = 0.0f;
  if (i < n){
    for(int z=0;z<Z;z++) a += SEGP[(size_t)z*n*64 + (size_t)i*64 + j];
    xrow[r][j] = X[(size_t)i*64 + j];
    if (j == 0){
      int c=0; for(int z=0;z<Z;z++) c += cntp8[z*n+i];
      cnt_s[r] = (float)(c>1?c:1);
    }
  }
  agg_s[r][j] = a;
  __syncthreads();
  float v = 0.0f;
  if (i < n){
    float acc=0.0f, rt=0.0f;
    for(int q=0;q<64;q++){
      acc = fmaf(agg_s[r][q], Wrel[q*64+j], acc);
      rt  = fmaf(xrow[r][q],  Wroot[q*64+j], rt);
    }
    v = fmaxf(acc/cnt_s[r] + brel[j] + rt, 0.0f);
    XN[(size_t)i*64 + j] = v;
  }
  __syncthreads();
  agg_s[r][j] = v;
  __syncthreads();
  if (r == 0) atomicAdd(&meanacc[j], (agg_s[0][j]+agg_s[1][j]+agg_s[2][j]+agg_s[3][j])*inv_n);
}

// ---------------- row-chunked column softmax stats (3 kernels, 16x parallelism) ----------------
// R9: k_smax_fused ran at 2.6% occupancy (85 blocks) for ~40us x3 pools.
// Split over 16 row-chunks: partial max -> partial exp-sum -> tiny combine.
// mcol is bit-identical (max is exact); sum order changes rounding only.
__global__ __launch_bounds__(256) void k_smax_pmax(const float* __restrict__ S,int n,int chunk,
                                                   float* __restrict__ mpart){
  __shared__ float red[16][17];
  const int jc = threadIdx.x & 15, rg = threadIdx.x >> 4;
  const int j = blockIdx.x*16 + jc;
  const int z = blockIdx.y;
  const int i0 = z*chunk;
  int i1 = i0 + chunk; if (i1 > n) i1 = n;
  float m = -3.0e38f;
  if (j < n)
    for(int i=i0+rg;i<i1;i+=16) m = fmaxf(m, S[(size_t)i*n+j]);
  red[rg][jc] = m;
  __syncthreads();
  for(int s=8;s>0;s>>=1){
    if(rg<s) red[rg][jc] = fmaxf(red[rg][jc], red[rg+s][jc]);
    __syncthreads();
  }
  if (rg==0 && j<n) mpart[(size_t)z*n + j] = red[0][jc];
}
__global__ __launch_bounds__(256) void k_smax_psum(const float* __restrict__ S,int n,int chunk,
                                                   const float* __restrict__ mpart,
                                                   float* __restrict__ spart){
  __shared__ float red[16][17];
  const int jc = threadIdx.x & 15, rg = threadIdx.x >> 4;
  const int j = blockIdx.x*16 + jc;
  const int z = blockIdx.y;
  float mv = -3.0e38f;
  if (j < n) mv = mpart[(size_t)rg*n + j];
  red[rg][jc] = mv;
  __syncthreads();
  for(int s=8;s>0;s>>=1){
    if(rg<s) red[rg][jc] = fmaxf(red[rg][jc], red[rg+s][jc]);
    __syncthreads();
  }
  const float mc = red[0][jc];
  __syncthreads();
  const int i0 = z*chunk;
  int i1 = i0 + chunk; if (i1 > n) i1 = n;
  float sum = 0.0f;
  if (j < n)
    for(int i=i0+rg;i<i1;i+=16) sum += expf(S[(size_t)i*n+j]-mc);
  red[rg][jc] = sum;
  __syncthreads();
  for(int s=8;s>0;s>>=1){
    if(rg<s) red[rg][jc] += red[rg+s][jc];
    __syncthreads();
  }
  if (rg==0 && j<n) spart[(size_t)z*n + j] = red[0][jc];
}
__global__ void k_smax_fin(const float* __restrict__ mpart,const float* __restrict__ spart,
                           int n,float* __restrict__ mcol,float* __restrict__ invd){
  int j = blockIdx.x*256+threadIdx.x; if(j>=n) return;
  float m = mpart[j];
  for(int z=1;z<16;z++) m = fmaxf(m, mpart[(size_t)z*n+j]);
  mcol[j] = m;
  float s = 0.0f;
  for(int z=0;z<16;z++) s += spart[(size_t)z*n+j];
  invd[j] = 1.0f/s;
}

// slab sum * invd -> XC; then aN/bN/cN per row; zeroes pcnt.
__global__ __launch_bounds__(256) void k_xcabc_dense(
    const float* __restrict__ SEGP,int Z,const float* __restrict__ invd,
    float* __restrict__ XC,
    const float* __restrict__ w1,const float* bb1,const float* __restrict__ w2,
    const float* __restrict__ w3,const float* bb3,
    float* aN,float* bN,float* cN,int* pcnt,int n)
{
  __shared__ float xc[4][65];
  const int tid = threadIdx.x;
  const int r = tid>>6, j = tid&63;
  const int i = blockIdx.x*4 + r;
  if (blockIdx.x==0 && tid==0) *pcnt = 0;
  float v = 0.0f;
  if (i < n){
    for(int z=0;z<Z;z++) v += SEGP[(size_t)z*n*64 + (size_t)i*64 + j];
    v *= invd[i];
    XC[(size_t)i*64+j] = v;
  }
  xc[r][j] = v;
  __syncthreads();
  if (i < n && j < 3){
    float s = (j==0)?bb1[0]:((j==2)?bb3[0]:0.0f);
    const float* w = (j==0)?w1:((j==1)?w2:w3);
    for(int q=0;q<64;q++) s = fmaf(xc[r][q], w[q], s);
    if(j==0) aN[i]=s; else if(j==1) bN[i]=s; else cN[i]=s;
  }
}

__global__ void k_aggcol(const float* __restrict__ A,const float* __restrict__ aN,
                         float* __restrict__ aggp,int n){
  int idx = blockIdx.x*256+threadIdx.x; if(idx>=n*16) return;
  int j = idx % n, c = idx / n;
  int i0 = (int)(((long long)n*c)/16), i1 = (int)(((long long)n*(c+1))/16);
  float s = 0.0f;
  for(int i=i0;i<i1;i++) if(A[(size_t)i*n + j] != 0.0f) s += aN[i];
  aggp[c*n + j] = s;
}

// ---------------- parallel top-k rank ----------------
__global__ void k_fit_dense(const float* __restrict__ aggp,const float* __restrict__ cntP,
                            const float* __restrict__ aN,const float* __restrict__ bN,
                            const float* __restrict__ cN,
                            float* __restrict__ fit,int* __restrict__ rank,int* pcnt,int n){
  int u = blockIdx.x*256+threadIdx.x;
  if (blockIdx.x==0 && threadIdx.x==0) *pcnt = 0;
  if (u >= n) return;
  float a = aN[u];
  for(int c=0;c<16;c++) a += aggp[c*n+u];
  fit[u] = sigm(a - cntP[u]*bN[u] + cN[u]);
  rank[u] = 0;
}
__global__ __launch_bounds__(256) void k_rank_cnt(const float* __restrict__ fit,
                                                  int* __restrict__ rank,int n){
  __shared__ float fsc[128];
  const int u0 = blockIdx.y*128;
  int u1 = u0+128; if (u1 > n) u1 = n;
  const int cl = u1 - u0;
  if ((int)threadIdx.x < cl) fsc[threadIdx.x] = fit[u0+threadIdx.x];
  __syncthreads();
  const int v = blockIdx.x*256+threadIdx.x;
  if (v >= n) return;
  const float fv = fit[v];
  int r = 0;
  for(int t=0;t<cl;t++){
    const float fu = fsc[t];
    const int u = u0+t;
    r += (fu > fv || (fu == fv && u < v)) ? 1 : 0;
  }
  atomicAdd(&rank[v], r);
}
// Selection + coalesced XN write; optionally records inverse perm (ipos[v]=slot).
__global__ __launch_bounds__(256) void k_rank_sel(const int* __restrict__ rank,
    const float* __restrict__ fit,const float* __restrict__ XC,float* __restrict__ XN,
    int n,int k,int* pcnt,int* perm,int* __restrict__ ipos){
  __shared__ int ps[4];
  const int r = threadIdx.x>>6, h = threadIdx.x&63;
  const int v = blockIdx.x*4 + r;
  const bool sel = (v < n) && (rank[v] < k);
  if (h == 0 && sel){
    int p = atomicAdd(pcnt,1);
    ps[r] = p;
    perm[p] = v;
    if (ipos) ipos[v] = p;
  }
  __syncthreads();
  if (sel){
    const int p = ps[r];
    XN[(size_t)p*64 + h] = XC[(size_t)v*64 + h] * fit[v];
  }
}

// ---------------- prologue: degrees + CSR over L=E+n edges (incl self) ----------------
__global__ void k_deg(const int* __restrict__ src,const int* __restrict__ dst,int* indeg,int* outdeg,int E){
  int e = blockIdx.x*256+threadIdx.x; if(e>=E) return;
  atomicAdd(&indeg[dst[e]],1); atomicAdd(&outdeg[src[e]],1);
}
__global__ __launch_bounds__(256) void k_prefix2(const int* __restrict__ indeg,const int* __restrict__ outdeg,
                          int* offD,int* curD,int* offS,int* curS,int n){
  __shared__ int ds[1504];
  const int* dsrc = blockIdx.y ? outdeg : indeg;
  for(int u=threadIdx.x; u<n; u+=256) ds[u] = dsrc[u];
  __syncthreads();
  int t = blockIdx.x*256+threadIdx.x; if(t>n) return;
  int s = 0;
  for(int u=0;u<t;u++) s += ds[u]+1;
  if (blockIdx.y){ offS[t]=s; if(t<n) curS[t]=s; }
  else           { offD[t]=s; if(t<n) curD[t]=s; }
}
__global__ void k_csr_fill2(const int* src,const int* dst,
                            int* curS,int* colS,int* eidS,
                            int* curD,int* rowD,int* eidD,int E,int n){
  int e = blockIdx.x*256+threadIdx.x; if(e>=E+n) return;
  int s,d; edge_sd(e,src,dst,E,s,d);
  int p = atomicAdd(&curS[s],1); colS[p]=d; eidS[p]=e;
  int q = atomicAdd(&curD[d],1); rowD[q]=s; eidD[q]=e;
}

__global__ void k_mm_small(const float* __restrict__ A,const float* __restrict__ W,
                           const float* __restrict__ b,float* __restrict__ C,
                           int M,int K,int Np,int act){
  int idx = blockIdx.x*256+threadIdx.x; if(idx>=M*Np) return;
  int m = idx/Np, j = idx - m*Np;
  float s = b ? b[j] : 0.0f;
  const float* a = A + (size_t)m*K;
  for(int q=0;q<K;q++) s = fmaf(a[q], W[(size_t)q*Np + j], s);
  if(act==1) s = fmaxf(s, 0.0f);
  C[idx] = s;
}

// feast: gather-mean over in-edges (incl self), +b, elu; optional mean (H==64)
__global__ void k_feast_gf(const float* __restrict__ Y,const int* __restrict__ offD,
                           const int* __restrict__ rowD,
                           const float* __restrict__ b,float* X,int n,int H,
                           float* __restrict__ meanacc,float inv_n){
  __shared__ float ms[4][64];
  int idx = blockIdx.x*256+threadIdx.x;
  float v = 0.0f;
  if(idx<n*H){
    int i = idx/H, h = idx - i*H;
    int p0 = offD[i], p1 = offD[i+1];
    float s = 0.0f;
    for(int p=p0;p<p1;p++) s += Y[(size_t)rowD[p]*H + h];
    float t = s/(float)(p1-p0) + b[h];
    v = t > 0.0f ? t : (expf(t)-1.0f);
    X[idx] = v;
  }
  if(meanacc){
    int r = threadIdx.x>>6, j = threadIdx.x&63;
    ms[r][j] = (idx<n*H) ? v : 0.0f;
    __syncthreads();
    if(r==0) atomicAdd(&meanacc[j], (ms[0][j]+ms[1][j]+ms[2][j]+ms[3][j])*inv_n);
  }
}

// fused sparse gconv: gather agg (real edges only), 2 matmuls, relu, mean.
__global__ __launch_bounds__(256) void k_gconv_sparse_f(
    const float* __restrict__ X,const int* __restrict__ offD,const int* __restrict__ rowD,
    const int* __restrict__ eidD,int E,
    const float* __restrict__ Wrel,const float* __restrict__ brel,
    const float* __restrict__ Wroot,
    float* __restrict__ XN,int n,float* __restrict__ meanacc,float inv_n)
{
  __shared__ float agg_s[4][65];
  __shared__ float xrow[4][65];
  __shared__ float cnt_s[4];
  const int tid = threadIdx.x;
  const int r = tid>>6, j = tid&63;
  const int i = blockIdx.x*4 + r;
  float a = 0.0f;
  if (i < n){
    int p0 = offD[i], p1 = offD[i+1], c = 0;
    for(int p=p0;p<p1;p++){
      if (eidD[p] < E){ a += X[(size_t)rowD[p]*64 + j]; c++; }
    }
    xrow[r][j] = X[(size_t)i*64 + j];
    if (j == 0) cnt_s[r] = (float)(c>1?c:1);
  }
  agg_s[r][j] = a;
  __syncthreads();
  float v = 0.0f;
  if (i < n){
    float acc=0.0f, rt=0.0f;
    for(int q=0;q<64;q++){
      acc = fmaf(agg_s[r][q], Wrel[q*64+j], acc);
      rt  = fmaf(xrow[r][q],  Wroot[q*64+j], rt);
    }
    v = fmaxf(acc/cnt_s[r] + brel[j] + rt, 0.0f);
    XN[(size_t)i*64 + j] = v;
  }
  __syncthreads();
  agg_s[r][j] = v;
  __syncthreads();
  if (r == 0) atomicAdd(&meanacc[j], (agg_s[0][j]+agg_s[1][j]+agg_s[2][j]+agg_s[3][j])*inv_n);
}

// pool0: xq = segmax gather (incl self) then @pW+pb
__global__ __launch_bounds__(256) void k_xqmaxq(
    const float* __restrict__ X,const int* __restrict__ offD,const int* __restrict__ rowD,
    const float* __restrict__ pWp,const float* __restrict__ pbp,
    float* __restrict__ XQ2,int n)
{
  __shared__ float xq[4][65];
  const int tid = threadIdx.x;
  const int r = tid>>6, j = tid&63;
  const int i = blockIdx.x*4 + r;
  float v = -3.0e38f;
  if (i < n){
    int p0 = offD[i], p1 = offD[i+1];
    for(int p=p0;p<p1;p++) v = fmaxf(v, X[(size_t)rowD[p]*64 + j]);
  }
  xq[r][j] = v;
  __syncthreads();
  if (i < n){
    float s = pbp[j];
    for(int q=0;q<64;q++) s = fmaf(xq[r][q], pWp[q*64+j], s);
    XQ2[(size_t)i*64+j] = s;
  }
}

__global__ void k_edge_score(const int* __restrict__ src,const int* __restrict__ dst,
                             const float* __restrict__ XQ2,const float* __restrict__ X,
                             float* sE,int E,int n){
  int e = blockIdx.x*256+threadIdx.x; if(e>=E+n) return;
  int s,d; edge_sd(e,src,dst,E,s,d);
  const float* q = XQ2 + (size_t)d*64;
  const float* x = X + (size_t)s*64;
  float acc = 0.0f;
  for(int h=0;h<64;h++) acc = fmaf(q[h], x[h], acc);
  sE[e] = acc > 0.0f ? acc : 0.2f*acc;
}

// per-dst softmax over in-edges -> scE; also emits Mt[p] = {rowD[p]*kk, bits(scE)}
__global__ void k_dstsoft(const int* __restrict__ offD,const int* __restrict__ eidD,
                          const int* __restrict__ rowD,
                          const float* __restrict__ sE,float* __restrict__ scE,
                          int2* __restrict__ Mt,int kk,int n){
  int i = blockIdx.x*256+threadIdx.x; if(i>=n) return;
  int p0 = offD[i], p1 = offD[i+1];
  float m = -3.0e38f;
  for(int p=p0;p<p1;p++) m = fmaxf(m, sE[eidD[p]]);
  float d = 0.0f;
  for(int p=p0;p<p1;p++) d += expf(sE[eidD[p]]-m);
  float inv = 1.0f/d;
  for(int p=p0;p<p1;p++){
    int e = eidD[p];
    float v = expf(sE[e]-m)*inv;
    scE[e] = v;
    Mt[p] = make_int2(rowD[p]*kk, __float_as_int(v));
  }
}

// pool0: xc gather + aN/bN/cN; zeroes pcnt
__global__ __launch_bounds__(256) void k_xcabc0(
    const int* __restrict__ offD,const int* __restrict__ rowD,const int* __restrict__ eidD,
    const float* __restrict__ scE,const float* __restrict__ X,
    float* __restrict__ XC,
    const float* __restrict__ w1,const float* bb1,const float* __restrict__ w2,
    const float* __restrict__ w3,const float* bb3,
    float* aN,float* bN,float* cN,int* pcnt,int n)
{
  __shared__ float xc[4][65];
  const int tid = threadIdx.x;
  const int r = tid>>6, j = tid&63;
  const int i = blockIdx.x*4 + r;
  if (blockIdx.x==0 && tid==0) *pcnt = 0;
  float v = 0.0f;
  if (i < n){
    int p0 = offD[i], p1 = offD[i+1];
    for(int p=p0;p<p1;p++) v += scE[eidD[p]] * X[(size_t)rowD[p]*64 + j];
    XC[(size_t)i*64+j] = v;
  }
  xc[r][j] = v;
  __syncthreads();
  if (i < n && j < 3){
    float s = (j==0)?bb1[0]:((j==2)?bb3[0]:0.0f);
    const float* w = (j==0)?w1:((j==1)?w2:w3);
    for(int q=0;q<64;q++) s = fmaf(xc[r][q], w[q], s);
    if(j==0) aN[i]=s; else if(j==1) bN[i]=s; else cN[i]=s;
  }
}

// pool0 fit + zero rank + ipos=-1
__global__ void k_aggfit0(const int* __restrict__ offD,const int* __restrict__ rowD,
                          const float* aN,const float* bN,const float* cN,
                          float* fit,int* __restrict__ rank,int* __restrict__ ipos,int n){
  int i = blockIdx.x*256+threadIdx.x; if(i>=n) return;
  int p0 = offD[i], p1 = offD[i+1];
  float s = 0.0f;
  for(int p=p0;p<p1;p++) s += aN[rowD[p]];
  fit[i] = sigm(s - (float)(p1-p0)*bN[i] + cN[i]);
  rank[i] = 0;
  ipos[i] = -1;
}

// R column-permuted at write time: Rp[i][ipos[c]] += scE  (only kept columns).
__global__ void k_stage1p(const int* src,const int* dst,const int* __restrict__ offS,
                          const int* __restrict__ colS,const int* __restrict__ eidS,
                          const float* __restrict__ scE,const int* __restrict__ ipos,
                          float* Rp,int E,int n,int kk){
  int e = blockIdx.x*256+threadIdx.x; if(e>=E+n) return;
  int i,j; edge_sd(e,src,dst,E,i,j);
  int p0 = offS[j], p1 = offS[j+1];
  float* Ri = Rp + (size_t)i*kk;
  for(int p=p0;p<p1;p++){
    int ip = ipos[colS[p]];
    if (ip >= 0) atomicAdd(&Ri[ip], scE[eidS[p]]);
  }
}
// A_new[u][v] = sum over in-edges of perm[u]: scE * Rp[row][v].
__global__ __launch_bounds__(256) void k_stage2x(
    const int* __restrict__ perm,const int* __restrict__ offD,
    const int2* __restrict__ Mt,
    const float* __restrict__ Rp,float* A,int k,int vw,int cbn){
  const int bid = blockIdx.x;
  const int slice = bid & 7;
  const int rest = bid >> 3;
  const int cb = rest % cbn;
  const int ub = rest / cbn;
  const int u = ub*4 + (threadIdx.x>>6);
  if (u >= k) return;
  const int vbase = slice*vw;
  int vend = vbase + vw; if (vend > k) vend = k;
  const int v = vbase + cb*64 + (threadIdx.x&63);
  const bool vok = v < vend;
  const int vs = vok ? v : vbase;
  const int d = perm[u];
  float acc = 0.0f;
  int p = offD[d];
  const int p1 = offD[d+1];
  for(; p+4 <= p1; p += 4){
    const int2 m0 = Mt[p];
    const int2 m1 = Mt[p+1];
    const int2 m2 = Mt[p+2];
    const int2 m3 = Mt[p+3];
    const float r0 = Rp[m0.x + vs];
    const float r1 = Rp[m1.x + vs];
    const float r2 = Rp[m2.x + vs];
    const float r3 = Rp[m3.x + vs];
    acc = fmaf(__int_as_float(m0.y), r0, acc);
    acc = fmaf(__int_as_float(m1.y), r1, acc);
    acc = fmaf(__int_as_float(m2.y), r2, acc);
    acc = fmaf(__int_as_float(m3.y), r3, acc);
  }
  for(; p < p1; ++p){
    const int2 m = Mt[p];
    acc = fmaf(__int_as_float(m.y), Rp[m.x + vs], acc);
  }
  if (vok) A[(size_t)u*k + v] = (u==v) ? 0.0f : acc;
}

__global__ void k_head2(const float* __restrict__ xs,const float* __restrict__ W1,
                        const float* __restrict__ b1,const float* __restrict__ W2,
                        const float* __restrict__ b2,float* out){
  __shared__ float h2[64];
  __shared__ float lg[10];
  int t = threadIdx.x;
  float s = b1[t];
  for(int q=0;q<640;q++) s = fmaf(xs[q], W1[q*64+t], s);
  h2[t] = fmaxf(s, 0.0f);
  __syncthreads();
  if(t < 10){
    float s2 = b2[t];
    for(int k=0;k<64;k++) s2 = fmaf(h2[k], W2[k*10+t], s2);
    lg[t] = s2;
  }
  __syncthreads();
  if(t == 0){
    float mx = lg[0];
    for(int i=1;i<10;i++) mx = fmaxf(mx, lg[i]);
    float se = 0.0f;
    for(int i=0;i<10;i++) se += expf(lg[i]-mx);
    float lse = mx + logf(se);
    for(int i=0;i<10;i++) out[i] = lg[i]-lse;
  }
}

// ---------------- host orchestration ----------------
extern "C" void kernel_launch(void* const* d_in, const int* in_sizes, int n_in,
                              void* d_out, int out_size, void* d_ws, size_t ws_size,
                              hipStream_t stream) {
  const int N0 = 1500, E = 24000, Z = 16, L = E + N0;
  const float* x0   = (const float*)d_in[0];
  const int* esrc   = (const int*)d_in[1];
  const int* edst   = (const int*)d_in[2];
  const float* W1   = (const float*)d_in[3];  const float* b1   = (const float*)d_in[4];
  const float* W2   = (const float*)d_in[5];  const float* b2   = (const float*)d_in[6];
  const float* W3   = (const float*)d_in[7];  const float* b3   = (const float*)d_in[8];
  const float* Wrel = (const float*)d_in[9];  const float* brel = (const float*)d_in[10];
  const float* Wroot= (const float*)d_in[11];
  const float* pW   = (const float*)d_in[12]; const float* pb   = (const float*)d_in[13];
  const float* leW1 = (const float*)d_in[14]; const float* leb1 = (const float*)d_in[15];
  const float* leW2 = (const float*)d_in[16]; const float* leW3 = (const float*)d_in[17];
  const float* leb3 = (const float*)d_in[18];
  const float* linW1= (const float*)d_in[19]; const float* linb1= (const float*)d_in[20];
  const float* linW2= (const float*)d_in[21]; const float* linb2= (const float*)d_in[22];
  float* out = (float*)d_out;

  float* ws = (float*)d_ws;
  size_t cur = 0;
  auto allocF = [&](size_t nf)->float*{ float* p = ws + cur; cur += (nf + 15) & ~(size_t)15; return p; };
  // contiguous zero block: xs | indeg | outdeg
  float* xs   = allocF(640);
  int* indeg  = (int*)allocF(1504);
  int* outdeg = (int*)allocF(1504);
  float* Xa  = allocF(96000); float* Xb  = allocF(96000); float* Y   = allocF(96000);
  float* XQ2 = allocF(96000); float* XC  = allocF(96000);
  float* mcol = allocF(1504); float* invd = allocF(1504);
  float* aN = allocF(1504); float* bN = allocF(1504); float* cN = allocF(1504);
  float* fit = allocF(1504); float* cntP = allocF(1504);
  int* pcnt = (int*)allocF(16);
  int* perm = (int*)allocF(1504);
  int* offD = (int*)allocF(1504); int* offS = (int*)allocF(1504);
  int* curD = (int*)allocF(1504); int* curS = (int*)allocF(1504);
  int* colS = (int*)allocF(25504); int* eidS = (int*)allocF(25504);
  int* rowD = (int*)allocF(25504); int* eidD = (int*)allocF(25504);
  float* sE = allocF(25504); float* scE = allocF(25504);
  int2* Mt  = (int2*)allocF(51008);
  int* cntp8 = (int*)allocF((size_t)Z*1504);
  float* aggp = allocF(16*1504);
  float* mpart = allocF(16*1504);
  float* spart = allocF(16*1504);
  float* SEGP = allocF((size_t)Z*1504*64);
  float* Rbig = allocF((size_t)1500*1500);   // pool0 Rp; aliased as split-K slab 0 + SCb
  float* SCb  = Rbig;
  float* A0  = allocF((size_t)1350*1350);
  float* A1s = allocF((size_t)1350*1350);
  const size_t SLAB = 1650048;               // >= 1350*1215
  float* PS2 = allocF(SLAB);
  float* PS3 = allocF(SLAB);
  const size_t BFSZ = (size_t)1350*4224/2 + 32;
  ushort* Abf = (ushort*)allocF(BFSZ);
  ushort* Bbf = (ushort*)allocF(BFSZ);
  ushort* Cbf = (ushort*)allocF(BFSZ);
  ushort* Dbf = (ushort*)allocF(BFSZ);
  int* rankb = indeg;                        // dead after k_prefix2

  dim3 B256(256);
  auto G1 = [&](size_t n){ return dim3((unsigned)((n + 255) / 256)); };
  auto ZF = [&](void* p, size_t nfloats){ k_zero<<<G1(nfloats),B256,0,stream>>>((float*)p, nfloats); };
  auto kcz = [&](int K){ return (int)(((K + Z*16 - 1) / (Z*16)) * 16); };

  // ---- prologue: zero (xs+indeg+outdeg contiguous), degrees, CSR ----
  ZF(xs, 640 + 1504 + 1504);
  k_deg<<<G1(E),B256,0,stream>>>(esrc, edst, indeg, outdeg, E);
  k_prefix2<<<dim3((N0+256)/256,2),B256,0,stream>>>(indeg, outdeg, offD, curD, offS, curS, N0);
  k_csr_fill2<<<G1(L),B256,0,stream>>>(esrc, edst, curS, colS, eidS, curD, rowD, eidD, E, N0);

  // ---- FEAST x3 (2 nodes each) ----
  auto feast = [&](const float* xin,int cin,const float* W,const float* bb,int hh,float* xout,float* macc){
    k_mm_small<<<G1((size_t)N0*hh),B256,0,stream>>>(xin, W, nullptr, Y, N0, cin, hh, 0);
    k_feast_gf<<<G1((size_t)N0*hh),B256,0,stream>>>(Y, offD, rowD, bb, xout, N0, hh, macc, 1.0f/N0);
  };
  feast(x0, 16, W1, b1, 32, Xa, nullptr);
  feast(Xa, 32, W2, b2, 64, Xb, nullptr);
  feast(Xb, 64, W3, b3, 64, Xa, xs + 0);
  float* X = Xa; float* XN = Xb;

  // ---- i=0 gconv_sparse (1 node) ----
  k_gconv_sparse_f<<<dim3((N0+3)/4),B256,0,stream>>>(X, offD, rowD, eidD, E, Wrel, brel, Wroot,
                                                     XN, N0, xs + 64, 1.0f/N0);
  { float* t = X; X = XN; XN = t; }

  // ---- pool 0 (sparse ASAP), n=1500 -> k=1350 ----
  {
    const int n = 1500, kk = 1350;
    int* ipos = curD;   // dead after CSR build
    k_xqmaxq<<<dim3((n+3)/4),B256,0,stream>>>(X, offD, rowD, pW, pb, XQ2, n);
    k_edge_score<<<G1(L),B256,0,stream>>>(esrc, edst, XQ2, X, sE, E, n);
    k_dstsoft<<<G1(n),B256,0,stream>>>(offD, eidD, rowD, sE, scE, Mt, kk, n);
    k_xcabc0<<<dim3((n+3)/4),B256,0,stream>>>(offD, rowD, eidD, scE, X, XC,
                                              leW1, leb1, leW2, leW3, leb3, aN, bN, cN, pcnt, n);
    k_aggfit0<<<G1(n),B256,0,stream>>>(offD, rowD, aN, bN, cN, fit, rankb, ipos, n);
    k_rank_cnt<<<dim3((n+255)/256,(n+127)/128),B256,0,stream>>>(fit, rankb, n);
    k_rank_sel<<<dim3((n+3)/4),B256,0,stream>>>(rankb, fit, XC, XN, n, kk, pcnt, perm, ipos);
    ZF(Rbig, (size_t)n*kk);
    k_stage1p<<<G1(L),B256,0,stream>>>(esrc, edst, offS, colS, eidS, scE, ipos, Rbig, E, n, kk);
    {
      const int vw = (kk + 7) / 8;          // 169
      const int cbn = (vw + 63) / 64;       // 3
      const int ubn = (kk + 3) / 4;         // 338
      k_stage2x<<<dim3((unsigned)(8*cbn*ubn)),B256,0,stream>>>(perm, offD, Mt,
                                                               Rbig, A0, kk, vw, cbn);
    }
    { float* t = X; X = XN; XN = t; }
  }

  float* Acur = A0; float* Aoth = A1s;
  int nn = 1350;

  // ---- dense gconv (2 nodes) ----
  auto gconv_dense = [&](int layer){
    dim3 g(1, (nn+63)/64, Z);
    k_skinny<false,true,false,false><<<g,B256,0,stream>>>(Acur, nn, X, nullptr, SEGP, cntp8, nn, nn, kcz(nn));
    k_gconv_fuse<<<dim3((nn+3)/4),B256,0,stream>>>(SEGP, cntp8, Z,
        Wrel + (size_t)layer*4096, brel + layer*64, X, Wroot + (size_t)layer*4096,
        XN, nn, xs + (size_t)(layer+1)*64, 1.0f/nn);
    { float* t = X; X = XN; XN = t; }
  };

  // ---- dense ASAP pool ----
  auto asap_dense = [&](int kk, int p){
    {
      dim3 g(1, (nn+63)/64, Z);
      k_skinny<true,true,false,true><<<g,B256,0,stream>>>(Acur, nn, X, nullptr, SEGP, cntp8, nn, nn, kcz(nn));
    }
    k_poolq<<<dim3((nn+3)/4),B256,0,stream>>>(SEGP, cntp8, Z, pW + (size_t)p*4096, pb + p*64,
                                              X, Abf, Bbf, cntP, nn);
    {
      dim3 g((nn+63)/64, (nn+63)/64);
      k_gemm_mfma<1><<<g,B256,0,stream>>>(Abf, Bbf, SCb, nn, nn, nn, 192, Acur, nn);
    }
    {
      const int chunk = (nn + 15) / 16;
      dim3 gm((nn+15)/16, 16);
      k_smax_pmax<<<gm,B256,0,stream>>>(SCb, nn, chunk, mpart);
      k_smax_psum<<<gm,B256,0,stream>>>(SCb, nn, chunk, mpart, spart);
      k_smax_fin<<<G1(nn),B256,0,stream>>>(mpart, spart, nn, mcol, invd);
    }
    {
      dim3 g(1, (nn+63)/64, Z);
      k_skinny<false,false,true,false><<<g,B256,0,stream>>>(SCb, nn, X, mcol, SEGP, nullptr, nn, nn, kcz(nn));
    }
    k_xcabc_dense<<<dim3((nn+3)/4),B256,0,stream>>>(SEGP, Z, invd, XC,
        leW1 + p*64, leb1 + p, leW2 + p*64, leW3 + p*64, leb3 + p, aN, bN, cN, pcnt, nn);
    k_aggcol<<<G1((size_t)nn*16),B256,0,stream>>>(Acur, aN, aggp, nn);
    k_fit_dense<<<G1(nn),B256,0,stream>>>(aggp, cntP, aN, bN, cN, fit, rankb, pcnt, nn);
    k_rank_cnt<<<dim3((nn+255)/256,(nn+127)/128),B256,0,stream>>>(fit, rankb, nn);
    k_rank_sel<<<dim3((nn+3)/4),B256,0,stream>>>(rankb, fit, XC, XN, nn, kk, pcnt, perm, nullptr);
    const int Kp = (nn + 63) & ~63;
    const int K3 = 3*Kp;
    k_split3<<<G1((size_t)nn*Kp),B256,0,stream>>>(Acur, nn, nn, nn, Abf, Kp, 0);
    { dim3 gt((kk+31)/32, Kp/32);
      k_split3_Tdual<<<gt,B256,0,stream>>>(SCb, nn, kk, nn, perm, invd, mcol, Dbf, Bbf, Cbf, Kp); }
    // ---- TB = A@Sp + Sp : split-K x4 (128x128 tiles, K-step 64, XCD swizzle) ----
    const int Tk = K3 >> 6;
    const int kchunk = ((Tk + 3) >> 2) << 6;
    {
      dim3 g((kk+127)/128, (nn+127)/128, 4);
      k_gemm_pp<<<g,B256,0,stream>>>(Abf, Bbf, Rbig, Aoth, PS2, PS3, kk, nn, kk, K3, kchunk);
      dim3 gr((kk+31)/32, (nn+31)/32);
      k_red_tb<<<gr,B256,0,stream>>>(Rbig, Aoth, PS2, PS3, kk, Bbf, Cbf, nn, kk, Kp);
    }
    // ---- A_new = Sp^T @ TB (zero diag): split-K x4 (output Aoth aliases slab 1: safe) ----
    {
      dim3 g((kk+127)/128, (kk+127)/128, 4);
      k_gemm_pp<<<g,B256,0,stream>>>(Dbf, Cbf, Rbig, Aoth, PS2, PS3, kk, kk, kk, K3, kchunk);
      k_red_diag<<<G1((size_t)kk*kk),B256,0,stream>>>(Rbig, Aoth, PS2, PS3, Aoth, kk);
    }
    { float* t = X; X = XN; XN = t; }
    { float* t = Acur; Acur = Aoth; Aoth = t; }
    nn = kk;
  };

  gconv_dense(1);
  gconv_dense(2);
  asap_dense(1215, 1);
  gconv_dense(3);
  gconv_dense(4);
  asap_dense(1094, 2);
  gconv_dense(5);
  gconv_dense(6);
  asap_dense(985, 3);
  gconv_dense(7);
  gconv_dense(8);

  // ---- head (1 node) ----
  k_head2<<<1,64,0,stream>>>(xs, linW1, linb1, linW2, linb2, out);
}

// Round 11
// 1266.022 us; speedup vs baseline: 1.0790x; 1.0166x over previous
//
#include <hip/hip_runtime.h>
#include <math.h>

#define NEGV -1000000000.0f

typedef short short8 __attribute__((ext_vector_type(8)));
typedef float floatx4 __attribute__((ext_vector_type(4)));

__device__ __forceinline__ float sigm(float x){ return 1.0f/(1.0f+expf(-x)); }
__device__ __forceinline__ void edge_sd(int e,const int* src,const int* dst,int E,int& s,int& d){
  if(e<E){ s=src[e]; d=dst[e]; } else { s=e-E; d=s; }
}
__device__ __forceinline__ ushort bf16rn(float x){
  unsigned u = __float_as_uint(x);
  unsigned r = (u + 0x7fffu + ((u>>16)&1u)) >> 16;
  return (ushort)r;
}
__device__ __forceinline__ float bf16f(ushort h){ return __uint_as_float(((unsigned)h)<<16); }

__global__ void k_zero(float* __restrict__ p, size_t n){
  size_t i = (size_t)blockIdx.x*256 + threadIdx.x;
  if (i < n) p[i] = 0.0f;
}

// ---------------- bf16x3 conversions ----------------
__global__ void k_split3(const float* __restrict__ src,int R,int Cs,int ld,
                         ushort* __restrict__ dst,int Cp,int bmode){
  int idx = blockIdx.x*256+threadIdx.x;
  if (idx >= R*Cp) return;
  int r = idx / Cp, c = idx - r*Cp;
  float x = (c < Cs) ? src[(size_t)r*ld + c] : 0.0f;
  ushort h = bf16rn(x);
  ushort l = bf16rn(x - bf16f(h));
  size_t base = (size_t)r*(3*Cp) + c;
  dst[base]        = h;
  dst[base + Cp]   = bmode ? l : h;
  dst[base + 2*Cp] = bmode ? h : l;
}
// Sp = exp(src[:,perm]-mcol[perm])*invd[perm], transposed to K-innermost; writes BOTH
// A-role (dstA) and B-role (dstB); zero-pads k>=Rs rows in dstA/dstB AND dstCpad.
__global__ void k_split3_Tdual(const float* __restrict__ src,int Rs,int Cs,int ld,
                               const int* __restrict__ gperm,const float* __restrict__ cscale,
                               const float* __restrict__ emax,
                               ushort* __restrict__ dstA,ushort* __restrict__ dstB,
                               ushort* __restrict__ dstCpad,int Kp){
  __shared__ float t[32][33];
  int tx = threadIdx.x & 31, ty = threadIdx.x >> 5;
  int kb = blockIdx.y*32, xb = blockIdx.x*32;
  int x = xb + tx;
  int gx = (x < Cs) ? gperm[x] : 0;
#pragma unroll
  for (int i=0;i<4;i++){
    int k = kb + ty + i*8;
    t[ty+i*8][tx] = (k < Rs && x < Cs) ? src[(size_t)k*ld + gx] : 0.0f;
  }
  __syncthreads();
  const int K3 = 3*Kp;
#pragma unroll
  for (int i=0;i<4;i++){
    int xo = xb + ty + i*8, ko = kb + tx;
    if (xo < Cs){
      float v = 0.0f;
      if (ko < Rs){
        int g = gperm[xo];
        v = expf(t[tx][ty+i*8] - emax[g]) * cscale[g];
      }
      ushort h = bf16rn(v);
      ushort l = bf16rn(v - bf16f(h));
      size_t base = (size_t)xo*K3 + ko;
      dstA[base] = h; dstA[base+Kp] = h; dstA[base+2*Kp] = l;
      dstB[base] = h; dstB[base+Kp] = l; dstB[base+2*Kp] = h;
      if (ko >= Rs){ dstCpad[base]=0; dstCpad[base+Kp]=0; dstCpad[base+2*Kp]=0; }
    }
  }
}

// ---------------- MFMA bf16 GEMM (64x64 tile, K-step 64, double-buffered) ----------------
// EPI 1: mask(A+I)+leakyrelu.  (Used for the score GEMM, K3=192.)
template<int EPI>
__global__ __launch_bounds__(256) void k_gemm_mfma(
    const ushort* __restrict__ A, const ushort* __restrict__ B,
    float* __restrict__ C, int ldc, int M, int N, int K3,
    const float* __restrict__ mask, int ldm)
{
  __shared__ ushort As[2][64][72];
  __shared__ ushort Bs[2][64][72];
  const int tid = threadIdx.x;
  const int m0 = blockIdx.y*64, n0 = blockIdx.x*64;
  const int w = tid>>6, lane = tid&63;
  const int lo4 = lane&15, quad = lane>>4;
  const int sr = tid>>2, sseg = tid&3;

  floatx4 acc[4];
#pragma unroll
  for(int c=0;c<4;c++){ acc[c][0]=0.f; acc[c][1]=0.f; acc[c][2]=0.f; acc[c][3]=0.f; }

  const size_t arow = (size_t)(m0+sr)*K3;
  const size_t brow = (size_t)(n0+sr)*K3;
  const bool aval = (m0+sr) < M;
  const bool bval = (n0+sr) < N;

  uint4 av0 = make_uint4(0,0,0,0), av1 = make_uint4(0,0,0,0);
  uint4 bv0 = make_uint4(0,0,0,0), bv1 = make_uint4(0,0,0,0);
  if (aval){ av0 = *(const uint4*)(A + arow + sseg*8);
             av1 = *(const uint4*)(A + arow + 32 + sseg*8); }
  if (bval){ bv0 = *(const uint4*)(B + brow + sseg*8);
             bv1 = *(const uint4*)(B + brow + 32 + sseg*8); }
  *(uint4*)&As[0][sr][sseg*8] = av0; *(uint4*)&As[0][sr][32+sseg*8] = av1;
  *(uint4*)&Bs[0][sr][sseg*8] = bv0; *(uint4*)&Bs[0][sr][32+sseg*8] = bv1;
  __syncthreads();

  const int T = K3 >> 6;
  for (int i=0;i<T;i++){
    const int cb = i & 1;
    if (i+1 < T){
      const int k0 = (i+1)<<6;
      av0 = make_uint4(0,0,0,0); av1 = make_uint4(0,0,0,0);
      bv0 = make_uint4(0,0,0,0); bv1 = make_uint4(0,0,0,0);
      if (aval){ av0 = *(const uint4*)(A + arow + k0 + sseg*8);
                 av1 = *(const uint4*)(A + arow + k0 + 32 + sseg*8); }
      if (bval){ bv0 = *(const uint4*)(B + brow + k0 + sseg*8);
                 bv1 = *(const uint4*)(B + brow + k0 + 32 + sseg*8); }
    }
    short8 af0 = *(const short8*)&As[cb][16*w + lo4][quad*8];
    short8 af1 = *(const short8*)&As[cb][16*w + lo4][32+quad*8];
#pragma unroll
    for (int c=0;c<4;c++){
      short8 bf0 = *(const short8*)&Bs[cb][16*c + lo4][quad*8];
      acc[c] = __builtin_amdgcn_mfma_f32_16x16x32_bf16(af0, bf0, acc[c], 0, 0, 0);
      short8 bf1 = *(const short8*)&Bs[cb][16*c + lo4][32+quad*8];
      acc[c] = __builtin_amdgcn_mfma_f32_16x16x32_bf16(af1, bf1, acc[c], 0, 0, 0);
    }
    if (i+1 < T){
      __syncthreads();
      *(uint4*)&As[1-cb][sr][sseg*8] = av0; *(uint4*)&As[1-cb][sr][32+sseg*8] = av1;
      *(uint4*)&Bs[1-cb][sr][sseg*8] = bv0; *(uint4*)&Bs[1-cb][sr][32+sseg*8] = bv1;
      __syncthreads();
    }
  }

#pragma unroll
  for (int c=0;c<4;c++){
    const int gn = n0 + 16*c + lo4;
#pragma unroll
    for (int r=0;r<4;r++){
      const int gm = m0 + 16*w + quad*4 + r;
      if (gm < M && gn < N){
        float v = acc[c][r];
        if (EPI==1) v = (mask[(size_t)gm*ldm+gn] != 0.0f || gm==gn) ? (v > 0.0f ? v : 0.2f*v) : NEGV;
        C[(size_t)gm*ldc+gn] = v;
      }
    }
  }
}

// ---------------- split-K x4 MFMA partial-product GEMM, 128x128 tile ----------------
// K-step 64 (measured best). 4 waves, each owns a 64x64 output quadrant.
// XCD-chunked bijective swizzle. blockIdx.z selects a K-chunk.
__global__ __launch_bounds__(256) void k_gemm_pp(
    const ushort* __restrict__ A, const ushort* __restrict__ B,
    float* __restrict__ P0, float* __restrict__ P1,
    float* __restrict__ P2, float* __restrict__ P3, int ldp,
    int M, int N, int K3, int kchunk)
{
  __shared__ ushort As[2][128][72];
  __shared__ ushort Bs[2][128][72];
  const int tid = threadIdx.x;

  // ---- XCD-chunked bijective block remap ----
  const int gx = gridDim.x, gxy = gridDim.x*gridDim.y;
  const int TT = gxy*gridDim.z;
  const int s  = blockIdx.x + gx*blockIdx.y + gxy*blockIdx.z;
  const int c8 = s & 7, u = s >> 3;
  const int q = TT >> 3, r8 = TT & 7;
  const int w0 = (c8 < r8) ? c8*(q+1) + u : r8*(q+1) + (c8 - r8)*q + u;
  const int z  = w0 / gxy;
  const int lin = w0 - z*gxy;
  const int ty = lin / gx, tx = lin - ty*gx;

  const int m0 = ty*128, n0 = tx*128;
  const int w = tid>>6, lane = tid&63;
  const int lo4 = lane&15, quad = lane>>4;
  const int wr = w>>1, wc = w&1;

  // staging: thread t -> row t>>1, half t&1 (32 ushort = 4x uint4 per operand)
  const int srow = tid>>1, shalf = tid&1;

  float* __restrict__ P = (z==0) ? P0 : (z==1) ? P1 : (z==2) ? P2 : P3;
  const int kbeg = z * kchunk;
  int klen = K3 - kbeg; if (klen > kchunk) klen = kchunk; if (klen < 0) klen = 0;
  const int T = klen >> 6;

  floatx4 acc[4][4];
#pragma unroll
  for(int i=0;i<4;i++)
#pragma unroll
    for(int c=0;c<4;c++){ acc[i][c][0]=0.f; acc[i][c][1]=0.f; acc[i][c][2]=0.f; acc[i][c][3]=0.f; }

  const size_t arow = (size_t)(m0+srow)*K3 + kbeg + shalf*32;
  const size_t brow = (size_t)(n0+srow)*K3 + kbeg + shalf*32;
  const bool aval = (m0+srow) < M;
  const bool bval = (n0+srow) < N;
  const int sbase = shalf*32;

  uint4 apre[4], bpre[4];
#pragma unroll
  for(int s2=0;s2<4;s2++){ apre[s2]=make_uint4(0,0,0,0); bpre[s2]=make_uint4(0,0,0,0); }
  if (aval){
#pragma unroll
    for(int s2=0;s2<4;s2++) apre[s2] = *(const uint4*)(A + arow + s2*8);
  }
  if (bval){
#pragma unroll
    for(int s2=0;s2<4;s2++) bpre[s2] = *(const uint4*)(B + brow + s2*8);
  }
#pragma unroll
  for(int s2=0;s2<4;s2++){
    *(uint4*)&As[0][srow][sbase + s2*8] = apre[s2];
    *(uint4*)&Bs[0][srow][sbase + s2*8] = bpre[s2];
  }
  __syncthreads();

  for (int it=0; it<T; ++it){
    const int cb = it & 1;
    if (it+1 < T){
      const int k0 = (it+1)<<6;
#pragma unroll
      for(int s2=0;s2<4;s2++){ apre[s2]=make_uint4(0,0,0,0); bpre[s2]=make_uint4(0,0,0,0); }
      if (aval){
#pragma unroll
        for(int s2=0;s2<4;s2++) apre[s2] = *(const uint4*)(A + arow + k0 + s2*8);
      }
      if (bval){
#pragma unroll
        for(int s2=0;s2<4;s2++) bpre[s2] = *(const uint4*)(B + brow + k0 + s2*8);
      }
    }
    short8 af[4][2];
#pragma unroll
    for(int i=0;i<4;i++){
      af[i][0] = *(const short8*)&As[cb][wr*64 + 16*i + lo4][quad*8];
      af[i][1] = *(const short8*)&As[cb][wr*64 + 16*i + lo4][32 + quad*8];
    }
#pragma unroll
    for(int c=0;c<4;c++){
      short8 bf0 = *(const short8*)&Bs[cb][wc*64 + 16*c + lo4][quad*8];
      short8 bf1 = *(const short8*)&Bs[cb][wc*64 + 16*c + lo4][32 + quad*8];
#pragma unroll
      for(int i=0;i<4;i++){
        acc[i][c] = __builtin_amdgcn_mfma_f32_16x16x32_bf16(af[i][0], bf0, acc[i][c], 0, 0, 0);
        acc[i][c] = __builtin_amdgcn_mfma_f32_16x16x32_bf16(af[i][1], bf1, acc[i][c], 0, 0, 0);
      }
    }
    if (it+1 < T){
      __syncthreads();
#pragma unroll
      for(int s2=0;s2<4;s2++){
        *(uint4*)&As[1-cb][srow][sbase + s2*8] = apre[s2];
        *(uint4*)&Bs[1-cb][srow][sbase + s2*8] = bpre[s2];
      }
      __syncthreads();
    }
  }

#pragma unroll
  for(int c=0;c<4;c++){
    const int gn = n0 + wc*64 + 16*c + lo4;
    if (gn < N){
#pragma unroll
      for(int i=0;i<4;i++){
#pragma unroll
        for(int r=0;r<4;r++){
          const int gm = m0 + wr*64 + 16*i + quad*4 + r;
          if (gm < M) P[(size_t)gm*ldp+gn] = acc[i][c][r];
        }
      }
    }
  }
}

// reduce 4 TB slabs + Sp, transpose-store as bf16x3 B-role (h,l,h) at gn*K3o+gm.
__global__ __launch_bounds__(256) void k_red_tb(
    const float* __restrict__ P0,const float* __restrict__ P1,
    const float* __restrict__ P2,const float* __restrict__ P3,int ldp,
    const ushort* __restrict__ Bb, ushort* __restrict__ Cb,
    int M,int N,int Kp)
{
  __shared__ float t[32][33];
  const int tx = threadIdx.x & 31, ty = threadIdx.x >> 5;
  const int mb = blockIdx.y*32, nb = blockIdx.x*32;
  const int n = nb + tx;
#pragma unroll
  for (int i=0;i<4;i++){
    int m = mb + ty + i*8;
    float v = 0.0f;
    if (m < M && n < N){
      size_t o = (size_t)m*ldp + n;
      v = (P0[o] + P1[o]) + (P2[o] + P3[o]);
    }
    t[ty+i*8][tx] = v;
  }
  __syncthreads();
  const int K3o = 3*Kp;
#pragma unroll
  for (int i=0;i<4;i++){
    int no = nb + ty + i*8, mo = mb + tx;
    if (no < N && mo < M){
      size_t base = (size_t)no*K3o + mo;
      float sp = bf16f(Bb[base]) + bf16f(Bb[base+Kp]);
      float v = t[tx][ty+i*8] + sp;
      ushort h = bf16rn(v), l = bf16rn(v - bf16f(h));
      Cb[base] = h; Cb[base+Kp] = l; Cb[base+2*Kp] = h;
    }
  }
}

// reduce 4 A_new slabs + zero diagonal. (C may alias one of the slabs: per-element
// read-then-write, no cross-thread sharing -> safe.)
__global__ void k_red_diag(const float* __restrict__ P0,const float* __restrict__ P1,
                           const float* __restrict__ P2,const float* __restrict__ P3,
                           float* __restrict__ C,int kk){
  int idx = blockIdx.x*256+threadIdx.x;
  if (idx >= kk*kk) return;
  int u = idx/kk, v = idx - u*kk;
  float s = (P0[idx] + P1[idx]) + (P2[idx] + P3[idx]);
  C[idx] = (u==v) ? 0.0f : s;
}

// ---------------- atomic-free skinny agg GEMM ----------------
template<bool MAXM, bool COUNT, bool EXPM, bool SELF>
__global__ __launch_bounds__(256) void k_skinny(
    const float* __restrict__ A, int lda,
    const float* __restrict__ X,
    const float* __restrict__ mcol,
    float* __restrict__ P, int* __restrict__ cntp,
    int M, int K, int kchunk)
{
  __shared__ float As[16][68];
  __shared__ float Xs[16][68];
  const int tid = threadIdx.x;
  const int m0 = blockIdx.y * 64;
  const int tmb = (tid & 15) * 4, tnb = (tid >> 4) * 4;
  float acc[4][4];
  int cacc[4] = {0,0,0,0};
#pragma unroll
  for (int i=0;i<4;i++)
#pragma unroll
    for (int j=0;j<4;j++) acc[i][j] = MAXM ? NEGV : 0.0f;

  const int kstart = blockIdx.z * kchunk;
  int kend = kstart + kchunk; if (kend > K) kend = K;
  const int ml = tid & 63, tb = tid >> 6;
  const bool mvalid = (m0 + ml) < M;
  float mc = 0.0f;
  if (EXPM && mvalid) mc = mcol[m0 + ml];

  for (int k0 = kstart; k0 < kend; k0 += 16) {
#pragma unroll
    for (int s=0;s<4;s++) {
      const int tk = tb + s*4;
      float va = 0.0f, vx = 0.0f;
      if ((k0+tk) < K) {
        if (mvalid){
          va = A[(size_t)(k0+tk)*lda + m0 + ml];
          if (EXPM) va = expf(va - mc);
        }
        vx = X[(size_t)(k0+tk)*64 + ml];
      }
      As[tk][ml] = va;
      Xs[tk][ml] = vx;
    }
    __syncthreads();
#pragma unroll
    for (int kk=0; kk<16; kk++) {
      const float4 a4 = *(const float4*)&As[kk][tmb];
      const float4 b4 = *(const float4*)&Xs[kk][tnb];
      const float av[4] = {a4.x,a4.y,a4.z,a4.w};
      const float bv[4] = {b4.x,b4.y,b4.z,b4.w};
#pragma unroll
      for (int i=0;i<4;i++){
        if (COUNT) cacc[i] += (av[i] != 0.0f) ? 1 : 0;
#pragma unroll
        for (int j=0;j<4;j++) {
          if (MAXM) acc[i][j] = fmaxf(acc[i][j], av[i] != 0.0f ? bv[j] : NEGV);
          else      acc[i][j] = fmaf(av[i], bv[j], acc[i][j]);
        }
      }
    }
    __syncthreads();
  }

  const size_t slab = (size_t)blockIdx.z * M * 64;
#pragma unroll
  for (int i=0;i<4;i++){
    const int m = m0 + tmb + i;
    if (m < M){
#pragma unroll
      for (int j=0;j<4;j++){
        float v = acc[i][j];
        if (SELF) v = fmaxf(v, X[(size_t)m*64 + tnb + j]);
        P[slab + (size_t)m*64 + tnb + j] = v;
      }
    }
  }
  if (COUNT && tnb == 0){
#pragma unroll
    for (int i=0;i<4;i++){
      const int m = m0 + tmb + i;
      if (m < M) cntp[blockIdx.z*M + m] = cacc[i];
    }
  }
}

// slab max-reduce -> xq; xq2 = xq@pW+pb; cntP = 1 + sum counts.
// Also emits bf16x3 operands: dstA (A-role from X), dstB (B-role from xq2).
__global__ __launch_bounds__(256) void k_poolq(
    const float* __restrict__ SEGP,const int* __restrict__ cntp8,int Z,
    const float* __restrict__ pWp,const float* __restrict__ pbp,
    const float* __restrict__ X,
    ushort* __restrict__ dstA,ushort* __restrict__ dstB,
    float* __restrict__ cntP,int n)
{
  __shared__ float xq[4][65];
  const int tid = threadIdx.x;
  const int r = tid>>6, j = tid&63;
  const int i = blockIdx.x*4 + r;
  float v = NEGV;
  if (i < n){
    for(int z=0;z<Z;z++) v = fmaxf(v, SEGP[(size_t)z*n*64 + (size_t)i*64 + j]);
    if (j == 0){
      int c=1; for(int z=0;z<Z;z++) c += cntp8[z*n+i];
      cntP[i] = (float)c;
    }
  }
  xq[r][j] = v;
  __syncthreads();
  if (i < n){
    float s = pbp[j];
    for(int q=0;q<64;q++) s = fmaf(xq[r][q], pWp[q*64+j], s);
    size_t base = (size_t)i*192 + j;
    ushort h = bf16rn(s), l = bf16rn(s - bf16f(h));
    dstB[base] = h; dstB[base+64] = l; dstB[base+128] = h;
    float x = X[(size_t)i*64 + j];
    h = bf16rn(x); l = bf16rn(x - bf16f(h));
    dstA[base] = h; dstA[base+64] = h; dstA[base+128] = l;
  }
}

// fused dense gconv: reduce slabs, two 64x64 matmuls, relu, mean-accumulate.
__global__ __launch_bounds__(256) void k_gconv_fuse(
    const float* __restrict__ SEGP,const int* __restrict__ cntp8,int Z,
    const float* __restrict__ Wrel,const float* __restrict__ brel,
    const float* __restrict__ X,const float* __restrict__ Wroot,
    float* __restrict__ XN,int n,float* __restrict__ meanacc,float inv_n)
{
  __shared__ float agg_s[4][65];
  __shared__ float xrow[4][65];
  __shared__ float cnt_s[4];
  const int tid = threadIdx.x;
  const int r = tid>>6, j = tid&63;
  const int i = blockIdx.x*4 + r;
  float a = 0.0f;
  if (i < n){
    for(int z=0;z<Z;z++) a += SEGP[(size_t)z*n*64 + (size_t)i*64 + j];
    xrow[r][j] = X[(size_t)i*64 + j];
    if (j == 0){
      int c=0; for(int z=0;z<Z;z++) c += cntp8[z*n+i];
      cnt_s[r] = (float)(c>1?c:1);
    }
  }
  agg_s[r][j] = a;
  __syncthreads();
  float v = 0.0f;
  if (i < n){
    float acc=0.0f, rt=0.0f;
    for(int q=0;q<64;q++){
      acc = fmaf(agg_s[r][q], Wrel[q*64+j], acc);
      rt  = fmaf(xrow[r][q],  Wroot[q*64+j], rt);
    }
    v = fmaxf(acc/cnt_s[r] + brel[j] + rt, 0.0f);
    XN[(size_t)i*64 + j] = v;
  }
  __syncthreads();
  agg_s[r][j] = v;
  __syncthreads();
  if (r == 0) atomicAdd(&meanacc[j], (agg_s[0][j]+agg_s[1][j]+agg_s[2][j]+agg_s[3][j])*inv_n);
}

// ---------------- row-chunked column softmax stats (3 kernels, 16x parallelism) ----------------
__global__ __launch_bounds__(256) void k_smax_pmax(const float* __restrict__ S,int n,int chunk,
                                                   float* __restrict__ mpart){
  __shared__ float red[16][17];
  const int jc = threadIdx.x & 15, rg = threadIdx.x >> 4;
  const int j = blockIdx.x*16 + jc;
  const int z = blockIdx.y;
  const int i0 = z*chunk;
  int i1 = i0 + chunk; if (i1 > n) i1 = n;
  float m = -3.0e38f;
  if (j < n)
    for(int i=i0+rg;i<i1;i+=16) m = fmaxf(m, S[(size_t)i*n+j]);
  red[rg][jc] = m;
  __syncthreads();
  for(int s=8;s>0;s>>=1){
    if(rg<s) red[rg][jc] = fmaxf(red[rg][jc], red[rg+s][jc]);
    __syncthreads();
  }
  if (rg==0 && j<n) mpart[(size_t)z*n + j] = red[0][jc];
}
__global__ __launch_bounds__(256) void k_smax_psum(const float* __restrict__ S,int n,int chunk,
                                                   const float* __restrict__ mpart,
                                                   float* __restrict__ spart){
  __shared__ float red[16][17];
  const int jc = threadIdx.x & 15, rg = threadIdx.x >> 4;
  const int j = blockIdx.x*16 + jc;
  const int z = blockIdx.y;
  float mv = -3.0e38f;
  if (j < n) mv = mpart[(size_t)rg*n + j];
  red[rg][jc] = mv;
  __syncthreads();
  for(int s=8;s>0;s>>=1){
    if(rg<s) red[rg][jc] = fmaxf(red[rg][jc], red[rg+s][jc]);
    __syncthreads();
  }
  const float mc = red[0][jc];
  __syncthreads();
  const int i0 = z*chunk;
  int i1 = i0 + chunk; if (i1 > n) i1 = n;
  float sum = 0.0f;
  if (j < n)
    for(int i=i0+rg;i<i1;i+=16) sum += expf(S[(size_t)i*n+j]-mc);
  red[rg][jc] = sum;
  __syncthreads();
  for(int s=8;s>0;s>>=1){
    if(rg<s) red[rg][jc] += red[rg+s][jc];
    __syncthreads();
  }
  if (rg==0 && j<n) spart[(size_t)z*n + j] = red[0][jc];
}
__global__ void k_smax_fin(const float* __restrict__ mpart,const float* __restrict__ spart,
                           int n,float* __restrict__ mcol,float* __restrict__ invd){
  int j = blockIdx.x*256+threadIdx.x; if(j>=n) return;
  float m = mpart[j];
  for(int z=1;z<16;z++) m = fmaxf(m, mpart[(size_t)z*n+j]);
  mcol[j] = m;
  float s = 0.0f;
  for(int z=0;z<16;z++) s += spart[(size_t)z*n+j];
  invd[j] = 1.0f/s;
}

// slab sum * invd -> XC; then aN/bN/cN per row; zeroes pcnt.
__global__ __launch_bounds__(256) void k_xcabc_dense(
    const float* __restrict__ SEGP,int Z,const float* __restrict__ invd,
    float* __restrict__ XC,
    const float* __restrict__ w1,const float* bb1,const float* __restrict__ w2,
    const float* __restrict__ w3,const float* bb3,
    float* aN,float* bN,float* cN,int* pcnt,int n)
{
  __shared__ float xc[4][65];
  const int tid = threadIdx.x;
  const int r = tid>>6, j = tid&63;
  const int i = blockIdx.x*4 + r;
  if (blockIdx.x==0 && tid==0) *pcnt = 0;
  float v = 0.0f;
  if (i < n){
    for(int z=0;z<Z;z++) v += SEGP[(size_t)z*n*64 + (size_t)i*64 + j];
    v *= invd[i];
    XC[(size_t)i*64+j] = v;
  }
  xc[r][j] = v;
  __syncthreads();
  if (i < n && j < 3){
    float s = (j==0)?bb1[0]:((j==2)?bb3[0]:0.0f);
    const float* w = (j==0)?w1:((j==1)?w2:w3);
    for(int q=0;q<64;q++) s = fmaf(xc[r][q], w[q], s);
    if(j==0) aN[i]=s; else if(j==1) bN[i]=s; else cN[i]=s;
  }
}

// R10: 64 row-chunks (was 16) -> 4x blocks; k_aggcol ran at 0.33 blocks/CU.
__global__ void k_aggcol(const float* __restrict__ A,const float* __restrict__ aN,
                         float* __restrict__ aggp,int n){
  int idx = blockIdx.x*256+threadIdx.x; if(idx>=n*64) return;
  int j = idx % n, c = idx / n;
  int i0 = (int)(((long long)n*c)/64), i1 = (int)(((long long)n*(c+1))/64);
  float s = 0.0f;
  for(int i=i0;i<i1;i++) if(A[(size_t)i*n + j] != 0.0f) s += aN[i];
  aggp[c*n + j] = s;
}

// ---------------- parallel top-k rank ----------------
__global__ void k_fit_dense(const float* __restrict__ aggp,const float* __restrict__ cntP,
                            const float* __restrict__ aN,const float* __restrict__ bN,
                            const float* __restrict__ cN,
                            float* __restrict__ fit,int* __restrict__ rank,int* pcnt,int n){
  int u = blockIdx.x*256+threadIdx.x;
  if (blockIdx.x==0 && threadIdx.x==0) *pcnt = 0;
  if (u >= n) return;
  float a = aN[u];
  for(int c=0;c<64;c++) a += aggp[c*n+u];
  fit[u] = sigm(a - cntP[u]*bN[u] + cN[u]);
  rank[u] = 0;
}
__global__ __launch_bounds__(256) void k_rank_cnt(const float* __restrict__ fit,
                                                  int* __restrict__ rank,int n){
  __shared__ float fsc[128];
  const int u0 = blockIdx.y*128;
  int u1 = u0+128; if (u1 > n) u1 = n;
  const int cl = u1 - u0;
  if ((int)threadIdx.x < cl) fsc[threadIdx.x] = fit[u0+threadIdx.x];
  __syncthreads();
  const int v = blockIdx.x*256+threadIdx.x;
  if (v >= n) return;
  const float fv = fit[v];
  int r = 0;
  for(int t=0;t<cl;t++){
    const float fu = fsc[t];
    const int u = u0+t;
    r += (fu > fv || (fu == fv && u < v)) ? 1 : 0;
  }
  atomicAdd(&rank[v], r);
}
// Selection + coalesced XN write; optionally records inverse perm (ipos[v]=slot).
__global__ __launch_bounds__(256) void k_rank_sel(const int* __restrict__ rank,
    const float* __restrict__ fit,const float* __restrict__ XC,float* __restrict__ XN,
    int n,int k,int* pcnt,int* perm,int* __restrict__ ipos){
  __shared__ int ps[4];
  const int r = threadIdx.x>>6, h = threadIdx.x&63;
  const int v = blockIdx.x*4 + r;
  const bool sel = (v < n) && (rank[v] < k);
  if (h == 0 && sel){
    int p = atomicAdd(pcnt,1);
    ps[r] = p;
    perm[p] = v;
    if (ipos) ipos[v] = p;
  }
  __syncthreads();
  if (sel){
    const int p = ps[r];
    XN[(size_t)p*64 + h] = XC[(size_t)v*64 + h] * fit[v];
  }
}

// ---------------- prologue: degrees + CSR over L=E+n edges (incl self) ----------------
__global__ void k_deg(const int* __restrict__ src,const int* __restrict__ dst,int* indeg,int* outdeg,int E){
  int e = blockIdx.x*256+threadIdx.x; if(e>=E) return;
  atomicAdd(&indeg[dst[e]],1); atomicAdd(&outdeg[src[e]],1);
}
__global__ __launch_bounds__(256) void k_prefix2(const int* __restrict__ indeg,const int* __restrict__ outdeg,
                          int* offD,int* curD,int* offS,int* curS,int n){
  __shared__ int ds[1504];
  const int* dsrc = blockIdx.y ? outdeg : indeg;
  for(int u=threadIdx.x; u<n; u+=256) ds[u] = dsrc[u];
  __syncthreads();
  int t = blockIdx.x*256+threadIdx.x; if(t>n) return;
  int s = 0;
  for(int u=0;u<t;u++) s += ds[u]+1;
  if (blockIdx.y){ offS[t]=s; if(t<n) curS[t]=s; }
  else           { offD[t]=s; if(t<n) curD[t]=s; }
}
__global__ void k_csr_fill2(const int* src,const int* dst,
                            int* curS,int* colS,int* eidS,
                            int* curD,int* rowD,int* eidD,int E,int n){
  int e = blockIdx.x*256+threadIdx.x; if(e>=E+n) return;
  int s,d; edge_sd(e,src,dst,E,s,d);
  int p = atomicAdd(&curS[s],1); colS[p]=d; eidS[p]=e;
  int q = atomicAdd(&curD[d],1); rowD[q]=s; eidD[q]=e;
}

__global__ void k_mm_small(const float* __restrict__ A,const float* __restrict__ W,
                           const float* __restrict__ b,float* __restrict__ C,
                           int M,int K,int Np,int act){
  int idx = blockIdx.x*256+threadIdx.x; if(idx>=M*Np) return;
  int m = idx/Np, j = idx - m*Np;
  float s = b ? b[j] : 0.0f;
  const float* a = A + (size_t)m*K;
  for(int q=0;q<K;q++) s = fmaf(a[q], W[(size_t)q*Np + j], s);
  if(act==1) s = fmaxf(s, 0.0f);
  C[idx] = s;
}

// feast: gather-mean over in-edges (incl self), +b, elu; optional mean (H==64)
__global__ void k_feast_gf(const float* __restrict__ Y,const int* __restrict__ offD,
                           const int* __restrict__ rowD,
                           const float* __restrict__ b,float* X,int n,int H,
                           float* __restrict__ meanacc,float inv_n){
  __shared__ float ms[4][64];
  int idx = blockIdx.x*256+threadIdx.x;
  float v = 0.0f;
  if(idx<n*H){
    int i = idx/H, h = idx - i*H;
    int p0 = offD[i], p1 = offD[i+1];
    float s = 0.0f;
    for(int p=p0;p<p1;p++) s += Y[(size_t)rowD[p]*H + h];
    float t = s/(float)(p1-p0) + b[h];
    v = t > 0.0f ? t : (expf(t)-1.0f);
    X[idx] = v;
  }
  if(meanacc){
    int r = threadIdx.x>>6, j = threadIdx.x&63;
    ms[r][j] = (idx<n*H) ? v : 0.0f;
    __syncthreads();
    if(r==0) atomicAdd(&meanacc[j], (ms[0][j]+ms[1][j]+ms[2][j]+ms[3][j])*inv_n);
  }
}

// fused sparse gconv: gather agg (real edges only), 2 matmuls, relu, mean.
__global__ __launch_bounds__(256) void k_gconv_sparse_f(
    const float* __restrict__ X,const int* __restrict__ offD,const int* __restrict__ rowD,
    const int* __restrict__ eidD,int E,
    const float* __restrict__ Wrel,const float* __restrict__ brel,
    const float* __restrict__ Wroot,
    float* __restrict__ XN,int n,float* __restrict__ meanacc,float inv_n)
{
  __shared__ float agg_s[4][65];
  __shared__ float xrow[4][65];
  __shared__ float cnt_s[4];
  const int tid = threadIdx.x;
  const int r = tid>>6, j = tid&63;
  const int i = blockIdx.x*4 + r;
  float a = 0.0f;
  if (i < n){
    int p0 = offD[i], p1 = offD[i+1], c = 0;
    for(int p=p0;p<p1;p++){
      if (eidD[p] < E){ a += X[(size_t)rowD[p]*64 + j]; c++; }
    }
    xrow[r][j] = X[(size_t)i*64 + j];
    if (j == 0) cnt_s[r] = (float)(c>1?c:1);
  }
  agg_s[r][j] = a;
  __syncthreads();
  float v = 0.0f;
  if (i < n){
    float acc=0.0f, rt=0.0f;
    for(int q=0;q<64;q++){
      acc = fmaf(agg_s[r][q], Wrel[q*64+j], acc);
      rt  = fmaf(xrow[r][q],  Wroot[q*64+j], rt);
    }
    v = fmaxf(acc/cnt_s[r] + brel[j] + rt, 0.0f);
    XN[(size_t)i*64 + j] = v;
  }
  __syncthreads();
  agg_s[r][j] = v;
  __syncthreads();
  if (r == 0) atomicAdd(&meanacc[j], (agg_s[0][j]+agg_s[1][j]+agg_s[2][j]+agg_s[3][j])*inv_n);
}

// pool0: xq = segmax gather (incl self) then @pW+pb
__global__ __launch_bounds__(256) void k_xqmaxq(
    const float* __restrict__ X,const int* __restrict__ offD,const int* __restrict__ rowD,
    const float* __restrict__ pWp,const float* __restrict__ pbp,
    float* __restrict__ XQ2,int n)
{
  __shared__ float xq[4][65];
  const int tid = threadIdx.x;
  const int r = tid>>6, j = tid&63;
  const int i = blockIdx.x*4 + r;
  float v = -3.0e38f;
  if (i < n){
    int p0 = offD[i], p1 = offD[i+1];
    for(int p=p0;p<p1;p++) v = fmaxf(v, X[(size_t)rowD[p]*64 + j]);
  }
  xq[r][j] = v;
  __syncthreads();
  if (i < n){
    float s = pbp[j];
    for(int q=0;q<64;q++) s = fmaf(xq[r][q], pWp[q*64+j], s);
    XQ2[(size_t)i*64+j] = s;
  }
}

__global__ void k_edge_score(const int* __restrict__ src,const int* __restrict__ dst,
                             const float* __restrict__ XQ2,const float* __restrict__ X,
                             float* sE,int E,int n){
  int e = blockIdx.x*256+threadIdx.x; if(e>=E+n) return;
  int s,d; edge_sd(e,src,dst,E,s,d);
  const float* q = XQ2 + (size_t)d*64;
  const float* x = X + (size_t)s*64;
  float acc = 0.0f;
  for(int h=0;h<64;h++) acc = fmaf(q[h], x[h], acc);
  sE[e] = acc > 0.0f ? acc : 0.2f*acc;
}

// per-dst softmax over in-edges -> scE; also emits Mt[p] = {rowD[p]*kk, bits(scE)}
__global__ void k_dstsoft(const int* __restrict__ offD,const int* __restrict__ eidD,
                          const int* __restrict__ rowD,
                          const float* __restrict__ sE,float* __restrict__ scE,
                          int2* __restrict__ Mt,int kk,int n){
  int i = blockIdx.x*256+threadIdx.x; if(i>=n) return;
  int p0 = offD[i], p1 = offD[i+1];
  float m = -3.0e38f;
  for(int p=p0;p<p1;p++) m = fmaxf(m, sE[eidD[p]]);
  float d = 0.0f;
  for(int p=p0;p<p1;p++) d += expf(sE[eidD[p]]-m);
  float inv = 1.0f/d;
  for(int p=p0;p<p1;p++){
    int e = eidD[p];
    float v = expf(sE[e]-m)*inv;
    scE[e] = v;
    Mt[p] = make_int2(rowD[p]*kk, __float_as_int(v));
  }
}

// pool0: xc gather + aN/bN/cN; zeroes pcnt
__global__ __launch_bounds__(256) void k_xcabc0(
    const int* __restrict__ offD,const int* __restrict__ rowD,const int* __restrict__ eidD,
    const float* __restrict__ scE,const float* __restrict__ X,
    float* __restrict__ XC,
    const float* __restrict__ w1,const float* bb1,const float* __restrict__ w2,
    const float* __restrict__ w3,const float* bb3,
    float* aN,float* bN,float* cN,int* pcnt,int n)
{
  __shared__ float xc[4][65];
  const int tid = threadIdx.x;
  const int r = tid>>6, j = tid&63;
  const int i = blockIdx.x*4 + r;
  if (blockIdx.x==0 && tid==0) *pcnt = 0;
  float v = 0.0f;
  if (i < n){
    int p0 = offD[i], p1 = offD[i+1];
    for(int p=p0;p<p1;p++) v += scE[eidD[p]] * X[(size_t)rowD[p]*64 + j];
    XC[(size_t)i*64+j] = v;
  }
  xc[r][j] = v;
  __syncthreads();
  if (i < n && j < 3){
    float s = (j==0)?bb1[0]:((j==2)?bb3[0]:0.0f);
    const float* w = (j==0)?w1:((j==1)?w2:w3);
    for(int q=0;q<64;q++) s = fmaf(xc[r][q], w[q], s);
    if(j==0) aN[i]=s; else if(j==1) bN[i]=s; else cN[i]=s;
  }
}

// pool0 fit + zero rank + ipos=-1
__global__ void k_aggfit0(const int* __restrict__ offD,const int* __restrict__ rowD,
                          const float* aN,const float* bN,const float* cN,
                          float* fit,int* __restrict__ rank,int* __restrict__ ipos,int n){
  int i = blockIdx.x*256+threadIdx.x; if(i>=n) return;
  int p0 = offD[i], p1 = offD[i+1];
  float s = 0.0f;
  for(int p=p0;p<p1;p++) s += aN[rowD[p]];
  fit[i] = sigm(s - (float)(p1-p0)*bN[i] + cN[i]);
  rank[i] = 0;
  ipos[i] = -1;
}

// R column-permuted at write time: Rp[i][ipos[c]] += scE  (only kept columns).
__global__ void k_stage1p(const int* src,const int* dst,const int* __restrict__ offS,
                          const int* __restrict__ colS,const int* __restrict__ eidS,
                          const float* __restrict__ scE,const int* __restrict__ ipos,
                          float* Rp,int E,int n,int kk){
  int e = blockIdx.x*256+threadIdx.x; if(e>=E+n) return;
  int i,j; edge_sd(e,src,dst,E,i,j);
  int p0 = offS[j], p1 = offS[j+1];
  float* Ri = Rp + (size_t)i*kk;
  for(int p=p0;p<p1;p++){
    int ip = ipos[colS[p]];
    if (ip >= 0) atomicAdd(&Ri[ip], scE[eidS[p]]);
  }
}
// A_new[u][v] = sum over in-edges of perm[u]: scE * Rp[row][v].
__global__ __launch_bounds__(256) void k_stage2x(
    const int* __restrict__ perm,const int* __restrict__ offD,
    const int2* __restrict__ Mt,
    const float* __restrict__ Rp,float* A,int k,int vw,int cbn){
  const int bid = blockIdx.x;
  const int slice = bid & 7;
  const int rest = bid >> 3;
  const int cb = rest % cbn;
  const int ub = rest / cbn;
  const int u = ub*4 + (threadIdx.x>>6);
  if (u >= k) return;
  const int vbase = slice*vw;
  int vend = vbase + vw; if (vend > k) vend = k;
  const int v = vbase + cb*64 + (threadIdx.x&63);
  const bool vok = v < vend;
  const int vs = vok ? v : vbase;
  const int d = perm[u];
  float acc = 0.0f;
  int p = offD[d];
  const int p1 = offD[d+1];
  for(; p+4 <= p1; p += 4){
    const int2 m0 = Mt[p];
    const int2 m1 = Mt[p+1];
    const int2 m2 = Mt[p+2];
    const int2 m3 = Mt[p+3];
    const float r0 = Rp[m0.x + vs];
    const float r1 = Rp[m1.x + vs];
    const float r2 = Rp[m2.x + vs];
    const float r3 = Rp[m3.x + vs];
    acc = fmaf(__int_as_float(m0.y), r0, acc);
    acc = fmaf(__int_as_float(m1.y), r1, acc);
    acc = fmaf(__int_as_float(m2.y), r2, acc);
    acc = fmaf(__int_as_float(m3.y), r3, acc);
  }
  for(; p < p1; ++p){
    const int2 m = Mt[p];
    acc = fmaf(__int_as_float(m.y), Rp[m.x + vs], acc);
  }
  if (vok) A[(size_t)u*k + v] = (u==v) ? 0.0f : acc;
}

__global__ void k_head2(const float* __restrict__ xs,const float* __restrict__ W1,
                        const float* __restrict__ b1,const float* __restrict__ W2,
                        const float* __restrict__ b2,float* out){
  __shared__ float h2[64];
  __shared__ float lg[10];
  int t = threadIdx.x;
  float s = b1[t];
  for(int q=0;q<640;q++) s = fmaf(xs[q], W1[q*64+t], s);
  h2[t] = fmaxf(s, 0.0f);
  __syncthreads();
  if(t < 10){
    float s2 = b2[t];
    for(int k=0;k<64;k++) s2 = fmaf(h2[k], W2[k*10+t], s2);
    lg[t] = s2;
  }
  __syncthreads();
  if(t == 0){
    float mx = lg[0];
    for(int i=1;i<10;i++) mx = fmaxf(mx, lg[i]);
    float se = 0.0f;
    for(int i=0;i<10;i++) se += expf(lg[i]-mx);
    float lse = mx + logf(se);
    for(int i=0;i<10;i++) out[i] = lg[i]-lse;
  }
}

// ---------------- host orchestration ----------------
extern "C" void kernel_launch(void* const* d_in, const int* in_sizes, int n_in,
                              void* d_out, int out_size, void* d_ws, size_t ws_size,
                              hipStream_t stream) {
  const int N0 = 1500, E = 24000, Z = 32, L = E + N0;
  const float* x0   = (const float*)d_in[0];
  const int* esrc   = (const int*)d_in[1];
  const int* edst   = (const int*)d_in[2];
  const float* W1   = (const float*)d_in[3];  const float* b1   = (const float*)d_in[4];
  const float* W2   = (const float*)d_in[5];  const float* b2   = (const float*)d_in[6];
  const float* W3   = (const float*)d_in[7];  const float* b3   = (const float*)d_in[8];
  const float* Wrel = (const float*)d_in[9];  const float* brel = (const float*)d_in[10];
  const float* Wroot= (const float*)d_in[11];
  const float* pW   = (const float*)d_in[12]; const float* pb   = (const float*)d_in[13];
  const float* leW1 = (const float*)d_in[14]; const float* leb1 = (const float*)d_in[15];
  const float* leW2 = (const float*)d_in[16]; const float* leW3 = (const float*)d_in[17];
  const float* leb3 = (const float*)d_in[18];
  const float* linW1= (const float*)d_in[19]; const float* linb1= (const float*)d_in[20];
  const float* linW2= (const float*)d_in[21]; const float* linb2= (const float*)d_in[22];
  float* out = (float*)d_out;

  float* ws = (float*)d_ws;
  size_t cur = 0;
  auto allocF = [&](size_t nf)->float*{ float* p = ws + cur; cur += (nf + 15) & ~(size_t)15; return p; };
  // contiguous zero block: xs | indeg | outdeg
  float* xs   = allocF(640);
  int* indeg  = (int*)allocF(1504);
  int* outdeg = (int*)allocF(1504);
  float* Xa  = allocF(96000); float* Xb  = allocF(96000); float* Y   = allocF(96000);
  float* XQ2 = allocF(96000); float* XC  = allocF(96000);
  float* mcol = allocF(1504); float* invd = allocF(1504);
  float* aN = allocF(1504); float* bN = allocF(1504); float* cN = allocF(1504);
  float* fit = allocF(1504); float* cntP = allocF(1504);
  int* pcnt = (int*)allocF(16);
  int* perm = (int*)allocF(1504);
  int* offD = (int*)allocF(1504); int* offS = (int*)allocF(1504);
  int* curD = (int*)allocF(1504); int* curS = (int*)allocF(1504);
  int* colS = (int*)allocF(25504); int* eidS = (int*)allocF(25504);
  int* rowD = (int*)allocF(25504); int* eidD = (int*)allocF(25504);
  float* sE = allocF(25504); float* scE = allocF(25504);
  int2* Mt  = (int2*)allocF(51008);
  int* cntp8 = (int*)allocF((size_t)Z*1504);
  float* aggp = allocF(64*1504);
  float* mpart = allocF(16*1504);
  float* spart = allocF(16*1504);
  float* SEGP = allocF((size_t)Z*1504*64);
  float* Rbig = allocF((size_t)1500*1500);   // pool0 Rp; aliased as split-K slab 0 + SCb
  float* SCb  = Rbig;
  float* A0  = allocF((size_t)1350*1350);
  float* A1s = allocF((size_t)1350*1350);
  const size_t SLAB = 1650048;               // >= 1350*1215
  float* PS2 = allocF(SLAB);
  float* PS3 = allocF(SLAB);
  const size_t BFSZ = (size_t)1350*4224/2 + 32;
  ushort* Abf = (ushort*)allocF(BFSZ);
  ushort* Bbf = (ushort*)allocF(BFSZ);
  ushort* Cbf = (ushort*)allocF(BFSZ);
  ushort* Dbf = (ushort*)allocF(BFSZ);
  int* rankb = indeg;                        // dead after k_prefix2

  dim3 B256(256);
  auto G1 = [&](size_t n){ return dim3((unsigned)((n + 255) / 256)); };
  auto ZF = [&](void* p, size_t nfloats){ k_zero<<<G1(nfloats),B256,0,stream>>>((float*)p, nfloats); };
  auto kcz = [&](int K){ return (int)(((K + Z*16 - 1) / (Z*16)) * 16); };

  // ---- prologue: zero (xs+indeg+outdeg contiguous), degrees, CSR ----
  ZF(xs, 640 + 1504 + 1504);
  k_deg<<<G1(E),B256,0,stream>>>(esrc, edst, indeg, outdeg, E);
  k_prefix2<<<dim3((N0+256)/256,2),B256,0,stream>>>(indeg, outdeg, offD, curD, offS, curS, N0);
  k_csr_fill2<<<G1(L),B256,0,stream>>>(esrc, edst, curS, colS, eidS, curD, rowD, eidD, E, N0);

  // ---- FEAST x3 (2 nodes each) ----
  auto feast = [&](const float* xin,int cin,const float* W,const float* bb,int hh,float* xout,float* macc){
    k_mm_small<<<G1((size_t)N0*hh),B256,0,stream>>>(xin, W, nullptr, Y, N0, cin, hh, 0);
    k_feast_gf<<<G1((size_t)N0*hh),B256,0,stream>>>(Y, offD, rowD, bb, xout, N0, hh, macc, 1.0f/N0);
  };
  feast(x0, 16, W1, b1, 32, Xa, nullptr);
  feast(Xa, 32, W2, b2, 64, Xb, nullptr);
  feast(Xb, 64, W3, b3, 64, Xa, xs + 0);
  float* X = Xa; float* XN = Xb;

  // ---- i=0 gconv_sparse (1 node) ----
  k_gconv_sparse_f<<<dim3((N0+3)/4),B256,0,stream>>>(X, offD, rowD, eidD, E, Wrel, brel, Wroot,
                                                     XN, N0, xs + 64, 1.0f/N0);
  { float* t = X; X = XN; XN = t; }

  // ---- pool 0 (sparse ASAP), n=1500 -> k=1350 ----
  {
    const int n = 1500, kk = 1350;
    int* ipos = curD;   // dead after CSR build
    k_xqmaxq<<<dim3((n+3)/4),B256,0,stream>>>(X, offD, rowD, pW, pb, XQ2, n);
    k_edge_score<<<G1(L),B256,0,stream>>>(esrc, edst, XQ2, X, sE, E, n);
    k_dstsoft<<<G1(n),B256,0,stream>>>(offD, eidD, rowD, sE, scE, Mt, kk, n);
    k_xcabc0<<<dim3((n+3)/4),B256,0,stream>>>(offD, rowD, eidD, scE, X, XC,
                                              leW1, leb1, leW2, leW3, leb3, aN, bN, cN, pcnt, n);
    k_aggfit0<<<G1(n),B256,0,stream>>>(offD, rowD, aN, bN, cN, fit, rankb, ipos, n);
    k_rank_cnt<<<dim3((n+255)/256,(n+127)/128),B256,0,stream>>>(fit, rankb, n);
    k_rank_sel<<<dim3((n+3)/4),B256,0,stream>>>(rankb, fit, XC, XN, n, kk, pcnt, perm, ipos);
    ZF(Rbig, (size_t)n*kk);
    k_stage1p<<<G1(L),B256,0,stream>>>(esrc, edst, offS, colS, eidS, scE, ipos, Rbig, E, n, kk);
    {
      const int vw = (kk + 7) / 8;          // 169
      const int cbn = (vw + 63) / 64;       // 3
      const int ubn = (kk + 3) / 4;         // 338
      k_stage2x<<<dim3((unsigned)(8*cbn*ubn)),B256,0,stream>>>(perm, offD, Mt,
                                                               Rbig, A0, kk, vw, cbn);
    }
    { float* t = X; X = XN; XN = t; }
  }

  float* Acur = A0; float* Aoth = A1s;
  int nn = 1350;

  // ---- dense gconv (2 nodes) ----
  auto gconv_dense = [&](int layer){
    dim3 g(1, (nn+63)/64, Z);
    k_skinny<false,true,false,false><<<g,B256,0,stream>>>(Acur, nn, X, nullptr, SEGP, cntp8, nn, nn, kcz(nn));
    k_gconv_fuse<<<dim3((nn+3)/4),B256,0,stream>>>(SEGP, cntp8, Z,
        Wrel + (size_t)layer*4096, brel + layer*64, X, Wroot + (size_t)layer*4096,
        XN, nn, xs + (size_t)(layer+1)*64, 1.0f/nn);
    { float* t = X; X = XN; XN = t; }
  };

  // ---- dense ASAP pool ----
  auto asap_dense = [&](int kk, int p){
    {
      dim3 g(1, (nn+63)/64, Z);
      k_skinny<true,true,false,true><<<g,B256,0,stream>>>(Acur, nn, X, nullptr, SEGP, cntp8, nn, nn, kcz(nn));
    }
    k_poolq<<<dim3((nn+3)/4),B256,0,stream>>>(SEGP, cntp8, Z, pW + (size_t)p*4096, pb + p*64,
                                              X, Abf, Bbf, cntP, nn);
    {
      dim3 g((nn+63)/64, (nn+63)/64);
      k_gemm_mfma<1><<<g,B256,0,stream>>>(Abf, Bbf, SCb, nn, nn, nn, 192, Acur, nn);
    }
    {
      const int chunk = (nn + 15) / 16;
      dim3 gm((nn+15)/16, 16);
      k_smax_pmax<<<gm,B256,0,stream>>>(SCb, nn, chunk, mpart);
      k_smax_psum<<<gm,B256,0,stream>>>(SCb, nn, chunk, mpart, spart);
      k_smax_fin<<<G1(nn),B256,0,stream>>>(mpart, spart, nn, mcol, invd);
    }
    {
      dim3 g(1, (nn+63)/64, Z);
      k_skinny<false,false,true,false><<<g,B256,0,stream>>>(SCb, nn, X, mcol, SEGP, nullptr, nn, nn, kcz(nn));
    }
    k_xcabc_dense<<<dim3((nn+3)/4),B256,0,stream>>>(SEGP, Z, invd, XC,
        leW1 + p*64, leb1 + p, leW2 + p*64, leW3 + p*64, leb3 + p, aN, bN, cN, pcnt, nn);
    k_aggcol<<<G1((size_t)nn*64),B256,0,stream>>>(Acur, aN, aggp, nn);
    k_fit_dense<<<G1(nn),B256,0,stream>>>(aggp, cntP, aN, bN, cN, fit, rankb, pcnt, nn);
    k_rank_cnt<<<dim3((nn+255)/256,(nn+127)/128),B256,0,stream>>>(fit, rankb, nn);
    k_rank_sel<<<dim3((nn+3)/4),B256,0,stream>>>(rankb, fit, XC, XN, nn, kk, pcnt, perm, nullptr);
    const int Kp = (nn + 63) & ~63;
    const int K3 = 3*Kp;
    k_split3<<<G1((size_t)nn*Kp),B256,0,stream>>>(Acur, nn, nn, nn, Abf, Kp, 0);
    { dim3 gt((kk+31)/32, Kp/32);
      k_split3_Tdual<<<gt,B256,0,stream>>>(SCb, nn, kk, nn, perm, invd, mcol, Dbf, Bbf, Cbf, Kp); }
    // ---- TB = A@Sp + Sp : split-K x4 (128x128 tiles, K-step 64, XCD swizzle) ----
    const int Tk = K3 >> 6;
    const int kchunk = ((Tk + 3) >> 2) << 6;
    {
      dim3 g((kk+127)/128, (nn+127)/128, 4);
      k_gemm_pp<<<g,B256,0,stream>>>(Abf, Bbf, Rbig, Aoth, PS2, PS3, kk, nn, kk, K3, kchunk);
      dim3 gr((kk+31)/32, (nn+31)/32);
      k_red_tb<<<gr,B256,0,stream>>>(Rbig, Aoth, PS2, PS3, kk, Bbf, Cbf, nn, kk, Kp);
    }
    // ---- A_new = Sp^T @ TB (zero diag): split-K x4 (output Aoth aliases slab 1: safe) ----
    {
      dim3 g((kk+127)/128, (kk+127)/128, 4);
      k_gemm_pp<<<g,B256,0,stream>>>(Dbf, Cbf, Rbig, Aoth, PS2, PS3, kk, kk, kk, K3, kchunk);
      k_red_diag<<<G1((size_t)kk*kk),B256,0,stream>>>(Rbig, Aoth, PS2, PS3, Aoth, kk);
    }
    { float* t = X; X = XN; XN = t; }
    { float* t = Acur; Acur = Aoth; Aoth = t; }
    nn = kk;
  };

  gconv_dense(1);
  gconv_dense(2);
  asap_dense(1215, 1);
  gconv_dense(3);
  gconv_dense(4);
  asap_dense(1094, 2);
  gconv_dense(5);
  gconv_dense(6);
  asap_dense(985, 3);
  gconv_dense(7);
  gconv_dense(8);

  // ---- head (1 node) ----
  k_head2<<<1,64,0,stream>>>(xs, linW1, linb1, linW2, linb2, out);
}

// Round 12
// 1260.725 us; speedup vs baseline: 1.0835x; 1.0042x over previous
//
#include <hip/hip_runtime.h>
#include <math.h>

#define NEGV -1000000000.0f

typedef short short8 __attribute__((ext_vector_type(8)));
typedef float floatx4 __attribute__((ext_vector_type(4)));

__device__ __forceinline__ float sigm(float x){ return 1.0f/(1.0f+expf(-x)); }
__device__ __forceinline__ void edge_sd(int e,const int* src,const int* dst,int E,int& s,int& d){
  if(e<E){ s=src[e]; d=dst[e]; } else { s=e-E; d=s; }
}
__device__ __forceinline__ ushort bf16rn(float x){
  unsigned u = __float_as_uint(x);
  unsigned r = (u + 0x7fffu + ((u>>16)&1u)) >> 16;
  return (ushort)r;
}
__device__ __forceinline__ float bf16f(ushort h){ return __uint_as_float(((unsigned)h)<<16); }

__global__ void k_zero(float* __restrict__ p, size_t n){
  size_t i = (size_t)blockIdx.x*256 + threadIdx.x;
  if (i < n) p[i] = 0.0f;
}

// ---------------- bf16x3 conversions ----------------
// R11: 2 elements/thread, ushort2 stores (Cp multiple of 64 -> pairs in-row, aligned).
__global__ void k_split3(const float* __restrict__ src,int R,int Cs,int ld,
                         ushort* __restrict__ dst,int Cp,int bmode){
  int idx = blockIdx.x*256+threadIdx.x;
  const int half = (R*Cp)>>1;
  if (idx >= half) return;
  const int e0 = idx*2;
  const int r = e0 / Cp, c = e0 - r*Cp;
  const float x0 = (c   < Cs) ? src[(size_t)r*ld + c]   : 0.0f;
  const float x1 = (c+1 < Cs) ? src[(size_t)r*ld + c+1] : 0.0f;
  ushort h0 = bf16rn(x0), l0 = bf16rn(x0 - bf16f(h0));
  ushort h1 = bf16rn(x1), l1 = bf16rn(x1 - bf16f(h1));
  size_t base = (size_t)r*(3*Cp) + c;
  ushort2 hh = make_ushort2(h0,h1);
  ushort2 ll = make_ushort2(l0,l1);
  *(ushort2*)&dst[base]        = hh;
  *(ushort2*)&dst[base + Cp]   = bmode ? ll : hh;
  *(ushort2*)&dst[base + 2*Cp] = bmode ? hh : ll;
}
// Sp = exp(src[:,perm]-mcol[perm])*invd[perm], transposed to K-innermost; writes BOTH
// A-role (dstA) and B-role (dstB); zero-pads k>=Rs rows in dstA/dstB AND dstCpad.
__global__ void k_split3_Tdual(const float* __restrict__ src,int Rs,int Cs,int ld,
                               const int* __restrict__ gperm,const float* __restrict__ cscale,
                               const float* __restrict__ emax,
                               ushort* __restrict__ dstA,ushort* __restrict__ dstB,
                               ushort* __restrict__ dstCpad,int Kp){
  __shared__ float t[32][33];
  int tx = threadIdx.x & 31, ty = threadIdx.x >> 5;
  int kb = blockIdx.y*32, xb = blockIdx.x*32;
  int x = xb + tx;
  int gx = (x < Cs) ? gperm[x] : 0;
#pragma unroll
  for (int i=0;i<4;i++){
    int k = kb + ty + i*8;
    t[ty+i*8][tx] = (k < Rs && x < Cs) ? src[(size_t)k*ld + gx] : 0.0f;
  }
  __syncthreads();
  const int K3 = 3*Kp;
#pragma unroll
  for (int i=0;i<4;i++){
    int xo = xb + ty + i*8, ko = kb + tx;
    if (xo < Cs){
      float v = 0.0f;
      if (ko < Rs){
        int g = gperm[xo];
        v = expf(t[tx][ty+i*8] - emax[g]) * cscale[g];
      }
      ushort h = bf16rn(v);
      ushort l = bf16rn(v - bf16f(h));
      size_t base = (size_t)xo*K3 + ko;
      dstA[base] = h; dstA[base+Kp] = h; dstA[base+2*Kp] = l;
      dstB[base] = h; dstB[base+Kp] = l; dstB[base+2*Kp] = h;
      if (ko >= Rs){ dstCpad[base]=0; dstCpad[base+Kp]=0; dstCpad[base+2*Kp]=0; }
    }
  }
}

// ---------------- MFMA bf16 GEMM (64x64 tile, K-step 64, double-buffered) ----------------
// EPI 1: mask(A+I)+leakyrelu.  (Used for the score GEMM, K3=192.)
template<int EPI>
__global__ __launch_bounds__(256) void k_gemm_mfma(
    const ushort* __restrict__ A, const ushort* __restrict__ B,
    float* __restrict__ C, int ldc, int M, int N, int K3,
    const float* __restrict__ mask, int ldm)
{
  __shared__ ushort As[2][64][72];
  __shared__ ushort Bs[2][64][72];
  const int tid = threadIdx.x;
  const int m0 = blockIdx.y*64, n0 = blockIdx.x*64;
  const int w = tid>>6, lane = tid&63;
  const int lo4 = lane&15, quad = lane>>4;
  const int sr = tid>>2, sseg = tid&3;

  floatx4 acc[4];
#pragma unroll
  for(int c=0;c<4;c++){ acc[c][0]=0.f; acc[c][1]=0.f; acc[c][2]=0.f; acc[c][3]=0.f; }

  const size_t arow = (size_t)(m0+sr)*K3;
  const size_t brow = (size_t)(n0+sr)*K3;
  const bool aval = (m0+sr) < M;
  const bool bval = (n0+sr) < N;

  uint4 av0 = make_uint4(0,0,0,0), av1 = make_uint4(0,0,0,0);
  uint4 bv0 = make_uint4(0,0,0,0), bv1 = make_uint4(0,0,0,0);
  if (aval){ av0 = *(const uint4*)(A + arow + sseg*8);
             av1 = *(const uint4*)(A + arow + 32 + sseg*8); }
  if (bval){ bv0 = *(const uint4*)(B + brow + sseg*8);
             bv1 = *(const uint4*)(B + brow + 32 + sseg*8); }
  *(uint4*)&As[0][sr][sseg*8] = av0; *(uint4*)&As[0][sr][32+sseg*8] = av1;
  *(uint4*)&Bs[0][sr][sseg*8] = bv0; *(uint4*)&Bs[0][sr][32+sseg*8] = bv1;
  __syncthreads();

  const int T = K3 >> 6;
  for (int i=0;i<T;i++){
    const int cb = i & 1;
    if (i+1 < T){
      const int k0 = (i+1)<<6;
      av0 = make_uint4(0,0,0,0); av1 = make_uint4(0,0,0,0);
      bv0 = make_uint4(0,0,0,0); bv1 = make_uint4(0,0,0,0);
      if (aval){ av0 = *(const uint4*)(A + arow + k0 + sseg*8);
                 av1 = *(const uint4*)(A + arow + k0 + 32 + sseg*8); }
      if (bval){ bv0 = *(const uint4*)(B + brow + k0 + sseg*8);
                 bv1 = *(const uint4*)(B + brow + k0 + 32 + sseg*8); }
    }
    short8 af0 = *(const short8*)&As[cb][16*w + lo4][quad*8];
    short8 af1 = *(const short8*)&As[cb][16*w + lo4][32+quad*8];
#pragma unroll
    for (int c=0;c<4;c++){
      short8 bf0 = *(const short8*)&Bs[cb][16*c + lo4][quad*8];
      acc[c] = __builtin_amdgcn_mfma_f32_16x16x32_bf16(af0, bf0, acc[c], 0, 0, 0);
      short8 bf1 = *(const short8*)&Bs[cb][16*c + lo4][32+quad*8];
      acc[c] = __builtin_amdgcn_mfma_f32_16x16x32_bf16(af1, bf1, acc[c], 0, 0, 0);
    }
    if (i+1 < T){
      __syncthreads();
      *(uint4*)&As[1-cb][sr][sseg*8] = av0; *(uint4*)&As[1-cb][sr][32+sseg*8] = av1;
      *(uint4*)&Bs[1-cb][sr][sseg*8] = bv0; *(uint4*)&Bs[1-cb][sr][32+sseg*8] = bv1;
      __syncthreads();
    }
  }

#pragma unroll
  for (int c=0;c<4;c++){
    const int gn = n0 + 16*c + lo4;
#pragma unroll
    for (int r=0;r<4;r++){
      const int gm = m0 + 16*w + quad*4 + r;
      if (gm < M && gn < N){
        float v = acc[c][r];
        if (EPI==1) v = (mask[(size_t)gm*ldm+gn] != 0.0f || gm==gn) ? (v > 0.0f ? v : 0.2f*v) : NEGV;
        C[(size_t)gm*ldc+gn] = v;
      }
    }
  }
}

// ---------------- split-K x4 MFMA partial-product GEMM, 128x128 tile ----------------
// K-step 64 (measured best). 4 waves, each owns a 64x64 output quadrant.
// XCD-chunked bijective swizzle. blockIdx.z selects a K-chunk.
__global__ __launch_bounds__(256) void k_gemm_pp(
    const ushort* __restrict__ A, const ushort* __restrict__ B,
    float* __restrict__ P0, float* __restrict__ P1,
    float* __restrict__ P2, float* __restrict__ P3, int ldp,
    int M, int N, int K3, int kchunk)
{
  __shared__ ushort As[2][128][72];
  __shared__ ushort Bs[2][128][72];
  const int tid = threadIdx.x;

  // ---- XCD-chunked bijective block remap ----
  const int gx = gridDim.x, gxy = gridDim.x*gridDim.y;
  const int TT = gxy*gridDim.z;
  const int s  = blockIdx.x + gx*blockIdx.y + gxy*blockIdx.z;
  const int c8 = s & 7, u = s >> 3;
  const int q = TT >> 3, r8 = TT & 7;
  const int w0 = (c8 < r8) ? c8*(q+1) + u : r8*(q+1) + (c8 - r8)*q + u;
  const int z  = w0 / gxy;
  const int lin = w0 - z*gxy;
  const int ty = lin / gx, tx = lin - ty*gx;

  const int m0 = ty*128, n0 = tx*128;
  const int w = tid>>6, lane = tid&63;
  const int lo4 = lane&15, quad = lane>>4;
  const int wr = w>>1, wc = w&1;

  // staging: thread t -> row t>>1, half t&1 (32 ushort = 4x uint4 per operand)
  const int srow = tid>>1, shalf = tid&1;

  float* __restrict__ P = (z==0) ? P0 : (z==1) ? P1 : (z==2) ? P2 : P3;
  const int kbeg = z * kchunk;
  int klen = K3 - kbeg; if (klen > kchunk) klen = kchunk; if (klen < 0) klen = 0;
  const int T = klen >> 6;

  floatx4 acc[4][4];
#pragma unroll
  for(int i=0;i<4;i++)
#pragma unroll
    for(int c=0;c<4;c++){ acc[i][c][0]=0.f; acc[i][c][1]=0.f; acc[i][c][2]=0.f; acc[i][c][3]=0.f; }

  const size_t arow = (size_t)(m0+srow)*K3 + kbeg + shalf*32;
  const size_t brow = (size_t)(n0+srow)*K3 + kbeg + shalf*32;
  const bool aval = (m0+srow) < M;
  const bool bval = (n0+srow) < N;
  const int sbase = shalf*32;

  uint4 apre[4], bpre[4];
#pragma unroll
  for(int s2=0;s2<4;s2++){ apre[s2]=make_uint4(0,0,0,0); bpre[s2]=make_uint4(0,0,0,0); }
  if (aval){
#pragma unroll
    for(int s2=0;s2<4;s2++) apre[s2] = *(const uint4*)(A + arow + s2*8);
  }
  if (bval){
#pragma unroll
    for(int s2=0;s2<4;s2++) bpre[s2] = *(const uint4*)(B + brow + s2*8);
  }
#pragma unroll
  for(int s2=0;s2<4;s2++){
    *(uint4*)&As[0][srow][sbase + s2*8] = apre[s2];
    *(uint4*)&Bs[0][srow][sbase + s2*8] = bpre[s2];
  }
  __syncthreads();

  for (int it=0; it<T; ++it){
    const int cb = it & 1;
    if (it+1 < T){
      const int k0 = (it+1)<<6;
#pragma unroll
      for(int s2=0;s2<4;s2++){ apre[s2]=make_uint4(0,0,0,0); bpre[s2]=make_uint4(0,0,0,0); }
      if (aval){
#pragma unroll
        for(int s2=0;s2<4;s2++) apre[s2] = *(const uint4*)(A + arow + k0 + s2*8);
      }
      if (bval){
#pragma unroll
        for(int s2=0;s2<4;s2++) bpre[s2] = *(const uint4*)(B + brow + k0 + s2*8);
      }
    }
    short8 af[4][2];
#pragma unroll
    for(int i=0;i<4;i++){
      af[i][0] = *(const short8*)&As[cb][wr*64 + 16*i + lo4][quad*8];
      af[i][1] = *(const short8*)&As[cb][wr*64 + 16*i + lo4][32 + quad*8];
    }
#pragma unroll
    for(int c=0;c<4;c++){
      short8 bf0 = *(const short8*)&Bs[cb][wc*64 + 16*c + lo4][quad*8];
      short8 bf1 = *(const short8*)&Bs[cb][wc*64 + 16*c + lo4][32 + quad*8];
#pragma unroll
      for(int i=0;i<4;i++){
        acc[i][c] = __builtin_amdgcn_mfma_f32_16x16x32_bf16(af[i][0], bf0, acc[i][c], 0, 0, 0);
        acc[i][c] = __builtin_amdgcn_mfma_f32_16x16x32_bf16(af[i][1], bf1, acc[i][c], 0, 0, 0);
      }
    }
    if (it+1 < T){
      __syncthreads();
#pragma unroll
      for(int s2=0;s2<4;s2++){
        *(uint4*)&As[1-cb][srow][sbase + s2*8] = apre[s2];
        *(uint4*)&Bs[1-cb][srow][sbase + s2*8] = bpre[s2];
      }
      __syncthreads();
    }
  }

#pragma unroll
  for(int c=0;c<4;c++){
    const int gn = n0 + wc*64 + 16*c + lo4;
    if (gn < N){
#pragma unroll
      for(int i=0;i<4;i++){
#pragma unroll
        for(int r=0;r<4;r++){
          const int gm = m0 + wr*64 + 16*i + quad*4 + r;
          if (gm < M) P[(size_t)gm*ldp+gn] = acc[i][c][r];
        }
      }
    }
  }
}

// reduce 4 TB slabs + Sp, transpose-store as bf16x3 B-role (h,l,h) at gn*K3o+gm.
__global__ __launch_bounds__(256) void k_red_tb(
    const float* __restrict__ P0,const float* __restrict__ P1,
    const float* __restrict__ P2,const float* __restrict__ P3,int ldp,
    const ushort* __restrict__ Bb, ushort* __restrict__ Cb,
    int M,int N,int Kp)
{
  __shared__ float t[32][33];
  const int tx = threadIdx.x & 31, ty = threadIdx.x >> 5;
  const int mb = blockIdx.y*32, nb = blockIdx.x*32;
  const int n = nb + tx;
#pragma unroll
  for (int i=0;i<4;i++){
    int m = mb + ty + i*8;
    float v = 0.0f;
    if (m < M && n < N){
      size_t o = (size_t)m*ldp + n;
      v = (P0[o] + P1[o]) + (P2[o] + P3[o]);
    }
    t[ty+i*8][tx] = v;
  }
  __syncthreads();
  const int K3o = 3*Kp;
#pragma unroll
  for (int i=0;i<4;i++){
    int no = nb + ty + i*8, mo = mb + tx;
    if (no < N && mo < M){
      size_t base = (size_t)no*K3o + mo;
      float sp = bf16f(Bb[base]) + bf16f(Bb[base+Kp]);
      float v = t[tx][ty+i*8] + sp;
      ushort h = bf16rn(v), l = bf16rn(v - bf16f(h));
      Cb[base] = h; Cb[base+Kp] = l; Cb[base+2*Kp] = h;
    }
  }
}

// reduce 4 A_new slabs + zero diagonal, 4 elems/thread (R11: float4 loads; slabs are
// allocated past kk*kk so the tail over-read is in-bounds; C aliases a slab but each
// thread reads-then-writes only its own 4 elements).
__global__ void k_red_diag(const float* __restrict__ P0,const float* __restrict__ P1,
                           const float* __restrict__ P2,const float* __restrict__ P3,
                           float* __restrict__ C,int kk){
  const int total = kk*kk;
  const int base = (blockIdx.x*256+threadIdx.x)*4;
  if (base >= total) return;
  float4 a = *(const float4*)&P0[base];
  float4 b = *(const float4*)&P1[base];
  float4 c4 = *(const float4*)&P2[base];
  float4 d = *(const float4*)&P3[base];
  float sv[4] = { (a.x+b.x)+(c4.x+d.x), (a.y+b.y)+(c4.y+d.y),
                  (a.z+b.z)+(c4.z+d.z), (a.w+b.w)+(c4.w+d.w) };
#pragma unroll
  for (int j=0;j<4;j++){
    const int id = base + j;
    if (id < total){
      const int u = id/kk, v = id - u*kk;
      C[id] = (u==v) ? 0.0f : sv[j];
    }
  }
}

// ---------------- atomic-free skinny agg GEMM ----------------
// R11: single-stage LDS (whole k-chunk <=48 rows staged once) -> 2 barriers per block
// instead of 2 per 16-row tile. Zero-padded rows are exact identities for all variants.
template<bool MAXM, bool COUNT, bool EXPM, bool SELF>
__global__ __launch_bounds__(256) void k_skinny(
    const float* __restrict__ A, int lda,
    const float* __restrict__ X,
    const float* __restrict__ mcol,
    float* __restrict__ P, int* __restrict__ cntp,
    int M, int K, int kchunk)
{
  __shared__ float As[48][68];
  __shared__ float Xs[48][68];
  const int tid = threadIdx.x;
  const int m0 = blockIdx.y * 64;
  const int tmb = (tid & 15) * 4, tnb = (tid >> 4) * 4;
  float acc[4][4];
  int cacc[4] = {0,0,0,0};
#pragma unroll
  for (int i=0;i<4;i++)
#pragma unroll
    for (int j=0;j<4;j++) acc[i][j] = MAXM ? NEGV : 0.0f;

  const int kstart = blockIdx.z * kchunk;
  int kend = kstart + kchunk; if (kend > K) kend = K;
  const int klen = kend - kstart;          // <= 48
  const int ml = tid & 63, tb = tid >> 6;
  const bool mvalid = (m0 + ml) < M;
  float mc = 0.0f;
  if (EXPM && mvalid) mc = mcol[m0 + ml];

#pragma unroll
  for (int s=0;s<12;s++) {
    const int tk = tb + s*4;
    float va = 0.0f, vx = 0.0f;
    if (tk < klen) {
      const int row = kstart + tk;
      if (mvalid){
        va = A[(size_t)row*lda + m0 + ml];
        if (EXPM) va = expf(va - mc);
      }
      vx = X[(size_t)row*64 + ml];
    }
    As[tk][ml] = va;
    Xs[tk][ml] = vx;
  }
  __syncthreads();
  for (int kk=0; kk<klen; kk++) {
    const float4 a4 = *(const float4*)&As[kk][tmb];
    const float4 b4 = *(const float4*)&Xs[kk][tnb];
    const float av[4] = {a4.x,a4.y,a4.z,a4.w};
    const float bv[4] = {b4.x,b4.y,b4.z,b4.w};
#pragma unroll
    for (int i=0;i<4;i++){
      if (COUNT) cacc[i] += (av[i] != 0.0f) ? 1 : 0;
#pragma unroll
      for (int j=0;j<4;j++) {
        if (MAXM) acc[i][j] = fmaxf(acc[i][j], av[i] != 0.0f ? bv[j] : NEGV);
        else      acc[i][j] = fmaf(av[i], bv[j], acc[i][j]);
      }
    }
  }

  const size_t slab = (size_t)blockIdx.z * M * 64;
#pragma unroll
  for (int i=0;i<4;i++){
    const int m = m0 + tmb + i;
    if (m < M){
#pragma unroll
      for (int j=0;j<4;j++){
        float v = acc[i][j];
        if (SELF) v = fmaxf(v, X[(size_t)m*64 + tnb + j]);
        P[slab + (size_t)m*64 + tnb + j] = v;
      }
    }
  }
  if (COUNT && tnb == 0){
#pragma unroll
    for (int i=0;i<4;i++){
      const int m = m0 + tmb + i;
      if (m < M) cntp[blockIdx.z*M + m] = cacc[i];
    }
  }
}

// slab max-reduce -> xq; xq2 = xq@pW+pb; cntP = 1 + sum counts.
// Also emits bf16x3 operands: dstA (A-role from X), dstB (B-role from xq2).
__global__ __launch_bounds__(256) void k_poolq(
    const float* __restrict__ SEGP,const int* __restrict__ cntp8,int Z,
    const float* __restrict__ pWp,const float* __restrict__ pbp,
    const float* __restrict__ X,
    ushort* __restrict__ dstA,ushort* __restrict__ dstB,
    float* __restrict__ cntP,int n)
{
  __shared__ float xq[4][65];
  const int tid = threadIdx.x;
  const int r = tid>>6, j = tid&63;
  const int i = blockIdx.x*4 + r;
  float v = NEGV;
  if (i < n){
    for(int z=0;z<Z;z++) v = fmaxf(v, SEGP[(size_t)z*n*64 + (size_t)i*64 + j]);
    if (j == 0){
      int c=1; for(int z=0;z<Z;z++) c += cntp8[z*n+i];
      cntP[i] = (float)c;
    }
  }
  xq[r][j] = v;
  __syncthreads();
  if (i < n){
    float s = pbp[j];
    for(int q=0;q<64;q++) s = fmaf(xq[r][q], pWp[q*64+j], s);
    size_t base = (size_t)i*192 + j;
    ushort h = bf16rn(s), l = bf16rn(s - bf16f(h));
    dstB[base] = h; dstB[base+64] = l; dstB[base+128] = h;
    float x = X[(size_t)i*64 + j];
    h = bf16rn(x); l = bf16rn(x - bf16f(h));
    dstA[base] = h; dstA[base+64] = h; dstA[base+128] = l;
  }
}

// fused dense gconv: reduce slabs, two 64x64 matmuls, relu, mean-accumulate.
__global__ __launch_bounds__(256) void k_gconv_fuse(
    const float* __restrict__ SEGP,const int* __restrict__ cntp8,int Z,
    const float* __restrict__ Wrel,const float* __restrict__ brel,
    const float* __restrict__ X,const float* __restrict__ Wroot,
    float* __restrict__ XN,int n,float* __restrict__ meanacc,float inv_n)
{
  __shared__ float agg_s[4][65];
  __shared__ float xrow[4][65];
  __shared__ float cnt_s[4];
  const int tid = threadIdx.x;
  const int r = tid>>6, j = tid&63;
  const int i = blockIdx.x*4 + r;
  float a = 0.0f;
  if (i < n){
    for(int z=0;z<Z;z++) a += SEGP[(size_t)z*n*64 + (size_t)i*64 + j];
    xrow[r][j] = X[(size_t)i*64 + j];
    if (j == 0){
      int c=0; for(int z=0;z<Z;z++) c += cntp8[z*n+i];
      cnt_s[r] = (float)(c>1?c:1);
    }
  }
  agg_s[r][j] = a;
  __syncthreads();
  float v = 0.0f;
  if (i < n){
    float acc=0.0f, rt=0.0f;
    for(int q=0;q<64;q++){
      acc = fmaf(agg_s[r][q], Wrel[q*64+j], acc);
      rt  = fmaf(xrow[r][q],  Wroot[q*64+j], rt);
    }
    v = fmaxf(acc/cnt_s[r] + brel[j] + rt, 0.0f);
    XN[(size_t)i*64 + j] = v;
  }
  __syncthreads();
  agg_s[r][j] = v;
  __syncthreads();
  if (r == 0) atomicAdd(&meanacc[j], (agg_s[0][j]+agg_s[1][j]+agg_s[2][j]+agg_s[3][j])*inv_n);
}

// ---------------- row-chunked column softmax stats (3 kernels, 16x parallelism) ----------------
__global__ __launch_bounds__(256) void k_smax_pmax(const float* __restrict__ S,int n,int chunk,
                                                   float* __restrict__ mpart){
  __shared__ float red[16][17];
  const int jc = threadIdx.x & 15, rg = threadIdx.x >> 4;
  const int j = blockIdx.x*16 + jc;
  const int z = blockIdx.y;
  const int i0 = z*chunk;
  int i1 = i0 + chunk; if (i1 > n) i1 = n;
  float m = -3.0e38f;
  if (j < n)
    for(int i=i0+rg;i<i1;i+=16) m = fmaxf(m, S[(size_t)i*n+j]);
  red[rg][jc] = m;
  __syncthreads();
  for(int s=8;s>0;s>>=1){
    if(rg<s) red[rg][jc] = fmaxf(red[rg][jc], red[rg+s][jc]);
    __syncthreads();
  }
  if (rg==0 && j<n) mpart[(size_t)z*n + j] = red[0][jc];
}
__global__ __launch_bounds__(256) void k_smax_psum(const float* __restrict__ S,int n,int chunk,
                                                   const float* __restrict__ mpart,
                                                   float* __restrict__ spart){
  __shared__ float red[16][17];
  const int jc = threadIdx.x & 15, rg = threadIdx.x >> 4;
  const int j = blockIdx.x*16 + jc;
  const int z = blockIdx.y;
  float mv = -3.0e38f;
  if (j < n) mv = mpart[(size_t)rg*n + j];
  red[rg][jc] = mv;
  __syncthreads();
  for(int s=8;s>0;s>>=1){
    if(rg<s) red[rg][jc] = fmaxf(red[rg][jc], red[rg+s][jc]);
    __syncthreads();
  }
  const float mc = red[0][jc];
  __syncthreads();
  const int i0 = z*chunk;
  int i1 = i0 + chunk; if (i1 > n) i1 = n;
  float sum = 0.0f;
  if (j < n)
    for(int i=i0+rg;i<i1;i+=16) sum += expf(S[(size_t)i*n+j]-mc);
  red[rg][jc] = sum;
  __syncthreads();
  for(int s=8;s>0;s>>=1){
    if(rg<s) red[rg][jc] += red[rg+s][jc];
    __syncthreads();
  }
  if (rg==0 && j<n) spart[(size_t)z*n + j] = red[0][jc];
}
__global__ void k_smax_fin(const float* __restrict__ mpart,const float* __restrict__ spart,
                           int n,float* __restrict__ mcol,float* __restrict__ invd){
  int j = blockIdx.x*256+threadIdx.x; if(j>=n) return;
  float m = mpart[j];
  for(int z=1;z<16;z++) m = fmaxf(m, mpart[(size_t)z*n+j]);
  mcol[j] = m;
  float s = 0.0f;
  for(int z=0;z<16;z++) s += spart[(size_t)z*n+j];
  invd[j] = 1.0f/s;
}

// slab sum * invd -> XC; then aN/bN/cN per row; zeroes pcnt.
__global__ __launch_bounds__(256) void k_xcabc_dense(
    const float* __restrict__ SEGP,int Z,const float* __restrict__ invd,
    float* __restrict__ XC,
    const float* __restrict__ w1,const float* bb1,const float* __restrict__ w2,
    const float* __restrict__ w3,const float* bb3,
    float* aN,float* bN,float* cN,int* pcnt,int n)
{
  __shared__ float xc[4][65];
  const int tid = threadIdx.x;
  const int r = tid>>6, j = tid&63;
  const int i = blockIdx.x*4 + r;
  if (blockIdx.x==0 && tid==0) *pcnt = 0;
  float v = 0.0f;
  if (i < n){
    for(int z=0;z<Z;z++) v += SEGP[(size_t)z*n*64 + (size_t)i*64 + j];
    v *= invd[i];
    XC[(size_t)i*64+j] = v;
  }
  xc[r][j] = v;
  __syncthreads();
  if (i < n && j < 3){
    float s = (j==0)?bb1[0]:((j==2)?bb3[0]:0.0f);
    const float* w = (j==0)?w1:((j==1)?w2:w3);
    for(int q=0;q<64;q++) s = fmaf(xc[r][q], w[q], s);
    if(j==0) aN[i]=s; else if(j==1) bN[i]=s; else cN[i]=s;
  }
}

// 64 row-chunks.
__global__ void k_aggcol(const float* __restrict__ A,const float* __restrict__ aN,
                         float* __restrict__ aggp,int n){
  int idx = blockIdx.x*256+threadIdx.x; if(idx>=n*64) return;
  int j = idx % n, c = idx / n;
  int i0 = (int)(((long long)n*c)/64), i1 = (int)(((long long)n*(c+1))/64);
  float s = 0.0f;
  for(int i=i0;i<i1;i++) if(A[(size_t)i*n + j] != 0.0f) s += aN[i];
  aggp[c*n + j] = s;
}

// ---------------- parallel top-k rank ----------------
__global__ void k_fit_dense(const float* __restrict__ aggp,const float* __restrict__ cntP,
                            const float* __restrict__ aN,const float* __restrict__ bN,
                            const float* __restrict__ cN,
                            float* __restrict__ fit,int* __restrict__ rank,int* pcnt,int n){
  int u = blockIdx.x*256+threadIdx.x;
  if (blockIdx.x==0 && threadIdx.x==0) *pcnt = 0;
  if (u >= n) return;
  float a = aN[u];
  for(int c=0;c<64;c++) a += aggp[c*n+u];
  fit[u] = sigm(a - cntP[u]*bN[u] + cN[u]);
  rank[u] = 0;
}
// R11: u-chunk 32 (was 128) -> 4x blocks (was 0.26 blocks/CU).
__global__ __launch_bounds__(256) void k_rank_cnt(const float* __restrict__ fit,
                                                  int* __restrict__ rank,int n){
  __shared__ float fsc[32];
  const int u0 = blockIdx.y*32;
  int u1 = u0+32; if (u1 > n) u1 = n;
  const int cl = u1 - u0;
  if ((int)threadIdx.x < cl) fsc[threadIdx.x] = fit[u0+threadIdx.x];
  __syncthreads();
  const int v = blockIdx.x*256+threadIdx.x;
  if (v >= n) return;
  const float fv = fit[v];
  int r = 0;
  for(int t=0;t<cl;t++){
    const float fu = fsc[t];
    const int u = u0+t;
    r += (fu > fv || (fu == fv && u < v)) ? 1 : 0;
  }
  atomicAdd(&rank[v], r);
}
// Selection + coalesced XN write; optionally records inverse perm (ipos[v]=slot).
__global__ __launch_bounds__(256) void k_rank_sel(const int* __restrict__ rank,
    const float* __restrict__ fit,const float* __restrict__ XC,float* __restrict__ XN,
    int n,int k,int* pcnt,int* perm,int* __restrict__ ipos){
  __shared__ int ps[4];
  const int r = threadIdx.x>>6, h = threadIdx.x&63;
  const int v = blockIdx.x*4 + r;
  const bool sel = (v < n) && (rank[v] < k);
  if (h == 0 && sel){
    int p = atomicAdd(pcnt,1);
    ps[r] = p;
    perm[p] = v;
    if (ipos) ipos[v] = p;
  }
  __syncthreads();
  if (sel){
    const int p = ps[r];
    XN[(size_t)p*64 + h] = XC[(size_t)v*64 + h] * fit[v];
  }
}

// ---------------- prologue: degrees + CSR over L=E+n edges (incl self) ----------------
__global__ void k_deg(const int* __restrict__ src,const int* __restrict__ dst,int* indeg,int* outdeg,int E){
  int e = blockIdx.x*256+threadIdx.x; if(e>=E) return;
  atomicAdd(&indeg[dst[e]],1); atomicAdd(&outdeg[src[e]],1);
}
__global__ __launch_bounds__(256) void k_prefix2(const int* __restrict__ indeg,const int* __restrict__ outdeg,
                          int* offD,int* curD,int* offS,int* curS,int n){
  __shared__ int ds[1504];
  const int* dsrc = blockIdx.y ? outdeg : indeg;
  for(int u=threadIdx.x; u<n; u+=256) ds[u] = dsrc[u];
  __syncthreads();
  int t = blockIdx.x*256+threadIdx.x; if(t>n) return;
  int s = 0;
  for(int u=0;u<t;u++) s += ds[u]+1;
  if (blockIdx.y){ offS[t]=s; if(t<n) curS[t]=s; }
  else           { offD[t]=s; if(t<n) curD[t]=s; }
}
__global__ void k_csr_fill2(const int* src,const int* dst,
                            int* curS,int* colS,int* eidS,
                            int* curD,int* rowD,int* eidD,int E,int n){
  int e = blockIdx.x*256+threadIdx.x; if(e>=E+n) return;
  int s,d; edge_sd(e,src,dst,E,s,d);
  int p = atomicAdd(&curS[s],1); colS[p]=d; eidS[p]=e;
  int q = atomicAdd(&curD[d],1); rowD[q]=s; eidD[q]=e;
}

__global__ void k_mm_small(const float* __restrict__ A,const float* __restrict__ W,
                           const float* __restrict__ b,float* __restrict__ C,
                           int M,int K,int Np,int act){
  int idx = blockIdx.x*256+threadIdx.x; if(idx>=M*Np) return;
  int m = idx/Np, j = idx - m*Np;
  float s = b ? b[j] : 0.0f;
  const float* a = A + (size_t)m*K;
  for(int q=0;q<K;q++) s = fmaf(a[q], W[(size_t)q*Np + j], s);
  if(act==1) s = fmaxf(s, 0.0f);
  C[idx] = s;
}

// feast: gather-mean over in-edges (incl self), +b, elu; optional mean (H==64)
__global__ void k_feast_gf(const float* __restrict__ Y,const int* __restrict__ offD,
                           const int* __restrict__ rowD,
                           const float* __restrict__ b,float* X,int n,int H,
                           float* __restrict__ meanacc,float inv_n){
  __shared__ float ms[4][64];
  int idx = blockIdx.x*256+threadIdx.x;
  float v = 0.0f;
  if(idx<n*H){
    int i = idx/H, h = idx - i*H;
    int p0 = offD[i], p1 = offD[i+1];
    float s = 0.0f;
    for(int p=p0;p<p1;p++) s += Y[(size_t)rowD[p]*H + h];
    float t = s/(float)(p1-p0) + b[h];
    v = t > 0.0f ? t : (expf(t)-1.0f);
    X[idx] = v;
  }
  if(meanacc){
    int r = threadIdx.x>>6, j = threadIdx.x&63;
    ms[r][j] = (idx<n*H) ? v : 0.0f;
    __syncthreads();
    if(r==0) atomicAdd(&meanacc[j], (ms[0][j]+ms[1][j]+ms[2][j]+ms[3][j])*inv_n);
  }
}

// fused sparse gconv: gather agg (real edges only), 2 matmuls, relu, mean.
__global__ __launch_bounds__(256) void k_gconv_sparse_f(
    const float* __restrict__ X,const int* __restrict__ offD,const int* __restrict__ rowD,
    const int* __restrict__ eidD,int E,
    const float* __restrict__ Wrel,const float* __restrict__ brel,
    const float* __restrict__ Wroot,
    float* __restrict__ XN,int n,float* __restrict__ meanacc,float inv_n)
{
  __shared__ float agg_s[4][65];
  __shared__ float xrow[4][65];
  __shared__ float cnt_s[4];
  const int tid = threadIdx.x;
  const int r = tid>>6, j = tid&63;
  const int i = blockIdx.x*4 + r;
  float a = 0.0f;
  if (i < n){
    int p0 = offD[i], p1 = offD[i+1], c = 0;
    for(int p=p0;p<p1;p++){
      if (eidD[p] < E){ a += X[(size_t)rowD[p]*64 + j]; c++; }
    }
    xrow[r][j] = X[(size_t)i*64 + j];
    if (j == 0) cnt_s[r] = (float)(c>1?c:1);
  }
  agg_s[r][j] = a;
  __syncthreads();
  float v = 0.0f;
  if (i < n){
    float acc=0.0f, rt=0.0f;
    for(int q=0;q<64;q++){
      acc = fmaf(agg_s[r][q], Wrel[q*64+j], acc);
      rt  = fmaf(xrow[r][q],  Wroot[q*64+j], rt);
    }
    v = fmaxf(acc/cnt_s[r] + brel[j] + rt, 0.0f);
    XN[(size_t)i*64 + j] = v;
  }
  __syncthreads();
  agg_s[r][j] = v;
  __syncthreads();
  if (r == 0) atomicAdd(&meanacc[j], (agg_s[0][j]+agg_s[1][j]+agg_s[2][j]+agg_s[3][j])*inv_n);
}

// pool0: xq = segmax gather (incl self) then @pW+pb
__global__ __launch_bounds__(256) void k_xqmaxq(
    const float* __restrict__ X,const int* __restrict__ offD,const int* __restrict__ rowD,
    const float* __restrict__ pWp,const float* __restrict__ pbp,
    float* __restrict__ XQ2,int n)
{
  __shared__ float xq[4][65];
  const int tid = threadIdx.x;
  const int r = tid>>6, j = tid&63;
  const int i = blockIdx.x*4 + r;
  float v = -3.0e38f;
  if (i < n){
    int p0 = offD[i], p1 = offD[i+1];
    for(int p=p0;p<p1;p++) v = fmaxf(v, X[(size_t)rowD[p]*64 + j]);
  }
  xq[r][j] = v;
  __syncthreads();
  if (i < n){
    float s = pbp[j];
    for(int q=0;q<64;q++) s = fmaf(xq[r][q], pWp[q*64+j], s);
    XQ2[(size_t)i*64+j] = s;
  }
}

__global__ void k_edge_score(const int* __restrict__ src,const int* __restrict__ dst,
                             const float* __restrict__ XQ2,const float* __restrict__ X,
                             float* sE,int E,int n){
  int e = blockIdx.x*256+threadIdx.x; if(e>=E+n) return;
  int s,d; edge_sd(e,src,dst,E,s,d);
  const float* q = XQ2 + (size_t)d*64;
  const float* x = X + (size_t)s*64;
  float acc = 0.0f;
  for(int h=0;h<64;h++) acc = fmaf(q[h], x[h], acc);
  sE[e] = acc > 0.0f ? acc : 0.2f*acc;
}

// per-dst softmax over in-edges -> scE; also emits Mt[p] = {rowD[p]*kk, bits(scE)}
__global__ void k_dstsoft(const int* __restrict__ offD,const int* __restrict__ eidD,
                          const int* __restrict__ rowD,
                          const float* __restrict__ sE,float* __restrict__ scE,
                          int2* __restrict__ Mt,int kk,int n){
  int i = blockIdx.x*256+threadIdx.x; if(i>=n) return;
  int p0 = offD[i], p1 = offD[i+1];
  float m = -3.0e38f;
  for(int p=p0;p<p1;p++) m = fmaxf(m, sE[eidD[p]]);
  float d = 0.0f;
  for(int p=p0;p<p1;p++) d += expf(sE[eidD[p]]-m);
  float inv = 1.0f/d;
  for(int p=p0;p<p1;p++){
    int e = eidD[p];
    float v = expf(sE[e]-m)*inv;
    scE[e] = v;
    Mt[p] = make_int2(rowD[p]*kk, __float_as_int(v));
  }
}

// pool0: xc gather + aN/bN/cN; zeroes pcnt
__global__ __launch_bounds__(256) void k_xcabc0(
    const int* __restrict__ offD,const int* __restrict__ rowD,const int* __restrict__ eidD,
    const float* __restrict__ scE,const float* __restrict__ X,
    float* __restrict__ XC,
    const float* __restrict__ w1,const float* bb1,const float* __restrict__ w2,
    const float* __restrict__ w3,const float* bb3,
    float* aN,float* bN,float* cN,int* pcnt,int n)
{
  __shared__ float xc[4][65];
  const int tid = threadIdx.x;
  const int r = tid>>6, j = tid&63;
  const int i = blockIdx.x*4 + r;
  if (blockIdx.x==0 && tid==0) *pcnt = 0;
  float v = 0.0f;
  if (i < n){
    int p0 = offD[i], p1 = offD[i+1];
    for(int p=p0;p<p1;p++) v += scE[eidD[p]] * X[(size_t)rowD[p]*64 + j];
    XC[(size_t)i*64+j] = v;
  }
  xc[r][j] = v;
  __syncthreads();
  if (i < n && j < 3){
    float s = (j==0)?bb1[0]:((j==2)?bb3[0]:0.0f);
    const float* w = (j==0)?w1:((j==1)?w2:w3);
    for(int q=0;q<64;q++) s = fmaf(xc[r][q], w[q], s);
    if(j==0) aN[i]=s; else if(j==1) bN[i]=s; else cN[i]=s;
  }
}

// pool0 fit + zero rank + ipos=-1
__global__ void k_aggfit0(const int* __restrict__ offD,const int* __restrict__ rowD,
                          const float* aN,const float* bN,const float* cN,
                          float* fit,int* __restrict__ rank,int* __restrict__ ipos,int n){
  int i = blockIdx.x*256+threadIdx.x; if(i>=n) return;
  int p0 = offD[i], p1 = offD[i+1];
  float s = 0.0f;
  for(int p=p0;p<p1;p++) s += aN[rowD[p]];
  fit[i] = sigm(s - (float)(p1-p0)*bN[i] + cN[i]);
  rank[i] = 0;
  ipos[i] = -1;
}

// R column-permuted at write time: Rp[i][ipos[c]] += scE  (only kept columns).
__global__ void k_stage1p(const int* src,const int* dst,const int* __restrict__ offS,
                          const int* __restrict__ colS,const int* __restrict__ eidS,
                          const float* __restrict__ scE,const int* __restrict__ ipos,
                          float* Rp,int E,int n,int kk){
  int e = blockIdx.x*256+threadIdx.x; if(e>=E+n) return;
  int i,j; edge_sd(e,src,dst,E,i,j);
  int p0 = offS[j], p1 = offS[j+1];
  float* Ri = Rp + (size_t)i*kk;
  for(int p=p0;p<p1;p++){
    int ip = ipos[colS[p]];
    if (ip >= 0) atomicAdd(&Ri[ip], scE[eidS[p]]);
  }
}
// A_new[u][v] = sum over in-edges of perm[u]: scE * Rp[row][v].
__global__ __launch_bounds__(256) void k_stage2x(
    const int* __restrict__ perm,const int* __restrict__ offD,
    const int2* __restrict__ Mt,
    const float* __restrict__ Rp,float* A,int k,int vw,int cbn){
  const int bid = blockIdx.x;
  const int slice = bid & 7;
  const int rest = bid >> 3;
  const int cb = rest % cbn;
  const int ub = rest / cbn;
  const int u = ub*4 + (threadIdx.x>>6);
  if (u >= k) return;
  const int vbase = slice*vw;
  int vend = vbase + vw; if (vend > k) vend = k;
  const int v = vbase + cb*64 + (threadIdx.x&63);
  const bool vok = v < vend;
  const int vs = vok ? v : vbase;
  const int d = perm[u];
  float acc = 0.0f;
  int p = offD[d];
  const int p1 = offD[d+1];
  for(; p+4 <= p1; p += 4){
    const int2 m0 = Mt[p];
    const int2 m1 = Mt[p+1];
    const int2 m2 = Mt[p+2];
    const int2 m3 = Mt[p+3];
    const float r0 = Rp[m0.x + vs];
    const float r1 = Rp[m1.x + vs];
    const float r2 = Rp[m2.x + vs];
    const float r3 = Rp[m3.x + vs];
    acc = fmaf(__int_as_float(m0.y), r0, acc);
    acc = fmaf(__int_as_float(m1.y), r1, acc);
    acc = fmaf(__int_as_float(m2.y), r2, acc);
    acc = fmaf(__int_as_float(m3.y), r3, acc);
  }
  for(; p < p1; ++p){
    const int2 m = Mt[p];
    acc = fmaf(__int_as_float(m.y), Rp[m.x + vs], acc);
  }
  if (vok) A[(size_t)u*k + v] = (u==v) ? 0.0f : acc;
}

__global__ void k_head2(const float* __restrict__ xs,const float* __restrict__ W1,
                        const float* __restrict__ b1,const float* __restrict__ W2,
                        const float* __restrict__ b2,float* out){
  __shared__ float h2[64];
  __shared__ float lg[10];
  int t = threadIdx.x;
  float s = b1[t];
  for(int q=0;q<640;q++) s = fmaf(xs[q], W1[q*64+t], s);
  h2[t] = fmaxf(s, 0.0f);
  __syncthreads();
  if(t < 10){
    float s2 = b2[t];
    for(int k=0;k<64;k++) s2 = fmaf(h2[k], W2[k*10+t], s2);
    lg[t] = s2;
  }
  __syncthreads();
  if(t == 0){
    float mx = lg[0];
    for(int i=1;i<10;i++) mx = fmaxf(mx, lg[i]);
    float se = 0.0f;
    for(int i=0;i<10;i++) se += expf(lg[i]-mx);
    float lse = mx + logf(se);
    for(int i=0;i<10;i++) out[i] = lg[i]-lse;
  }
}

// ---------------- host orchestration ----------------
extern "C" void kernel_launch(void* const* d_in, const int* in_sizes, int n_in,
                              void* d_out, int out_size, void* d_ws, size_t ws_size,
                              hipStream_t stream) {
  const int N0 = 1500, E = 24000, Z = 32, L = E + N0;
  const float* x0   = (const float*)d_in[0];
  const int* esrc   = (const int*)d_in[1];
  const int* edst   = (const int*)d_in[2];
  const float* W1   = (const float*)d_in[3];  const float* b1   = (const float*)d_in[4];
  const float* W2   = (const float*)d_in[5];  const float* b2   = (const float*)d_in[6];
  const float* W3   = (const float*)d_in[7];  const float* b3   = (const float*)d_in[8];
  const float* Wrel = (const float*)d_in[9];  const float* brel = (const float*)d_in[10];
  const float* Wroot= (const float*)d_in[11];
  const float* pW   = (const float*)d_in[12]; const float* pb   = (const float*)d_in[13];
  const float* leW1 = (const float*)d_in[14]; const float* leb1 = (const float*)d_in[15];
  const float* leW2 = (const float*)d_in[16]; const float* leW3 = (const float*)d_in[17];
  const float* leb3 = (const float*)d_in[18];
  const float* linW1= (const float*)d_in[19]; const float* linb1= (const float*)d_in[20];
  const float* linW2= (const float*)d_in[21]; const float* linb2= (const float*)d_in[22];
  float* out = (float*)d_out;

  float* ws = (float*)d_ws;
  size_t cur = 0;
  auto allocF = [&](size_t nf)->float*{ float* p = ws + cur; cur += (nf + 15) & ~(size_t)15; return p; };
  // contiguous zero block: xs | indeg | outdeg
  float* xs   = allocF(640);
  int* indeg  = (int*)allocF(1504);
  int* outdeg = (int*)allocF(1504);
  float* Xa  = allocF(96000); float* Xb  = allocF(96000); float* Y   = allocF(96000);
  float* XQ2 = allocF(96000); float* XC  = allocF(96000);
  float* mcol = allocF(1504); float* invd = allocF(1504);
  float* aN = allocF(1504); float* bN = allocF(1504); float* cN = allocF(1504);
  float* fit = allocF(1504); float* cntP = allocF(1504);
  int* pcnt = (int*)allocF(16);
  int* perm = (int*)allocF(1504);
  int* offD = (int*)allocF(1504); int* offS = (int*)allocF(1504);
  int* curD = (int*)allocF(1504); int* curS = (int*)allocF(1504);
  int* colS = (int*)allocF(25504); int* eidS = (int*)allocF(25504);
  int* rowD = (int*)allocF(25504); int* eidD = (int*)allocF(25504);
  float* sE = allocF(25504); float* scE = allocF(25504);
  int2* Mt  = (int2*)allocF(51008);
  int* cntp8 = (int*)allocF((size_t)Z*1504);
  float* aggp = allocF(64*1504);
  float* mpart = allocF(16*1504);
  float* spart = allocF(16*1504);
  float* SEGP = allocF((size_t)Z*1504*64);
  float* Rbig = allocF((size_t)1500*1500);   // pool0 Rp; aliased as split-K slab 0 + SCb
  float* SCb  = Rbig;
  float* A0  = allocF((size_t)1350*1350 + 16);
  float* A1s = allocF((size_t)1350*1350 + 16);
  const size_t SLAB = 1650048;               // >= 1350*1215
  float* PS2 = allocF(SLAB);
  float* PS3 = allocF(SLAB);
  const size_t BFSZ = (size_t)1350*4224/2 + 32;
  ushort* Abf = (ushort*)allocF(BFSZ);
  ushort* Bbf = (ushort*)allocF(BFSZ);
  ushort* Cbf = (ushort*)allocF(BFSZ);
  ushort* Dbf = (ushort*)allocF(BFSZ);
  int* rankb = indeg;                        // dead after k_prefix2

  dim3 B256(256);
  auto G1 = [&](size_t n){ return dim3((unsigned)((n + 255) / 256)); };
  auto ZF = [&](void* p, size_t nfloats){ k_zero<<<G1(nfloats),B256,0,stream>>>((float*)p, nfloats); };
  auto kcz = [&](int K){ return (int)(((K + Z*16 - 1) / (Z*16)) * 16); };

  // ---- prologue: zero (xs+indeg+outdeg contiguous), degrees, CSR ----
  ZF(xs, 640 + 1504 + 1504);
  k_deg<<<G1(E),B256,0,stream>>>(esrc, edst, indeg, outdeg, E);
  k_prefix2<<<dim3((N0+256)/256,2),B256,0,stream>>>(indeg, outdeg, offD, curD, offS, curS, N0);
  k_csr_fill2<<<G1(L),B256,0,stream>>>(esrc, edst, curS, colS, eidS, curD, rowD, eidD, E, N0);

  // ---- FEAST x3 (2 nodes each) ----
  auto feast = [&](const float* xin,int cin,const float* W,const float* bb,int hh,float* xout,float* macc){
    k_mm_small<<<G1((size_t)N0*hh),B256,0,stream>>>(xin, W, nullptr, Y, N0, cin, hh, 0);
    k_feast_gf<<<G1((size_t)N0*hh),B256,0,stream>>>(Y, offD, rowD, bb, xout, N0, hh, macc, 1.0f/N0);
  };
  feast(x0, 16, W1, b1, 32, Xa, nullptr);
  feast(Xa, 32, W2, b2, 64, Xb, nullptr);
  feast(Xb, 64, W3, b3, 64, Xa, xs + 0);
  float* X = Xa; float* XN = Xb;

  // ---- i=0 gconv_sparse (1 node) ----
  k_gconv_sparse_f<<<dim3((N0+3)/4),B256,0,stream>>>(X, offD, rowD, eidD, E, Wrel, brel, Wroot,
                                                     XN, N0, xs + 64, 1.0f/N0);
  { float* t = X; X = XN; XN = t; }

  // ---- pool 0 (sparse ASAP), n=1500 -> k=1350 ----
  {
    const int n = 1500, kk = 1350;
    int* ipos = curD;   // dead after CSR build
    k_xqmaxq<<<dim3((n+3)/4),B256,0,stream>>>(X, offD, rowD, pW, pb, XQ2, n);
    k_edge_score<<<G1(L),B256,0,stream>>>(esrc, edst, XQ2, X, sE, E, n);
    k_dstsoft<<<G1(n),B256,0,stream>>>(offD, eidD, rowD, sE, scE, Mt, kk, n);
    k_xcabc0<<<dim3((n+3)/4),B256,0,stream>>>(offD, rowD, eidD, scE, X, XC,
                                              leW1, leb1, leW2, leW3, leb3, aN, bN, cN, pcnt, n);
    k_aggfit0<<<G1(n),B256,0,stream>>>(offD, rowD, aN, bN, cN, fit, rankb, ipos, n);
    k_rank_cnt<<<dim3((n+255)/256,(n+31)/32),B256,0,stream>>>(fit, rankb, n);
    k_rank_sel<<<dim3((n+3)/4),B256,0,stream>>>(rankb, fit, XC, XN, n, kk, pcnt, perm, ipos);
    ZF(Rbig, (size_t)n*kk);
    k_stage1p<<<G1(L),B256,0,stream>>>(esrc, edst, offS, colS, eidS, scE, ipos, Rbig, E, n, kk);
    {
      const int vw = (kk + 7) / 8;          // 169
      const int cbn = (vw + 63) / 64;       // 3
      const int ubn = (kk + 3) / 4;         // 338
      k_stage2x<<<dim3((unsigned)(8*cbn*ubn)),B256,0,stream>>>(perm, offD, Mt,
                                                               Rbig, A0, kk, vw, cbn);
    }
    { float* t = X; X = XN; XN = t; }
  }

  float* Acur = A0; float* Aoth = A1s;
  int nn = 1350;

  // ---- dense gconv (2 nodes) ----
  auto gconv_dense = [&](int layer){
    dim3 g(1, (nn+63)/64, Z);
    k_skinny<false,true,false,false><<<g,B256,0,stream>>>(Acur, nn, X, nullptr, SEGP, cntp8, nn, nn, kcz(nn));
    k_gconv_fuse<<<dim3((nn+3)/4),B256,0,stream>>>(SEGP, cntp8, Z,
        Wrel + (size_t)layer*4096, brel + layer*64, X, Wroot + (size_t)layer*4096,
        XN, nn, xs + (size_t)(layer+1)*64, 1.0f/nn);
    { float* t = X; X = XN; XN = t; }
  };

  // ---- dense ASAP pool ----
  auto asap_dense = [&](int kk, int p){
    {
      dim3 g(1, (nn+63)/64, Z);
      k_skinny<true,true,false,true><<<g,B256,0,stream>>>(Acur, nn, X, nullptr, SEGP, cntp8, nn, nn, kcz(nn));
    }
    k_poolq<<<dim3((nn+3)/4),B256,0,stream>>>(SEGP, cntp8, Z, pW + (size_t)p*4096, pb + p*64,
                                              X, Abf, Bbf, cntP, nn);
    {
      dim3 g((nn+63)/64, (nn+63)/64);
      k_gemm_mfma<1><<<g,B256,0,stream>>>(Abf, Bbf, SCb, nn, nn, nn, 192, Acur, nn);
    }
    {
      const int chunk = (nn + 15) / 16;
      dim3 gm((nn+15)/16, 16);
      k_smax_pmax<<<gm,B256,0,stream>>>(SCb, nn, chunk, mpart);
      k_smax_psum<<<gm,B256,0,stream>>>(SCb, nn, chunk, mpart, spart);
      k_smax_fin<<<G1(nn),B256,0,stream>>>(mpart, spart, nn, mcol, invd);
    }
    {
      dim3 g(1, (nn+63)/64, Z);
      k_skinny<false,false,true,false><<<g,B256,0,stream>>>(SCb, nn, X, mcol, SEGP, nullptr, nn, nn, kcz(nn));
    }
    k_xcabc_dense<<<dim3((nn+3)/4),B256,0,stream>>>(SEGP, Z, invd, XC,
        leW1 + p*64, leb1 + p, leW2 + p*64, leW3 + p*64, leb3 + p, aN, bN, cN, pcnt, nn);
    k_aggcol<<<G1((size_t)nn*64),B256,0,stream>>>(Acur, aN, aggp, nn);
    k_fit_dense<<<G1(nn),B256,0,stream>>>(aggp, cntP, aN, bN, cN, fit, rankb, pcnt, nn);
    k_rank_cnt<<<dim3((nn+255)/256,(nn+31)/32),B256,0,stream>>>(fit, rankb, nn);
    k_rank_sel<<<dim3((nn+3)/4),B256,0,stream>>>(rankb, fit, XC, XN, nn, kk, pcnt, perm, nullptr);
    const int Kp = (nn + 63) & ~63;
    const int K3 = 3*Kp;
    k_split3<<<G1(((size_t)nn*Kp)>>1),B256,0,stream>>>(Acur, nn, nn, nn, Abf, Kp, 0);
    { dim3 gt((kk+31)/32, Kp/32);
      k_split3_Tdual<<<gt,B256,0,stream>>>(SCb, nn, kk, nn, perm, invd, mcol, Dbf, Bbf, Cbf, Kp); }
    // ---- TB = A@Sp + Sp : split-K x4 (128x128 tiles, K-step 64, XCD swizzle) ----
    const int Tk = K3 >> 6;
    const int kchunk = ((Tk + 3) >> 2) << 6;
    {
      dim3 g((kk+127)/128, (nn+127)/128, 4);
      k_gemm_pp<<<g,B256,0,stream>>>(Abf, Bbf, Rbig, Aoth, PS2, PS3, kk, nn, kk, K3, kchunk);
      dim3 gr((kk+31)/32, (nn+31)/32);
      k_red_tb<<<gr,B256,0,stream>>>(Rbig, Aoth, PS2, PS3, kk, Bbf, Cbf, nn, kk, Kp);
    }
    // ---- A_new = Sp^T @ TB (zero diag): split-K x4 (output Aoth aliases slab 1: safe) ----
    {
      dim3 g((kk+127)/128, (kk+127)/128, 4);
      k_gemm_pp<<<g,B256,0,stream>>>(Dbf, Cbf, Rbig, Aoth, PS2, PS3, kk, kk, kk, K3, kchunk);
      k_red_diag<<<G1(((size_t)kk*kk + 3)>>2),B256,0,stream>>>(Rbig, Aoth, PS2, PS3, Aoth, kk);
    }
    { float* t = X; X = XN; XN = t; }
    { float* t = Acur; Acur = Aoth; Aoth = t; }
    nn = kk;
  };

  gconv_dense(1);
  gconv_dense(2);
  asap_dense(1215, 1);
  gconv_dense(3);
  gconv_dense(4);
  asap_dense(1094, 2);
  gconv_dense(5);
  gconv_dense(6);
  asap_dense(985, 3);
  gconv_dense(7);
  gconv_dense(8);

  // ---- head (1 node) ----
  k_head2<<<1,64,0,stream>>>(xs, linW1, linb1, linW2, linb2, out);
}